// Round 11
// baseline (702.763 us; speedup 1.0000x reference)
//
#include <hip/hip_runtime.h>
#include <hip/hip_bf16.h>

#define NA_ 4096
#define NB_ 4096
#define NN_ 8192            // total nodes
#define EE_ 131072          // edges per direction
#define NE_ (2*EE_ + NN_)   // homogeneous edges incl. self loops = 270336
#define HH_ 512
#define NEG_SLOPE_ 0.2f

typedef __attribute__((ext_vector_type(4))) float f32x4;
typedef __attribute__((ext_vector_type(8))) short s16x8;

__device__ inline unsigned short f2bf(float v) {
    __hip_bfloat16 h = __float2bfloat16(v);
    return __builtin_bit_cast(unsigned short, h);
}
__device__ inline float bf2f(unsigned short u) {
    return __uint_as_float(((unsigned)u) << 16);
}

// ---------------- float-order <-> unsigned-order mapping for atomic max ----
__device__ inline unsigned fkey(float f) {
    unsigned b = __float_as_uint(f);
    return (b & 0x80000000u) ? ~b : (b | 0x80000000u);
}
__device__ inline float finv(unsigned k) {
    return (k & 0x80000000u) ? __uint_as_float(k & 0x7fffffffu)
                             : __uint_as_float(~k);
}

// ---------------- homogeneous edge id -> (src, dst) ------------------------
__device__ inline void edge_sd(int i, const int* __restrict__ eAB,
                               const int* __restrict__ eBA, int& s, int& d) {
    if (i < EE_)            { s = eAB[i];            d = eAB[EE_ + i] + NA_; }
    else if (i < 2 * EE_)   { int j = i - EE_; s = eBA[j] + NA_; d = eBA[EE_ + j]; }
    else                    { s = i - 2 * EE_;       d = s; }
}

// ---------------- batched f32 -> bf16 (optionally split hi/lo) casts --------
struct CvtJob { const float* s; unsigned short* hi; unsigned short* lo; int n4; };
struct CvtJobs { CvtJob j[10]; };

__global__ __launch_bounds__(256) void cvt_all_k(CvtJobs jobs) {
    const CvtJob jb = jobs.j[blockIdx.y];
    int i = blockIdx.x * 256 + threadIdx.x;
    if (i >= jb.n4) return;
    float4 v = ((const float4*)jb.s)[i];
    ushort4 h;
    h.x = f2bf(v.x); h.y = f2bf(v.y); h.z = f2bf(v.z); h.w = f2bf(v.w);
    ((ushort4*)jb.hi)[i] = h;
    if (jb.lo) {
        ushort4 l;
        l.x = f2bf(v.x - bf2f(h.x));
        l.y = f2bf(v.y - bf2f(h.y));
        l.z = f2bf(v.z - bf2f(h.z));
        l.w = f2bf(v.w - bf2f(h.w));
        ((ushort4*)jb.lo)[i] = l;
    }
}

// ---------------- MFMA bf16 GEMM: C[M,N] = A @ B^T (+bias) -----------------
template<int BM, int BN, bool BIAS, typename OutT>
__global__ __launch_bounds__(256) void mgemm_k(
    const unsigned short* __restrict__ A, const unsigned short* __restrict__ B,
    const float* __restrict__ bias, OutT* __restrict__ C,
    int K, int lda, int ldb, int ldc)
{
    constexpr int BK = 32;
    constexpr int WM = BM / 2, WN = BN / 2;
    constexpr int AM = WM / 16, AN = WN / 16;
    constexpr int AISS = BM * 4 / 256, BISS = BN * 4 / 256;
    __shared__ unsigned short sA[BM * BK];
    __shared__ unsigned short sB[BN * BK];
    const int t = threadIdx.x, lane = t & 63, w = t >> 6;
    const int wr = w >> 1, wc = w & 1;
    const int fr = lane & 15, fq = lane >> 4;
    const int bm = blockIdx.y * BM, bn = blockIdx.x * BN;

    f32x4 acc[AM][AN];
    #pragma unroll
    for (int m = 0; m < AM; m++)
        #pragma unroll
        for (int n = 0; n < AN; n++)
            #pragma unroll
            for (int r = 0; r < 4; r++) acc[m][n][r] = 0.f;

    for (int k0 = 0; k0 < K; k0 += BK) {
        __syncthreads();
        #pragma unroll
        for (int i = 0; i < AISS; i++) {
            int slot = i * 256 + t;
            __builtin_amdgcn_global_load_lds(
                (const __attribute__((address_space(1))) unsigned int*)
                    (A + (size_t)(bm + (slot >> 2)) * lda + k0 + (slot & 3) * 8),
                (__attribute__((address_space(3))) unsigned int*)
                    (sA + (i * 256 + w * 64) * 8), 16, 0, 0);
        }
        #pragma unroll
        for (int i = 0; i < BISS; i++) {
            int slot = i * 256 + t;
            __builtin_amdgcn_global_load_lds(
                (const __attribute__((address_space(1))) unsigned int*)
                    (B + (size_t)(bn + (slot >> 2)) * ldb + k0 + (slot & 3) * 8),
                (__attribute__((address_space(3))) unsigned int*)
                    (sB + (i * 256 + w * 64) * 8), 16, 0, 0);
        }
        __syncthreads();
        s16x8 a[AM], b[AN];
        #pragma unroll
        for (int m = 0; m < AM; m++)
            a[m] = *(const s16x8*)&sA[(wr * WM + m * 16 + fr) * BK + fq * 8];
        #pragma unroll
        for (int n = 0; n < AN; n++)
            b[n] = *(const s16x8*)&sB[(wc * WN + n * 16 + fr) * BK + fq * 8];
        #pragma unroll
        for (int m = 0; m < AM; m++)
            #pragma unroll
            for (int n = 0; n < AN; n++)
                acc[m][n] = __builtin_amdgcn_mfma_f32_16x16x32_bf16(a[m], b[n], acc[m][n], 0, 0, 0);
    }

    // C/D layout: col = lane&15, row = (lane>>4)*4 + reg
    #pragma unroll
    for (int m = 0; m < AM; m++) {
        const int row = bm + wr * WM + m * 16 + fq * 4;
        #pragma unroll
        for (int n = 0; n < AN; n++) {
            const int col = bn + wc * WN + n * 16 + fr;
            const float bv = BIAS ? bias[col] : 0.f;
            #pragma unroll
            for (int r = 0; r < 4; r++) {
                float v = acc[m][n][r] + bv;
                if constexpr (sizeof(OutT) == 2)
                    C[(size_t)(row + r) * ldc + col] = (OutT)f2bf(v);
                else
                    C[(size_t)(row + r) * ldc + col] = v;
            }
        }
    }
}

// ---------------- QK^T MFMA GEMM + fused exp + row-sum ---------------------
// C[row][col] = exp(q[row].k[col]) bf16 (q pre-scaled); denom[row] += row-sum.
__global__ __launch_bounds__(256) void mgemm_qk_k(
    const unsigned short* __restrict__ A, const unsigned short* __restrict__ B,
    unsigned short* __restrict__ C, float* __restrict__ denom)
{
    constexpr int BK = 32;
    __shared__ unsigned short sA[128 * BK];
    __shared__ unsigned short sB[128 * BK];
    const int t = threadIdx.x, lane = t & 63, w = t >> 6;
    const int wr = w >> 1, wc = w & 1;
    const int fr = lane & 15, fq = lane >> 4;
    const int bm = blockIdx.y * 128, bn = blockIdx.x * 128;

    f32x4 acc[4][4];
    #pragma unroll
    for (int m = 0; m < 4; m++)
        #pragma unroll
        for (int n = 0; n < 4; n++)
            #pragma unroll
            for (int r = 0; r < 4; r++) acc[m][n][r] = 0.f;

    for (int k0 = 0; k0 < 512; k0 += BK) {
        __syncthreads();
        #pragma unroll
        for (int i = 0; i < 2; i++) {
            int slot = i * 256 + t;
            __builtin_amdgcn_global_load_lds(
                (const __attribute__((address_space(1))) unsigned int*)
                    (A + (size_t)(bm + (slot >> 2)) * 512 + k0 + (slot & 3) * 8),
                (__attribute__((address_space(3))) unsigned int*)
                    (sA + (i * 256 + w * 64) * 8), 16, 0, 0);
            __builtin_amdgcn_global_load_lds(
                (const __attribute__((address_space(1))) unsigned int*)
                    (B + (size_t)(bn + (slot >> 2)) * 512 + k0 + (slot & 3) * 8),
                (__attribute__((address_space(3))) unsigned int*)
                    (sB + (i * 256 + w * 64) * 8), 16, 0, 0);
        }
        __syncthreads();
        s16x8 a[4], b[4];
        #pragma unroll
        for (int m = 0; m < 4; m++)
            a[m] = *(const s16x8*)&sA[(wr * 64 + m * 16 + fr) * BK + fq * 8];
        #pragma unroll
        for (int n = 0; n < 4; n++)
            b[n] = *(const s16x8*)&sB[(wc * 64 + n * 16 + fr) * BK + fq * 8];
        #pragma unroll
        for (int m = 0; m < 4; m++)
            #pragma unroll
            for (int n = 0; n < 4; n++)
                acc[m][n] = __builtin_amdgcn_mfma_f32_16x16x32_bf16(a[m], b[n], acc[m][n], 0, 0, 0);
    }

    #pragma unroll
    for (int m = 0; m < 4; m++) {
        const int row = bm + wr * 64 + m * 16 + fq * 4;
        #pragma unroll
        for (int r = 0; r < 4; r++) {
            float rsum = 0.f;
            #pragma unroll
            for (int n = 0; n < 4; n++) {
                const int col = bn + wc * 64 + n * 16 + fr;
                float p = expf(acc[m][n][r]);
                rsum += p;
                C[(size_t)(row + r) * 8192 + col] = f2bf(p);
            }
            rsum += __shfl_xor(rsum, 1);
            rsum += __shfl_xor(rsum, 2);
            rsum += __shfl_xor(rsum, 4);
            rsum += __shfl_xor(rsum, 8);
            if (fr == 0) atomicAdd(&denom[row + r], rsum);
        }
    }
}

// ---------------- merged per-type input linear (A rows 0..4095, B rows 4096+)
template<bool SPLIT>
__global__ __launch_bounds__(256) void mgemm_in_k(
    const unsigned short* __restrict__ xA, const unsigned short* __restrict__ xB,
    const unsigned short* __restrict__ WA, const unsigned short* __restrict__ WB,
    const float* __restrict__ biasA, const float* __restrict__ biasB,
    unsigned short* __restrict__ o1, unsigned short* __restrict__ o2)
{
    constexpr int BK = 32;
    __shared__ unsigned short sA[128 * BK];
    __shared__ unsigned short sB[128 * BK];
    const int t = threadIdx.x, lane = t & 63, w = t >> 6;
    const int wr = w >> 1, wc = w & 1;
    const int fr = lane & 15, fq = lane >> 4;
    const int bm = blockIdx.y * 128, bn = blockIdx.x * 128;
    const bool isB = bm >= NA_;
    const unsigned short* A = isB ? xB : xA;
    const unsigned short* W = isB ? WB : WA;
    const float* bias = isB ? biasB : biasA;
    const int bml = bm - (isB ? NA_ : 0);

    f32x4 acc[4][4];
    #pragma unroll
    for (int m = 0; m < 4; m++)
        #pragma unroll
        for (int n = 0; n < 4; n++)
            #pragma unroll
            for (int r = 0; r < 4; r++) acc[m][n][r] = 0.f;

    for (int k0 = 0; k0 < 256; k0 += BK) {
        __syncthreads();
        #pragma unroll
        for (int i = 0; i < 2; i++) {
            int slot = i * 256 + t;
            __builtin_amdgcn_global_load_lds(
                (const __attribute__((address_space(1))) unsigned int*)
                    (A + (size_t)(bml + (slot >> 2)) * 256 + k0 + (slot & 3) * 8),
                (__attribute__((address_space(3))) unsigned int*)
                    (sA + (i * 256 + w * 64) * 8), 16, 0, 0);
            __builtin_amdgcn_global_load_lds(
                (const __attribute__((address_space(1))) unsigned int*)
                    (W + (size_t)(bn + (slot >> 2)) * 256 + k0 + (slot & 3) * 8),
                (__attribute__((address_space(3))) unsigned int*)
                    (sB + (i * 256 + w * 64) * 8), 16, 0, 0);
        }
        __syncthreads();
        s16x8 a[4], b[4];
        #pragma unroll
        for (int m = 0; m < 4; m++)
            a[m] = *(const s16x8*)&sA[(wr * 64 + m * 16 + fr) * BK + fq * 8];
        #pragma unroll
        for (int n = 0; n < 4; n++)
            b[n] = *(const s16x8*)&sB[(wc * 64 + n * 16 + fr) * BK + fq * 8];
        #pragma unroll
        for (int m = 0; m < 4; m++)
            #pragma unroll
            for (int n = 0; n < 4; n++)
                acc[m][n] = __builtin_amdgcn_mfma_f32_16x16x32_bf16(a[m], b[n], acc[m][n], 0, 0, 0);
    }

    #pragma unroll
    for (int m = 0; m < 4; m++) {
        const int row = bm + wr * 64 + m * 16 + fq * 4;
        #pragma unroll
        for (int n = 0; n < 4; n++) {
            const int col = bn + wc * 64 + n * 16 + fr;
            const float bv = bias[col];
            #pragma unroll
            for (int r = 0; r < 4; r++) {
                float v = acc[m][n][r] + bv;
                unsigned short hi = f2bf(v);
                o1[(size_t)(row + r) * 512 + col] = hi;
                if (SPLIT)
                    o2[(size_t)(row + r) * 512 + col] = f2bf(v - bf2f(hi));
            }
        }
    }
}

// ---------------- split-precision MFMA GEMM (~f32 accuracy) ----------------
__global__ __launch_bounds__(256) void mgemm3_k(
    const unsigned short* __restrict__ Ahi, const unsigned short* __restrict__ Alo,
    const unsigned short* __restrict__ Bhi, const unsigned short* __restrict__ Blo,
    float* __restrict__ C, unsigned short* __restrict__ Cb,
    int K, int lda, int ldb, int ldc)
{
    constexpr int BM = 128, BN = 128, BK = 32;
    __shared__ unsigned short sAh[BM * BK], sAl[BM * BK];
    __shared__ unsigned short sBh[BN * BK], sBl[BN * BK];
    const int t = threadIdx.x, lane = t & 63, w = t >> 6;
    const int wr = w >> 1, wc = w & 1;
    const int fr = lane & 15, fq = lane >> 4;
    const int bm = blockIdx.y * BM, bn = blockIdx.x * BN;

    f32x4 acc[4][4];
    #pragma unroll
    for (int m = 0; m < 4; m++)
        #pragma unroll
        for (int n = 0; n < 4; n++)
            #pragma unroll
            for (int r = 0; r < 4; r++) acc[m][n][r] = 0.f;

    for (int k0 = 0; k0 < K; k0 += BK) {
        __syncthreads();
        #pragma unroll
        for (int i = 0; i < 2; i++) {
            int slot = i * 256 + t;
            size_t ga = (size_t)(bm + (slot >> 2)) * lda + k0 + (slot & 3) * 8;
            size_t gb = (size_t)(bn + (slot >> 2)) * ldb + k0 + (slot & 3) * 8;
            unsigned loff = (unsigned)(i * 256 + w * 64) * 8;
            __builtin_amdgcn_global_load_lds(
                (const __attribute__((address_space(1))) unsigned int*)(Ahi + ga),
                (__attribute__((address_space(3))) unsigned int*)(sAh + loff), 16, 0, 0);
            __builtin_amdgcn_global_load_lds(
                (const __attribute__((address_space(1))) unsigned int*)(Alo + ga),
                (__attribute__((address_space(3))) unsigned int*)(sAl + loff), 16, 0, 0);
            __builtin_amdgcn_global_load_lds(
                (const __attribute__((address_space(1))) unsigned int*)(Bhi + gb),
                (__attribute__((address_space(3))) unsigned int*)(sBh + loff), 16, 0, 0);
            __builtin_amdgcn_global_load_lds(
                (const __attribute__((address_space(1))) unsigned int*)(Blo + gb),
                (__attribute__((address_space(3))) unsigned int*)(sBl + loff), 16, 0, 0);
        }
        __syncthreads();
        s16x8 ah[4], al[4], bh[4], bl[4];
        #pragma unroll
        for (int m = 0; m < 4; m++) {
            int o = (wr * 64 + m * 16 + fr) * BK + fq * 8;
            ah[m] = *(const s16x8*)&sAh[o];
            al[m] = *(const s16x8*)&sAl[o];
        }
        #pragma unroll
        for (int n = 0; n < 4; n++) {
            int o = (wc * 64 + n * 16 + fr) * BK + fq * 8;
            bh[n] = *(const s16x8*)&sBh[o];
            bl[n] = *(const s16x8*)&sBl[o];
        }
        #pragma unroll
        for (int m = 0; m < 4; m++)
            #pragma unroll
            for (int n = 0; n < 4; n++) {
                acc[m][n] = __builtin_amdgcn_mfma_f32_16x16x32_bf16(ah[m], bh[n], acc[m][n], 0, 0, 0);
                acc[m][n] = __builtin_amdgcn_mfma_f32_16x16x32_bf16(ah[m], bl[n], acc[m][n], 0, 0, 0);
                acc[m][n] = __builtin_amdgcn_mfma_f32_16x16x32_bf16(al[m], bh[n], acc[m][n], 0, 0, 0);
            }
    }

    #pragma unroll
    for (int m = 0; m < 4; m++) {
        const int row = bm + wr * 64 + m * 16 + fq * 4;
        #pragma unroll
        for (int n = 0; n < 4; n++) {
            const int col = bn + wc * 64 + n * 16 + fr;
            #pragma unroll
            for (int r = 0; r < 4; r++) {
                float v = acc[m][n][r];
                C[(size_t)(row + r) * ldc + col]  = v;
                Cb[(size_t)(row + r) * 512 + col] = f2bf(v);
            }
        }
    }
}

// ---------------- PV split-K MFMA GEMM (bf16 partials, XCD swizzle) --------
__global__ __launch_bounds__(256) void mgemm_pv_k(
    const unsigned short* __restrict__ A, const unsigned short* __restrict__ B,
    unsigned short* __restrict__ C, int kseg, size_t segstride)
{
    constexpr int BM = 128, BN = 128, BK = 32;
    __shared__ unsigned short sA[BM * BK];
    __shared__ unsigned short sB[BN * BK];
    const int t = threadIdx.x, lane = t & 63, w = t >> 6;
    const int wr = w >> 1, wc = w & 1;
    const int fr = lane & 15, fq = lane >> 4;
    const int L  = blockIdx.x + (blockIdx.y << 2) + (blockIdx.z << 6);
    const int xs = L >> 7;
    const int ys = (L & 127) & 15;
    const int zs = (L & 127) >> 4;
    const int bm = ys * BM, bn = xs * BN;
    const int kofs = zs * kseg;

    f32x4 acc[4][4];
    #pragma unroll
    for (int m = 0; m < 4; m++)
        #pragma unroll
        for (int n = 0; n < 4; n++)
            #pragma unroll
            for (int r = 0; r < 4; r++) acc[m][n][r] = 0.f;

    for (int k0 = 0; k0 < kseg; k0 += BK) {
        __syncthreads();
        #pragma unroll
        for (int i = 0; i < 2; i++) {
            int slot = i * 256 + t;
            __builtin_amdgcn_global_load_lds(
                (const __attribute__((address_space(1))) unsigned int*)
                    (A + (size_t)(bm + (slot >> 2)) * 8192 + kofs + k0 + (slot & 3) * 8),
                (__attribute__((address_space(3))) unsigned int*)
                    (sA + (i * 256 + w * 64) * 8), 16, 0, 0);
            __builtin_amdgcn_global_load_lds(
                (const __attribute__((address_space(1))) unsigned int*)
                    (B + (size_t)(bn + (slot >> 2)) * 8192 + kofs + k0 + (slot & 3) * 8),
                (__attribute__((address_space(3))) unsigned int*)
                    (sB + (i * 256 + w * 64) * 8), 16, 0, 0);
        }
        __syncthreads();
        s16x8 a[4], b[4];
        #pragma unroll
        for (int m = 0; m < 4; m++)
            a[m] = *(const s16x8*)&sA[(wr * 64 + m * 16 + fr) * BK + fq * 8];
        #pragma unroll
        for (int n = 0; n < 4; n++)
            b[n] = *(const s16x8*)&sB[(wc * 64 + n * 16 + fr) * BK + fq * 8];
        #pragma unroll
        for (int m = 0; m < 4; m++)
            #pragma unroll
            for (int n = 0; n < 4; n++)
                acc[m][n] = __builtin_amdgcn_mfma_f32_16x16x32_bf16(a[m], b[n], acc[m][n], 0, 0, 0);
    }

    unsigned short* Cz = C + (size_t)zs * segstride;
    #pragma unroll
    for (int m = 0; m < 4; m++) {
        const int row = bm + wr * 64 + m * 16 + fq * 4;
        #pragma unroll
        for (int n = 0; n < 4; n++) {
            const int col = bn + wc * 64 + n * 16 + fr;
            #pragma unroll
            for (int r = 0; r < 4; r++)
                Cz[(size_t)(row + r) * 512 + col] = f2bf(acc[m][n][r]);
        }
    }
}

// ---------------- reduce bf16 split-K partials, divide by denom -> bf16 ----
__global__ __launch_bounds__(256) void radd_k(const unsigned short* __restrict__ src,
                                              unsigned short* __restrict__ dst,
                                              const float* __restrict__ dn,
                                              int n8, int segs, size_t stride8) {
    int i = blockIdx.x * 256 + threadIdx.x;
    if (i >= n8) return;
    float acc[8] = {0,0,0,0,0,0,0,0};
    for (int s = 0; s < segs; s++) {
        s16x8 v = ((const s16x8*)src)[i + s * stride8];
        #pragma unroll
        for (int j = 0; j < 8; j++) acc[j] += bf2f((unsigned short)v[j]);
    }
    const float rd = 1.0f / dn[i >> 6];    // 64 groups of 8 per 512-col row
    s16x8 o;
    #pragma unroll
    for (int j = 0; j < 8; j++) o[j] = (short)f2bf(acc[j] * rd);
    ((s16x8*)dst)[i] = o;
}

// ---------------- qkv MFMA GEMM with split epilogue (scale folded into q) ---
__global__ __launch_bounds__(256) void mgemm_qkv_k(
    const unsigned short* __restrict__ A, const unsigned short* __restrict__ B,
    const float* __restrict__ bias, float scale,
    unsigned short* __restrict__ qb, unsigned short* __restrict__ kb,
    unsigned short* __restrict__ vb)
{
    constexpr int BM = 128, BN = 128, BK = 32;
    __shared__ unsigned short sA[BM * BK];
    __shared__ unsigned short sB[BN * BK];
    const int t = threadIdx.x, lane = t & 63, w = t >> 6;
    const int wr = w >> 1, wc = w & 1;
    const int fr = lane & 15, fq = lane >> 4;
    const int bm = blockIdx.y * BM, bn = blockIdx.x * BN;

    f32x4 acc[4][4];
    #pragma unroll
    for (int m = 0; m < 4; m++)
        #pragma unroll
        for (int n = 0; n < 4; n++)
            #pragma unroll
            for (int r = 0; r < 4; r++) acc[m][n][r] = 0.f;

    for (int k0 = 0; k0 < 512; k0 += BK) {
        __syncthreads();
        #pragma unroll
        for (int i = 0; i < 2; i++) {
            int slot = i * 256 + t;
            __builtin_amdgcn_global_load_lds(
                (const __attribute__((address_space(1))) unsigned int*)
                    (A + (size_t)(bm + (slot >> 2)) * 512 + k0 + (slot & 3) * 8),
                (__attribute__((address_space(3))) unsigned int*)
                    (sA + (i * 256 + w * 64) * 8), 16, 0, 0);
            __builtin_amdgcn_global_load_lds(
                (const __attribute__((address_space(1))) unsigned int*)
                    (B + (size_t)(bn + (slot >> 2)) * 512 + k0 + (slot & 3) * 8),
                (__attribute__((address_space(3))) unsigned int*)
                    (sB + (i * 256 + w * 64) * 8), 16, 0, 0);
        }
        __syncthreads();
        s16x8 a[4], b[4];
        #pragma unroll
        for (int m = 0; m < 4; m++)
            a[m] = *(const s16x8*)&sA[(wr * 64 + m * 16 + fr) * BK + fq * 8];
        #pragma unroll
        for (int n = 0; n < 4; n++)
            b[n] = *(const s16x8*)&sB[(wc * 64 + n * 16 + fr) * BK + fq * 8];
        #pragma unroll
        for (int m = 0; m < 4; m++)
            #pragma unroll
            for (int n = 0; n < 4; n++)
                acc[m][n] = __builtin_amdgcn_mfma_f32_16x16x32_bf16(a[m], b[n], acc[m][n], 0, 0, 0);
    }

    #pragma unroll
    for (int m = 0; m < 4; m++) {
        const int row = bm + wr * 64 + m * 16 + fq * 4;
        #pragma unroll
        for (int n = 0; n < 4; n++) {
            const int col = bn + wc * 64 + n * 16 + fr;
            const float bv = bias[col];
            #pragma unroll
            for (int r = 0; r < 4; r++) {
                float v = acc[m][n][r] + bv;
                if (col < 512)
                    qb[(size_t)(row + r) * 512 + col] = f2bf(v * scale);
                else if (col < 1024)
                    kb[(size_t)(row + r) * 512 + (col - 512)] = f2bf(v);
                else
                    vb[(size_t)(row + r) * 512 + (col - 1024)] = f2bf(v);
            }
        }
    }
}

// ---------------- bf16 transpose: vb[8192][512] -> vT[512][8192] ------------
__global__ __launch_bounds__(256) void trT_k(const unsigned short* __restrict__ vb,
                                             unsigned short* __restrict__ vT) {
    __shared__ unsigned short s[64][65];
    const int t = threadIdx.x;
    const int rowo = blockIdx.y * 64;
    const int colo = blockIdx.x * 64;
    {
        int r = t >> 2, cg = (t & 3) * 16;
        const s16x8* src = (const s16x8*)(vb + (size_t)(rowo + r) * 512 + colo + cg);
        s16x8 u0 = src[0], u1 = src[1];
        #pragma unroll
        for (int j = 0; j < 8; j++) {
            s[r][cg + j]     = (unsigned short)u0[j];
            s[r][cg + 8 + j] = (unsigned short)u1[j];
        }
    }
    __syncthreads();
    {
        int c = t >> 2, rg = (t & 3) * 16;
        s16x8 o0, o1;
        #pragma unroll
        for (int j = 0; j < 8; j++) {
            o0[j] = (short)s[rg + j][c];
            o1[j] = (short)s[rg + 8 + j][c];
        }
        s16x8* dst = (s16x8*)(vT + (size_t)(colo + c) * 8192 + rowo + rg);
        dst[0] = o0; dst[1] = o1;
    }
}

// ---------------- per-node attention dots (wave per node) -------------------
__global__ __launch_bounds__(256) void node_dots_k(
    const float* __restrict__ h, const float* __restrict__ a_src,
    const float* __restrict__ a_dst, float* __restrict__ as_, float* __restrict__ ad_)
{
    int wid  = (blockIdx.x * 256 + threadIdx.x) >> 6;
    int lane = threadIdx.x & 63;
    if (wid >= NN_) return;
    const float* hr = h + (size_t)wid * HH_;
    float s1 = 0.f, s2 = 0.f;
    #pragma unroll
    for (int j = 0; j < 8; j++) {
        float v = hr[lane + j*64];
        s1 = fmaf(v, a_src[lane + j*64], s1);
        s2 = fmaf(v, a_dst[lane + j*64], s2);
    }
    #pragma unroll
    for (int off = 32; off; off >>= 1) {
        s1 += __shfl_down(s1, off);
        s2 += __shfl_down(s2, off);
    }
    if (lane == 0) { as_[wid] = s1; ad_[wid] = s2; }
}

// ---------------- CSR build ------------------------------------------------
__global__ void count_deg_k(const int* eAB, const int* eBA, int* deg) {
    int i = blockIdx.x * 256 + threadIdx.x;
    if (i >= NE_) return;
    int s, d; edge_sd(i, eAB, eBA, s, d);
    atomicAdd(&deg[d], 1);
}

__global__ __launch_bounds__(256) void scan_k(const int* __restrict__ deg, int* rowstart) {
    __shared__ int part[256];
    int t = threadIdx.x;
    int base = t * 32;
    int loc[32]; int s = 0;
    #pragma unroll
    for (int j = 0; j < 32; j++) { loc[j] = s; s += deg[base + j]; }
    part[t] = s;
    __syncthreads();
    if (t == 0) {
        int a = 0;
        for (int i = 0; i < 256; i++) { int v = part[i]; part[i] = a; a += v; }
        rowstart[NN_] = a;
    }
    __syncthreads();
    int off = part[t];
    #pragma unroll
    for (int j = 0; j < 32; j++) rowstart[base + j] = off + loc[j];
}

// stores src node per CSR slot + slot index per edge (kills indirection later)
__global__ void fill_csr_k(const int* eAB, const int* eBA,
                           const int* __restrict__ rowstart, int* cursor,
                           int* csr_src, int* pos) {
    int i = blockIdx.x * 256 + threadIdx.x;
    if (i >= NE_) return;
    int s, d; edge_sd(i, eAB, eBA, s, d);
    int p = atomicAdd(&cursor[d], 1);
    int slot = rowstart[d] + p;
    csr_src[slot] = s;
    pos[i] = slot;
}

// ---------------- GAT edge passes ------------------------------------------
__global__ void edge_pass1_k(const int* eAB, const int* eBA,
                             const float* __restrict__ as_, const float* __restrict__ ad_,
                             float* evals, unsigned* mkey) {
    int i = blockIdx.x * 256 + threadIdx.x;
    if (i >= NE_) return;
    int s, d; edge_sd(i, eAB, eBA, s, d);
    float e = as_[s] + ad_[d];
    e = (e >= 0.f) ? e : NEG_SLOPE_ * e;
    evals[i] = e;
    atomicMax(&mkey[d], fkey(e));
}

// scatters exp into CSR order (evs) + accumulates denom
__global__ void edge_pass2_k(const int* eAB, const int* eBA,
                             const unsigned* __restrict__ mkey,
                             const float* __restrict__ evals,
                             const int* __restrict__ pos,
                             float* __restrict__ evs, float* denom) {
    int i = blockIdx.x * 256 + threadIdx.x;
    if (i >= NE_) return;
    int s, d; edge_sd(i, eAB, eBA, s, d);
    float m = finv(mkey[d]);
    float ex = expf(evals[i] - m);
    evs[pos[i]] = ex;
    atomicAdd(&denom[d], ex);
}

// ---------------- GAT aggregation: feature-half pass, streaming CSR ---------
// fhalf selects 256-feature half (4MB bf16 working set = one XCD L2).
template<bool SPLIT>
__global__ __launch_bounds__(256) void gat_agg_k(
    const int* __restrict__ rowstart, const int* __restrict__ csr_src,
    const float* __restrict__ evs, const float* __restrict__ denom,
    const unsigned short* __restrict__ hb, const float* __restrict__ bias,
    float* __restrict__ outF, int ldo,
    unsigned short* __restrict__ outHi, unsigned short* __restrict__ outLo,
    int fhalf)
{
    int wid  = (blockIdx.x * 256 + threadIdx.x) >> 6;
    int lane = threadIdx.x & 63;
    if (wid >= NN_) return;
    const int fo = fhalf * 256 + lane * 4;
    float a0 = 0.f, a1 = 0.f, a2 = 0.f, a3 = 0.f;
    int beg = rowstart[wid], end = rowstart[wid + 1];
    float rden = 1.0f / denom[wid];
    for (int p = beg; p < end; p++) {
        int s = csr_src[p];
        float alpha = evs[p] * rden;
        ushort4 hv = *(const ushort4*)(hb + (size_t)s * HH_ + fo);
        a0 = fmaf(alpha, bf2f(hv.x), a0);
        a1 = fmaf(alpha, bf2f(hv.y), a1);
        a2 = fmaf(alpha, bf2f(hv.z), a2);
        a3 = fmaf(alpha, bf2f(hv.w), a3);
    }
    a0 += bias[fo];  a1 += bias[fo+1];  a2 += bias[fo+2];  a3 += bias[fo+3];
    if (SPLIT) {
        ushort4 hi, lo;
        hi.x = f2bf(a0); lo.x = f2bf(a0 - bf2f(hi.x));
        hi.y = f2bf(a1); lo.y = f2bf(a1 - bf2f(hi.y));
        hi.z = f2bf(a2); lo.z = f2bf(a2 - bf2f(hi.z));
        hi.w = f2bf(a3); lo.w = f2bf(a3 - bf2f(hi.w));
        *(ushort4*)(outHi + (size_t)wid * HH_ + fo) = hi;
        *(ushort4*)(outLo + (size_t)wid * HH_ + fo) = lo;
    } else {
        *(float4*)(outF + (size_t)wid * ldo + fo) = make_float4(a0, a1, a2, a3);
    }
}

// ===========================================================================
extern "C" void kernel_launch(void* const* d_in, const int* in_sizes, int n_in,
                              void* d_out, int out_size, void* d_ws, size_t ws_size,
                              hipStream_t stream)
{
    const float* x_A    = (const float*)d_in[0];
    const float* x_B    = (const float*)d_in[1];
    const int*   eAB    = (const int*)d_in[2];
    const int*   eBA    = (const int*)d_in[3];
    const float* W_inA  = (const float*)d_in[4];  const float* b_inA  = (const float*)d_in[5];
    const float* W_inB  = (const float*)d_in[6];  const float* b_inB  = (const float*)d_in[7];
    const float* W_in2A = (const float*)d_in[8];  const float* b_in2A = (const float*)d_in[9];
    const float* W_in2B = (const float*)d_in[10]; const float* b_in2B = (const float*)d_in[11];
    const float* Wg1    = (const float*)d_in[12]; const float* a_src1 = (const float*)d_in[13];
    const float* a_dst1 = (const float*)d_in[14]; const float* bg1    = (const float*)d_in[15];
    const float* Wg2    = (const float*)d_in[16]; const float* a_src2 = (const float*)d_in[17];
    const float* a_dst2 = (const float*)d_in[18]; const float* bg2    = (const float*)d_in[19];
    const float* Wqkv   = (const float*)d_in[20]; const float* bqkv   = (const float*)d_in[21];
    const float* Wo     = (const float*)d_in[22]; const float* bo     = (const float*)d_in[23];

    float* out = (float*)d_out;

    char* base = (char*)d_ws;
    size_t off = 0;
    auto alloc = [&](size_t nb) -> char* {
        char* p = base + off;
        off = (off + nb + 255) & ~(size_t)255;
        return p;
    };

    // bufA and bufB MUST be adjacent: Sb (32MB) spans both during attention.
    float*          bufA  = (float*)alloc((size_t)NN_ * 512 * 4);
    float*          bufB  = (float*)alloc((size_t)NN_ * 512 * 4);
    float*          bufC  = (float*)alloc((size_t)NN_ * 512 * 4);
    float*          as_   = (float*)alloc(NN_ * 4);
    float*          ad_   = (float*)alloc(NN_ * 4);
    // mkey..cdn contiguous: one initial memset covers all five
    unsigned*       mkey  = (unsigned*)alloc(NN_ * 4);
    float*          denom = (float*)alloc(NN_ * 4);
    int*            deg   = (int*)alloc(NN_ * 4);
    int*            cursor= (int*)alloc(NN_ * 4);
    float*          cdn   = (float*)alloc(NN_ * 4);    // per-chunk attn denoms
    int*            rowst = (int*)alloc((NN_ + 1) * 4);
    float*          evals = (float*)alloc((size_t)NE_ * 4);
    int*            csrs  = (int*)alloc((size_t)NE_ * 4);   // src per CSR slot
    int*            pos   = (int*)alloc((size_t)NE_ * 4);   // edge -> CSR slot
    float*          evs   = (float*)alloc((size_t)NE_ * 4); // exp in CSR order
    unsigned short* xbA   = (unsigned short*)alloc((size_t)NA_ * 256 * 2);
    unsigned short* xbB   = (unsigned short*)alloc((size_t)NB_ * 256 * 2);
    unsigned short* WbinA = (unsigned short*)alloc((size_t)512 * 256 * 2);
    unsigned short* WbinB = (unsigned short*)alloc((size_t)512 * 256 * 2);
    unsigned short* Wbin2A= (unsigned short*)alloc((size_t)512 * 256 * 2);
    unsigned short* Wbin2B= (unsigned short*)alloc((size_t)512 * 256 * 2);
    unsigned short* Wbqkv = (unsigned short*)alloc((size_t)1536 * 512 * 2);
    unsigned short* Wbo   = (unsigned short*)alloc((size_t)512 * 512 * 2);
    unsigned short* Wg1hi = (unsigned short*)alloc((size_t)512 * 512 * 2);
    unsigned short* Wg1lo = (unsigned short*)alloc((size_t)512 * 512 * 2);
    unsigned short* Wg2hi = (unsigned short*)alloc((size_t)512 * 512 * 2);
    unsigned short* Wg2lo = (unsigned short*)alloc((size_t)512 * 512 * 2);
    unsigned short* qb    = (unsigned short*)alloc((size_t)NN_ * 512 * 2);
    unsigned short* kb    = (unsigned short*)alloc((size_t)NN_ * 512 * 2);
    unsigned short* vT    = (unsigned short*)alloc((size_t)512 * NN_ * 2);
    unsigned short* ab    = (unsigned short*)alloc((size_t)NN_ * 512 * 2);

    // overlays
    unsigned short* hb = vT;                              // bf16 h (local branch)
    unsigned short* gb = (unsigned short*)bufC;           // g bf16 (global, pre-loop)
    unsigned short* vb = gb + (size_t)NN_ * 512;          // v bf16 (global, pre-loop)
    unsigned short* Sb = (unsigned short*)bufA;           // scores: bufA+bufB = 32MB
    unsigned short* pv = (unsigned short*)bufC;           // PV bf16 partials (16MB)

    const int R = 2048, SEGS = 8, KSEG = 8192 / SEGS;
    const int EG = (NE_ + 255) / 256;
    const float scale = 0.044194173824159216f;  // 1/sqrt(512)

    // -------- all weight/input casts in ONE launch --------------------------
    CvtJobs jobs;
    jobs.j[0] = { x_A,    xbA,    nullptr, NA_ * 256 / 4 };
    jobs.j[1] = { x_B,    xbB,    nullptr, NB_ * 256 / 4 };
    jobs.j[2] = { W_inA,  WbinA,  nullptr, 512 * 256 / 4 };
    jobs.j[3] = { W_inB,  WbinB,  nullptr, 512 * 256 / 4 };
    jobs.j[4] = { W_in2A, Wbin2A, nullptr, 512 * 256 / 4 };
    jobs.j[5] = { W_in2B, Wbin2B, nullptr, 512 * 256 / 4 };
    jobs.j[6] = { Wqkv,   Wbqkv,  nullptr, 1536 * 512 / 4 };
    jobs.j[7] = { Wo,     Wbo,    nullptr, 512 * 512 / 4 };
    jobs.j[8] = { Wg1,    Wg1hi,  Wg1lo,   512 * 512 / 4 };
    jobs.j[9] = { Wg2,    Wg2hi,  Wg2lo,   512 * 512 / 4 };
    cvt_all_k<<<dim3(NA_ * 256 / 4 / 256, 10), 256, 0, stream>>>(jobs);

    // zero mkey, denom, deg, cursor, cdn in one shot
    hipMemsetAsync(mkey, 0, (size_t)NN_ * 4 * 5, stream);

    // -------- CSR build -----------------------------------------------------
    count_deg_k<<<EG, 256, 0, stream>>>(eAB, eBA, deg);
    scan_k<<<1, 256, 0, stream>>>(deg, rowst);
    fill_csr_k<<<EG, 256, 0, stream>>>(eAB, eBA, rowst, cursor, csrs, pos);

    // -------- local branch --------------------------------------------------
    mgemm_in_k<true><<<dim3(4, 64), 256, 0, stream>>>(
        xbA, xbB, WbinA, WbinB, b_inA, b_inB, qb, kb);
    mgemm3_k<<<dim3(4, 64), 256, 0, stream>>>(qb, kb, Wg1hi, Wg1lo,
                                              bufB, hb, 512, 512, 512, 512);
    node_dots_k<<<NN_/4, 256, 0, stream>>>(bufB, a_src1, a_dst1, as_, ad_);
    edge_pass1_k<<<EG, 256, 0, stream>>>(eAB, eBA, as_, ad_, evals, mkey);
    edge_pass2_k<<<EG, 256, 0, stream>>>(eAB, eBA, mkey, evals, pos, evs, denom);
    gat_agg_k<true><<<NN_/4, 256, 0, stream>>>(rowst, csrs, evs, denom,
                                               hb, bg1, nullptr, 0, qb, kb, 0);
    gat_agg_k<true><<<NN_/4, 256, 0, stream>>>(rowst, csrs, evs, denom,
                                               hb, bg1, nullptr, 0, qb, kb, 1);
    mgemm3_k<<<dim3(4, 64), 256, 0, stream>>>(qb, kb, Wg2hi, Wg2lo,
                                              bufB, hb, 512, 512, 512, 512);
    node_dots_k<<<NN_/4, 256, 0, stream>>>(bufB, a_src2, a_dst2, as_, ad_);
    hipMemsetAsync(mkey, 0, NN_ * 8, stream);           // mkey + denom
    edge_pass1_k<<<EG, 256, 0, stream>>>(eAB, eBA, as_, ad_, evals, mkey);
    edge_pass2_k<<<EG, 256, 0, stream>>>(eAB, eBA, mkey, evals, pos, evs, denom);
    // layer-2 aggregation writes the local half of d_out directly (ldo=1024)
    gat_agg_k<false><<<NN_/4, 256, 0, stream>>>(rowst, csrs, evs, denom,
                                                hb, bg2, out, 1024, nullptr, nullptr, 0);
    gat_agg_k<false><<<NN_/4, 256, 0, stream>>>(rowst, csrs, evs, denom,
                                                hb, bg2, out, 1024, nullptr, nullptr, 1);

    // -------- global branch -------------------------------------------------
    mgemm_in_k<false><<<dim3(4, 64), 256, 0, stream>>>(
        xbA, xbB, Wbin2A, Wbin2B, b_in2A, b_in2B, gb, nullptr);
    mgemm_qkv_k<<<dim3(12, 64), 256, 0, stream>>>(gb, Wbqkv, bqkv, scale, qb, kb, vb);
    trT_k<<<dim3(8, 128), 256, 0, stream>>>(vb, vT);
    for (int c0 = 0; c0 < 8192; c0 += R) {
        float* dn = cdn + c0;   // this chunk's 2048 denominators (pre-zeroed)
        mgemm_qk_k<<<dim3(64, R/128), 256, 0, stream>>>(
            qb + (size_t)c0 * 512, kb, Sb, dn);
        mgemm_pv_k<<<dim3(4, R/128, SEGS), 256, 0, stream>>>(
            Sb, vT, pv, KSEG, (size_t)R * 512);
        radd_k<<<(R*512/8 + 255)/256, 256, 0, stream>>>(
            pv, ab + (size_t)c0 * 512, dn, R*512/8, SEGS, (size_t)R*512/8);
    }
    // Wo GEMM writes the global half of d_out directly (ldc=1024, col offset 512)
    mgemm_k<128,128,true,float><<<dim3(4, 64), 256, 0, stream>>>(
        ab, Wbo, bo, out + 512, 512, 512, 512, 1024);
}

// Round 12
// 651.290 us; speedup vs baseline: 1.0790x; 1.0790x over previous
//
#include <hip/hip_runtime.h>
#include <hip/hip_bf16.h>

#define NA_ 4096
#define NB_ 4096
#define NN_ 8192            // total nodes
#define EE_ 131072          // edges per direction
#define NE_ (2*EE_ + NN_)   // homogeneous edges incl. self loops = 270336
#define HH_ 512
#define NEG_SLOPE_ 0.2f

typedef __attribute__((ext_vector_type(4))) float f32x4;
typedef __attribute__((ext_vector_type(8))) short s16x8;

__device__ inline unsigned short f2bf(float v) {
    __hip_bfloat16 h = __float2bfloat16(v);
    return __builtin_bit_cast(unsigned short, h);
}
__device__ inline float bf2f(unsigned short u) {
    return __uint_as_float(((unsigned)u) << 16);
}

// ---------------- float-order <-> unsigned-order mapping for atomic max ----
__device__ inline unsigned fkey(float f) {
    unsigned b = __float_as_uint(f);
    return (b & 0x80000000u) ? ~b : (b | 0x80000000u);
}
__device__ inline float finv(unsigned k) {
    return (k & 0x80000000u) ? __uint_as_float(k & 0x7fffffffu)
                             : __uint_as_float(~k);
}

// ---------------- homogeneous edge id -> (src, dst) ------------------------
__device__ inline void edge_sd(int i, const int* __restrict__ eAB,
                               const int* __restrict__ eBA, int& s, int& d) {
    if (i < EE_)            { s = eAB[i];            d = eAB[EE_ + i] + NA_; }
    else if (i < 2 * EE_)   { int j = i - EE_; s = eBA[j] + NA_; d = eBA[EE_ + j]; }
    else                    { s = i - 2 * EE_;       d = s; }
}

// ---------------- batched f32 -> bf16 (optionally split hi/lo) casts --------
struct CvtJob { const float* s; unsigned short* hi; unsigned short* lo; int n4; };
struct CvtJobs { CvtJob j[10]; };

__global__ __launch_bounds__(256) void cvt_all_k(CvtJobs jobs) {
    const CvtJob jb = jobs.j[blockIdx.y];
    int i = blockIdx.x * 256 + threadIdx.x;
    if (i >= jb.n4) return;
    float4 v = ((const float4*)jb.s)[i];
    ushort4 h;
    h.x = f2bf(v.x); h.y = f2bf(v.y); h.z = f2bf(v.z); h.w = f2bf(v.w);
    ((ushort4*)jb.hi)[i] = h;
    if (jb.lo) {
        ushort4 l;
        l.x = f2bf(v.x - bf2f(h.x));
        l.y = f2bf(v.y - bf2f(h.y));
        l.z = f2bf(v.z - bf2f(h.z));
        l.w = f2bf(v.w - bf2f(h.w));
        ((ushort4*)jb.lo)[i] = l;
    }
}

// ---------------- MFMA bf16 GEMM: C[M,N] = A @ B^T (+bias) -----------------
template<int BM, int BN, bool BIAS, typename OutT>
__global__ __launch_bounds__(256) void mgemm_k(
    const unsigned short* __restrict__ A, const unsigned short* __restrict__ B,
    const float* __restrict__ bias, OutT* __restrict__ C,
    int K, int lda, int ldb, int ldc)
{
    constexpr int BK = 32;
    constexpr int WM = BM / 2, WN = BN / 2;
    constexpr int AM = WM / 16, AN = WN / 16;
    constexpr int AISS = BM * 4 / 256, BISS = BN * 4 / 256;
    __shared__ unsigned short sA[BM * BK];
    __shared__ unsigned short sB[BN * BK];
    const int t = threadIdx.x, lane = t & 63, w = t >> 6;
    const int wr = w >> 1, wc = w & 1;
    const int fr = lane & 15, fq = lane >> 4;
    const int bm = blockIdx.y * BM, bn = blockIdx.x * BN;

    f32x4 acc[AM][AN];
    #pragma unroll
    for (int m = 0; m < AM; m++)
        #pragma unroll
        for (int n = 0; n < AN; n++)
            #pragma unroll
            for (int r = 0; r < 4; r++) acc[m][n][r] = 0.f;

    for (int k0 = 0; k0 < K; k0 += BK) {
        __syncthreads();
        #pragma unroll
        for (int i = 0; i < AISS; i++) {
            int slot = i * 256 + t;
            __builtin_amdgcn_global_load_lds(
                (const __attribute__((address_space(1))) unsigned int*)
                    (A + (size_t)(bm + (slot >> 2)) * lda + k0 + (slot & 3) * 8),
                (__attribute__((address_space(3))) unsigned int*)
                    (sA + (i * 256 + w * 64) * 8), 16, 0, 0);
        }
        #pragma unroll
        for (int i = 0; i < BISS; i++) {
            int slot = i * 256 + t;
            __builtin_amdgcn_global_load_lds(
                (const __attribute__((address_space(1))) unsigned int*)
                    (B + (size_t)(bn + (slot >> 2)) * ldb + k0 + (slot & 3) * 8),
                (__attribute__((address_space(3))) unsigned int*)
                    (sB + (i * 256 + w * 64) * 8), 16, 0, 0);
        }
        __syncthreads();
        s16x8 a[AM], b[AN];
        #pragma unroll
        for (int m = 0; m < AM; m++)
            a[m] = *(const s16x8*)&sA[(wr * WM + m * 16 + fr) * BK + fq * 8];
        #pragma unroll
        for (int n = 0; n < AN; n++)
            b[n] = *(const s16x8*)&sB[(wc * WN + n * 16 + fr) * BK + fq * 8];
        #pragma unroll
        for (int m = 0; m < AM; m++)
            #pragma unroll
            for (int n = 0; n < AN; n++)
                acc[m][n] = __builtin_amdgcn_mfma_f32_16x16x32_bf16(a[m], b[n], acc[m][n], 0, 0, 0);
    }

    // C/D layout: col = lane&15, row = (lane>>4)*4 + reg
    #pragma unroll
    for (int m = 0; m < AM; m++) {
        const int row = bm + wr * WM + m * 16 + fq * 4;
        #pragma unroll
        for (int n = 0; n < AN; n++) {
            const int col = bn + wc * WN + n * 16 + fr;
            const float bv = BIAS ? bias[col] : 0.f;
            #pragma unroll
            for (int r = 0; r < 4; r++) {
                float v = acc[m][n][r] + bv;
                if constexpr (sizeof(OutT) == 2)
                    C[(size_t)(row + r) * ldc + col] = (OutT)f2bf(v);
                else
                    C[(size_t)(row + r) * ldc + col] = v;
            }
        }
    }
}

// ---------------- QK^T MFMA GEMM (BK=64) + fused exp2 + row-sum ------------
// q pre-scaled by scale*log2e -> P = 2^(q.k); denom[row] += row-sum (atomic).
__global__ __launch_bounds__(256) void mgemm_qk_k(
    const unsigned short* __restrict__ A, const unsigned short* __restrict__ B,
    unsigned short* __restrict__ C, float* __restrict__ denom)
{
    constexpr int BK = 64;
    __shared__ unsigned short sA[128 * BK];
    __shared__ unsigned short sB[128 * BK];
    const int t = threadIdx.x, lane = t & 63, w = t >> 6;
    const int wr = w >> 1, wc = w & 1;
    const int fr = lane & 15, fq = lane >> 4;
    const int bm = blockIdx.y * 128, bn = blockIdx.x * 128;

    f32x4 acc[4][4];
    #pragma unroll
    for (int m = 0; m < 4; m++)
        #pragma unroll
        for (int n = 0; n < 4; n++)
            #pragma unroll
            for (int r = 0; r < 4; r++) acc[m][n][r] = 0.f;

    for (int k0 = 0; k0 < 512; k0 += BK) {
        __syncthreads();
        #pragma unroll
        for (int i = 0; i < 4; i++) {
            int slot = i * 256 + t;           // row = slot>>3, col-chunk = slot&7
            __builtin_amdgcn_global_load_lds(
                (const __attribute__((address_space(1))) unsigned int*)
                    (A + (size_t)(bm + (slot >> 3)) * 512 + k0 + (slot & 7) * 8),
                (__attribute__((address_space(3))) unsigned int*)
                    (sA + (i * 256 + w * 64) * 8), 16, 0, 0);
            __builtin_amdgcn_global_load_lds(
                (const __attribute__((address_space(1))) unsigned int*)
                    (B + (size_t)(bn + (slot >> 3)) * 512 + k0 + (slot & 7) * 8),
                (__attribute__((address_space(3))) unsigned int*)
                    (sB + (i * 256 + w * 64) * 8), 16, 0, 0);
        }
        __syncthreads();
        s16x8 a[4][2], b[4][2];
        #pragma unroll
        for (int m = 0; m < 4; m++)
            #pragma unroll
            for (int kk = 0; kk < 2; kk++)
                a[m][kk] = *(const s16x8*)&sA[(wr * 64 + m * 16 + fr) * BK + kk * 32 + fq * 8];
        #pragma unroll
        for (int n = 0; n < 4; n++)
            #pragma unroll
            for (int kk = 0; kk < 2; kk++)
                b[n][kk] = *(const s16x8*)&sB[(wc * 64 + n * 16 + fr) * BK + kk * 32 + fq * 8];
        #pragma unroll
        for (int m = 0; m < 4; m++)
            #pragma unroll
            for (int n = 0; n < 4; n++) {
                acc[m][n] = __builtin_amdgcn_mfma_f32_16x16x32_bf16(a[m][0], b[n][0], acc[m][n], 0, 0, 0);
                acc[m][n] = __builtin_amdgcn_mfma_f32_16x16x32_bf16(a[m][1], b[n][1], acc[m][n], 0, 0, 0);
            }
    }

    #pragma unroll
    for (int m = 0; m < 4; m++) {
        const int row = bm + wr * 64 + m * 16 + fq * 4;
        #pragma unroll
        for (int r = 0; r < 4; r++) {
            float rsum = 0.f;
            #pragma unroll
            for (int n = 0; n < 4; n++) {
                const int col = bn + wc * 64 + n * 16 + fr;
                float p = exp2f(acc[m][n][r]);
                rsum += p;
                C[(size_t)(row + r) * 8192 + col] = f2bf(p);
            }
            rsum += __shfl_xor(rsum, 1);
            rsum += __shfl_xor(rsum, 2);
            rsum += __shfl_xor(rsum, 4);
            rsum += __shfl_xor(rsum, 8);
            if (fr == 0) atomicAdd(&denom[row + r], rsum);
        }
    }
}

// ---------------- merged per-type input linear (A rows 0..4095, B rows 4096+)
template<bool SPLIT>
__global__ __launch_bounds__(256) void mgemm_in_k(
    const unsigned short* __restrict__ xA, const unsigned short* __restrict__ xB,
    const unsigned short* __restrict__ WA, const unsigned short* __restrict__ WB,
    const float* __restrict__ biasA, const float* __restrict__ biasB,
    unsigned short* __restrict__ o1, unsigned short* __restrict__ o2)
{
    constexpr int BK = 32;
    __shared__ unsigned short sA[128 * BK];
    __shared__ unsigned short sB[128 * BK];
    const int t = threadIdx.x, lane = t & 63, w = t >> 6;
    const int wr = w >> 1, wc = w & 1;
    const int fr = lane & 15, fq = lane >> 4;
    const int bm = blockIdx.y * 128, bn = blockIdx.x * 128;
    const bool isB = bm >= NA_;
    const unsigned short* A = isB ? xB : xA;
    const unsigned short* W = isB ? WB : WA;
    const float* bias = isB ? biasB : biasA;
    const int bml = bm - (isB ? NA_ : 0);

    f32x4 acc[4][4];
    #pragma unroll
    for (int m = 0; m < 4; m++)
        #pragma unroll
        for (int n = 0; n < 4; n++)
            #pragma unroll
            for (int r = 0; r < 4; r++) acc[m][n][r] = 0.f;

    for (int k0 = 0; k0 < 256; k0 += BK) {
        __syncthreads();
        #pragma unroll
        for (int i = 0; i < 2; i++) {
            int slot = i * 256 + t;
            __builtin_amdgcn_global_load_lds(
                (const __attribute__((address_space(1))) unsigned int*)
                    (A + (size_t)(bml + (slot >> 2)) * 256 + k0 + (slot & 3) * 8),
                (__attribute__((address_space(3))) unsigned int*)
                    (sA + (i * 256 + w * 64) * 8), 16, 0, 0);
            __builtin_amdgcn_global_load_lds(
                (const __attribute__((address_space(1))) unsigned int*)
                    (W + (size_t)(bn + (slot >> 2)) * 256 + k0 + (slot & 3) * 8),
                (__attribute__((address_space(3))) unsigned int*)
                    (sB + (i * 256 + w * 64) * 8), 16, 0, 0);
        }
        __syncthreads();
        s16x8 a[4], b[4];
        #pragma unroll
        for (int m = 0; m < 4; m++)
            a[m] = *(const s16x8*)&sA[(wr * 64 + m * 16 + fr) * BK + fq * 8];
        #pragma unroll
        for (int n = 0; n < 4; n++)
            b[n] = *(const s16x8*)&sB[(wc * 64 + n * 16 + fr) * BK + fq * 8];
        #pragma unroll
        for (int m = 0; m < 4; m++)
            #pragma unroll
            for (int n = 0; n < 4; n++)
                acc[m][n] = __builtin_amdgcn_mfma_f32_16x16x32_bf16(a[m], b[n], acc[m][n], 0, 0, 0);
    }

    #pragma unroll
    for (int m = 0; m < 4; m++) {
        const int row = bm + wr * 64 + m * 16 + fq * 4;
        #pragma unroll
        for (int n = 0; n < 4; n++) {
            const int col = bn + wc * 64 + n * 16 + fr;
            const float bv = bias[col];
            #pragma unroll
            for (int r = 0; r < 4; r++) {
                float v = acc[m][n][r] + bv;
                unsigned short hi = f2bf(v);
                o1[(size_t)(row + r) * 512 + col] = hi;
                if (SPLIT)
                    o2[(size_t)(row + r) * 512 + col] = f2bf(v - bf2f(hi));
            }
        }
    }
}

// ---------------- split-precision MFMA GEMM (~f32 accuracy) ----------------
__global__ __launch_bounds__(256) void mgemm3_k(
    const unsigned short* __restrict__ Ahi, const unsigned short* __restrict__ Alo,
    const unsigned short* __restrict__ Bhi, const unsigned short* __restrict__ Blo,
    float* __restrict__ C, unsigned short* __restrict__ Cb,
    int K, int lda, int ldb, int ldc)
{
    constexpr int BM = 128, BN = 128, BK = 32;
    __shared__ unsigned short sAh[BM * BK], sAl[BM * BK];
    __shared__ unsigned short sBh[BN * BK], sBl[BN * BK];
    const int t = threadIdx.x, lane = t & 63, w = t >> 6;
    const int wr = w >> 1, wc = w & 1;
    const int fr = lane & 15, fq = lane >> 4;
    const int bm = blockIdx.y * BM, bn = blockIdx.x * BN;

    f32x4 acc[4][4];
    #pragma unroll
    for (int m = 0; m < 4; m++)
        #pragma unroll
        for (int n = 0; n < 4; n++)
            #pragma unroll
            for (int r = 0; r < 4; r++) acc[m][n][r] = 0.f;

    for (int k0 = 0; k0 < K; k0 += BK) {
        __syncthreads();
        #pragma unroll
        for (int i = 0; i < 2; i++) {
            int slot = i * 256 + t;
            size_t ga = (size_t)(bm + (slot >> 2)) * lda + k0 + (slot & 3) * 8;
            size_t gb = (size_t)(bn + (slot >> 2)) * ldb + k0 + (slot & 3) * 8;
            unsigned loff = (unsigned)(i * 256 + w * 64) * 8;
            __builtin_amdgcn_global_load_lds(
                (const __attribute__((address_space(1))) unsigned int*)(Ahi + ga),
                (__attribute__((address_space(3))) unsigned int*)(sAh + loff), 16, 0, 0);
            __builtin_amdgcn_global_load_lds(
                (const __attribute__((address_space(1))) unsigned int*)(Alo + ga),
                (__attribute__((address_space(3))) unsigned int*)(sAl + loff), 16, 0, 0);
            __builtin_amdgcn_global_load_lds(
                (const __attribute__((address_space(1))) unsigned int*)(Bhi + gb),
                (__attribute__((address_space(3))) unsigned int*)(sBh + loff), 16, 0, 0);
            __builtin_amdgcn_global_load_lds(
                (const __attribute__((address_space(1))) unsigned int*)(Blo + gb),
                (__attribute__((address_space(3))) unsigned int*)(sBl + loff), 16, 0, 0);
        }
        __syncthreads();
        s16x8 ah[4], al[4], bh[4], bl[4];
        #pragma unroll
        for (int m = 0; m < 4; m++) {
            int o = (wr * 64 + m * 16 + fr) * BK + fq * 8;
            ah[m] = *(const s16x8*)&sAh[o];
            al[m] = *(const s16x8*)&sAl[o];
        }
        #pragma unroll
        for (int n = 0; n < 4; n++) {
            int o = (wc * 64 + n * 16 + fr) * BK + fq * 8;
            bh[n] = *(const s16x8*)&sBh[o];
            bl[n] = *(const s16x8*)&sBl[o];
        }
        #pragma unroll
        for (int m = 0; m < 4; m++)
            #pragma unroll
            for (int n = 0; n < 4; n++) {
                acc[m][n] = __builtin_amdgcn_mfma_f32_16x16x32_bf16(ah[m], bh[n], acc[m][n], 0, 0, 0);
                acc[m][n] = __builtin_amdgcn_mfma_f32_16x16x32_bf16(ah[m], bl[n], acc[m][n], 0, 0, 0);
                acc[m][n] = __builtin_amdgcn_mfma_f32_16x16x32_bf16(al[m], bh[n], acc[m][n], 0, 0, 0);
            }
    }

    #pragma unroll
    for (int m = 0; m < 4; m++) {
        const int row = bm + wr * 64 + m * 16 + fq * 4;
        #pragma unroll
        for (int n = 0; n < 4; n++) {
            const int col = bn + wc * 64 + n * 16 + fr;
            #pragma unroll
            for (int r = 0; r < 4; r++) {
                float v = acc[m][n][r];
                C[(size_t)(row + r) * ldc + col]  = v;
                Cb[(size_t)(row + r) * 512 + col] = f2bf(v);
            }
        }
    }
}

// ---------------- PV split-K MFMA GEMM (BK=64, bf16 partials, XCD swizzle) --
__global__ __launch_bounds__(256) void mgemm_pv_k(
    const unsigned short* __restrict__ A, const unsigned short* __restrict__ B,
    unsigned short* __restrict__ C, int kseg, size_t segstride)
{
    constexpr int BK = 64;
    __shared__ unsigned short sA[128 * BK];
    __shared__ unsigned short sB[128 * BK];
    const int t = threadIdx.x, lane = t & 63, w = t >> 6;
    const int wr = w >> 1, wc = w & 1;
    const int fr = lane & 15, fq = lane >> 4;
    const int L  = blockIdx.x + (blockIdx.y << 2) + (blockIdx.z << 6);
    const int xs = L >> 7;
    const int ys = (L & 127) & 15;
    const int zs = (L & 127) >> 4;
    const int bm = ys * 128, bn = xs * 128;
    const int kofs = zs * kseg;

    f32x4 acc[4][4];
    #pragma unroll
    for (int m = 0; m < 4; m++)
        #pragma unroll
        for (int n = 0; n < 4; n++)
            #pragma unroll
            for (int r = 0; r < 4; r++) acc[m][n][r] = 0.f;

    for (int k0 = 0; k0 < kseg; k0 += BK) {
        __syncthreads();
        #pragma unroll
        for (int i = 0; i < 4; i++) {
            int slot = i * 256 + t;           // row = slot>>3, col-chunk = slot&7
            __builtin_amdgcn_global_load_lds(
                (const __attribute__((address_space(1))) unsigned int*)
                    (A + (size_t)(bm + (slot >> 3)) * 8192 + kofs + k0 + (slot & 7) * 8),
                (__attribute__((address_space(3))) unsigned int*)
                    (sA + (i * 256 + w * 64) * 8), 16, 0, 0);
            __builtin_amdgcn_global_load_lds(
                (const __attribute__((address_space(1))) unsigned int*)
                    (B + (size_t)(bn + (slot >> 3)) * 8192 + kofs + k0 + (slot & 7) * 8),
                (__attribute__((address_space(3))) unsigned int*)
                    (sB + (i * 256 + w * 64) * 8), 16, 0, 0);
        }
        __syncthreads();
        s16x8 a[4][2], b[4][2];
        #pragma unroll
        for (int m = 0; m < 4; m++)
            #pragma unroll
            for (int kk = 0; kk < 2; kk++)
                a[m][kk] = *(const s16x8*)&sA[(wr * 64 + m * 16 + fr) * BK + kk * 32 + fq * 8];
        #pragma unroll
        for (int n = 0; n < 4; n++)
            #pragma unroll
            for (int kk = 0; kk < 2; kk++)
                b[n][kk] = *(const s16x8*)&sB[(wc * 64 + n * 16 + fr) * BK + kk * 32 + fq * 8];
        #pragma unroll
        for (int m = 0; m < 4; m++)
            #pragma unroll
            for (int n = 0; n < 4; n++) {
                acc[m][n] = __builtin_amdgcn_mfma_f32_16x16x32_bf16(a[m][0], b[n][0], acc[m][n], 0, 0, 0);
                acc[m][n] = __builtin_amdgcn_mfma_f32_16x16x32_bf16(a[m][1], b[n][1], acc[m][n], 0, 0, 0);
            }
    }

    unsigned short* Cz = C + (size_t)zs * segstride;
    #pragma unroll
    for (int m = 0; m < 4; m++) {
        const int row = bm + wr * 64 + m * 16 + fq * 4;
        #pragma unroll
        for (int n = 0; n < 4; n++) {
            const int col = bn + wc * 64 + n * 16 + fr;
            #pragma unroll
            for (int r = 0; r < 4; r++)
                Cz[(size_t)(row + r) * 512 + col] = f2bf(acc[m][n][r]);
        }
    }
}

// ---------------- reduce bf16 split-K partials, divide by denom -> bf16 ----
__global__ __launch_bounds__(256) void radd_k(const unsigned short* __restrict__ src,
                                              unsigned short* __restrict__ dst,
                                              const float* __restrict__ dn,
                                              int n8, int segs, size_t stride8) {
    int i = blockIdx.x * 256 + threadIdx.x;
    if (i >= n8) return;
    float acc[8] = {0,0,0,0,0,0,0,0};
    for (int s = 0; s < segs; s++) {
        s16x8 v = ((const s16x8*)src)[i + s * stride8];
        #pragma unroll
        for (int j = 0; j < 8; j++) acc[j] += bf2f((unsigned short)v[j]);
    }
    const float rd = 1.0f / dn[i >> 6];    // 64 groups of 8 per 512-col row
    s16x8 o;
    #pragma unroll
    for (int j = 0; j < 8; j++) o[j] = (short)f2bf(acc[j] * rd);
    ((s16x8*)dst)[i] = o;
}

// ---------------- qkv MFMA GEMM with split epilogue (scale folded into q) ---
__global__ __launch_bounds__(256) void mgemm_qkv_k(
    const unsigned short* __restrict__ A, const unsigned short* __restrict__ B,
    const float* __restrict__ bias, float scale,
    unsigned short* __restrict__ qb, unsigned short* __restrict__ kb,
    unsigned short* __restrict__ vb)
{
    constexpr int BM = 128, BN = 128, BK = 32;
    __shared__ unsigned short sA[BM * BK];
    __shared__ unsigned short sB[BN * BK];
    const int t = threadIdx.x, lane = t & 63, w = t >> 6;
    const int wr = w >> 1, wc = w & 1;
    const int fr = lane & 15, fq = lane >> 4;
    const int bm = blockIdx.y * BM, bn = blockIdx.x * BN;

    f32x4 acc[4][4];
    #pragma unroll
    for (int m = 0; m < 4; m++)
        #pragma unroll
        for (int n = 0; n < 4; n++)
            #pragma unroll
            for (int r = 0; r < 4; r++) acc[m][n][r] = 0.f;

    for (int k0 = 0; k0 < 512; k0 += BK) {
        __syncthreads();
        #pragma unroll
        for (int i = 0; i < 2; i++) {
            int slot = i * 256 + t;
            __builtin_amdgcn_global_load_lds(
                (const __attribute__((address_space(1))) unsigned int*)
                    (A + (size_t)(bm + (slot >> 2)) * 512 + k0 + (slot & 3) * 8),
                (__attribute__((address_space(3))) unsigned int*)
                    (sA + (i * 256 + w * 64) * 8), 16, 0, 0);
            __builtin_amdgcn_global_load_lds(
                (const __attribute__((address_space(1))) unsigned int*)
                    (B + (size_t)(bn + (slot >> 2)) * 512 + k0 + (slot & 3) * 8),
                (__attribute__((address_space(3))) unsigned int*)
                    (sB + (i * 256 + w * 64) * 8), 16, 0, 0);
        }
        __syncthreads();
        s16x8 a[4], b[4];
        #pragma unroll
        for (int m = 0; m < 4; m++)
            a[m] = *(const s16x8*)&sA[(wr * 64 + m * 16 + fr) * BK + fq * 8];
        #pragma unroll
        for (int n = 0; n < 4; n++)
            b[n] = *(const s16x8*)&sB[(wc * 64 + n * 16 + fr) * BK + fq * 8];
        #pragma unroll
        for (int m = 0; m < 4; m++)
            #pragma unroll
            for (int n = 0; n < 4; n++)
                acc[m][n] = __builtin_amdgcn_mfma_f32_16x16x32_bf16(a[m], b[n], acc[m][n], 0, 0, 0);
    }

    #pragma unroll
    for (int m = 0; m < 4; m++) {
        const int row = bm + wr * 64 + m * 16 + fq * 4;
        #pragma unroll
        for (int n = 0; n < 4; n++) {
            const int col = bn + wc * 64 + n * 16 + fr;
            const float bv = bias[col];
            #pragma unroll
            for (int r = 0; r < 4; r++) {
                float v = acc[m][n][r] + bv;
                if (col < 512)
                    qb[(size_t)(row + r) * 512 + col] = f2bf(v * scale);
                else if (col < 1024)
                    kb[(size_t)(row + r) * 512 + (col - 512)] = f2bf(v);
                else
                    vb[(size_t)(row + r) * 512 + (col - 1024)] = f2bf(v);
            }
        }
    }
}

// ---------------- bf16 transpose: vb[8192][512] -> vT[512][8192] ------------
__global__ __launch_bounds__(256) void trT_k(const unsigned short* __restrict__ vb,
                                             unsigned short* __restrict__ vT) {
    __shared__ unsigned short s[64][65];
    const int t = threadIdx.x;
    const int rowo = blockIdx.y * 64;
    const int colo = blockIdx.x * 64;
    {
        int r = t >> 2, cg = (t & 3) * 16;
        const s16x8* src = (const s16x8*)(vb + (size_t)(rowo + r) * 512 + colo + cg);
        s16x8 u0 = src[0], u1 = src[1];
        #pragma unroll
        for (int j = 0; j < 8; j++) {
            s[r][cg + j]     = (unsigned short)u0[j];
            s[r][cg + 8 + j] = (unsigned short)u1[j];
        }
    }
    __syncthreads();
    {
        int c = t >> 2, rg = (t & 3) * 16;
        s16x8 o0, o1;
        #pragma unroll
        for (int j = 0; j < 8; j++) {
            o0[j] = (short)s[rg + j][c];
            o1[j] = (short)s[rg + 8 + j][c];
        }
        s16x8* dst = (s16x8*)(vT + (size_t)(colo + c) * 8192 + rowo + rg);
        dst[0] = o0; dst[1] = o1;
    }
}

// ---------------- per-node attention dots (wave per node) -------------------
__global__ __launch_bounds__(256) void node_dots_k(
    const float* __restrict__ h, const float* __restrict__ a_src,
    const float* __restrict__ a_dst, float* __restrict__ as_, float* __restrict__ ad_)
{
    int wid  = (blockIdx.x * 256 + threadIdx.x) >> 6;
    int lane = threadIdx.x & 63;
    if (wid >= NN_) return;
    const float* hr = h + (size_t)wid * HH_;
    float s1 = 0.f, s2 = 0.f;
    #pragma unroll
    for (int j = 0; j < 8; j++) {
        float v = hr[lane + j*64];
        s1 = fmaf(v, a_src[lane + j*64], s1);
        s2 = fmaf(v, a_dst[lane + j*64], s2);
    }
    #pragma unroll
    for (int off = 32; off; off >>= 1) {
        s1 += __shfl_down(s1, off);
        s2 += __shfl_down(s2, off);
    }
    if (lane == 0) { as_[wid] = s1; ad_[wid] = s2; }
}

// ---------------- CSR build ------------------------------------------------
__global__ void count_deg_k(const int* eAB, const int* eBA, int* deg) {
    int i = blockIdx.x * 256 + threadIdx.x;
    if (i >= NE_) return;
    int s, d; edge_sd(i, eAB, eBA, s, d);
    atomicAdd(&deg[d], 1);
}

__global__ __launch_bounds__(256) void scan_k(const int* __restrict__ deg, int* rowstart) {
    __shared__ int part[256];
    int t = threadIdx.x;
    int base = t * 32;
    int loc[32]; int s = 0;
    #pragma unroll
    for (int j = 0; j < 32; j++) { loc[j] = s; s += deg[base + j]; }
    part[t] = s;
    __syncthreads();
    if (t == 0) {
        int a = 0;
        for (int i = 0; i < 256; i++) { int v = part[i]; part[i] = a; a += v; }
        rowstart[NN_] = a;
    }
    __syncthreads();
    int off = part[t];
    #pragma unroll
    for (int j = 0; j < 32; j++) rowstart[base + j] = off + loc[j];
}

// stores src node per CSR slot + slot index per edge (kills indirection later)
__global__ void fill_csr_k(const int* eAB, const int* eBA,
                           const int* __restrict__ rowstart, int* cursor,
                           int* csr_src, int* pos) {
    int i = blockIdx.x * 256 + threadIdx.x;
    if (i >= NE_) return;
    int s, d; edge_sd(i, eAB, eBA, s, d);
    int p = atomicAdd(&cursor[d], 1);
    int slot = rowstart[d] + p;
    csr_src[slot] = s;
    pos[i] = slot;
}

// ---------------- GAT edge passes ------------------------------------------
__global__ void edge_pass1_k(const int* eAB, const int* eBA,
                             const float* __restrict__ as_, const float* __restrict__ ad_,
                             float* evals, unsigned* mkey) {
    int i = blockIdx.x * 256 + threadIdx.x;
    if (i >= NE_) return;
    int s, d; edge_sd(i, eAB, eBA, s, d);
    float e = as_[s] + ad_[d];
    e = (e >= 0.f) ? e : NEG_SLOPE_ * e;
    evals[i] = e;
    atomicMax(&mkey[d], fkey(e));
}

// scatters exp into CSR order (evs) + accumulates denom
__global__ void edge_pass2_k(const int* eAB, const int* eBA,
                             const unsigned* __restrict__ mkey,
                             const float* __restrict__ evals,
                             const int* __restrict__ pos,
                             float* __restrict__ evs, float* denom) {
    int i = blockIdx.x * 256 + threadIdx.x;
    if (i >= NE_) return;
    int s, d; edge_sd(i, eAB, eBA, s, d);
    float m = finv(mkey[d]);
    float ex = expf(evals[i] - m);
    evs[pos[i]] = ex;
    atomicAdd(&denom[d], ex);
}

// ---------------- GAT aggregation: single pass, streaming CSR ---------------
template<bool SPLIT>
__global__ __launch_bounds__(256) void gat_agg_k(
    const int* __restrict__ rowstart, const int* __restrict__ csr_src,
    const float* __restrict__ evs, const float* __restrict__ denom,
    const unsigned short* __restrict__ hb, const float* __restrict__ bias,
    float* __restrict__ outF, int ldo,
    unsigned short* __restrict__ outHi, unsigned short* __restrict__ outLo)
{
    int wid  = (blockIdx.x * 256 + threadIdx.x) >> 6;
    int lane = threadIdx.x & 63;
    if (wid >= NN_) return;
    float acc[8] = {0.f,0.f,0.f,0.f,0.f,0.f,0.f,0.f};
    int beg = rowstart[wid], end = rowstart[wid + 1];
    float rden = 1.0f / denom[wid];
    for (int p = beg; p < end; p++) {
        int s = csr_src[p];
        float alpha = evs[p] * rden;
        s16x8 hv = *(const s16x8*)(hb + (size_t)s * HH_ + lane * 8);
        #pragma unroll
        for (int j = 0; j < 8; j++)
            acc[j] = fmaf(alpha, bf2f((unsigned short)hv[j]), acc[j]);
    }
    #pragma unroll
    for (int j = 0; j < 8; j++) acc[j] += bias[lane * 8 + j];
    if (SPLIT) {
        s16x8 hi, lo;
        #pragma unroll
        for (int j = 0; j < 8; j++) {
            unsigned short h = f2bf(acc[j]);
            hi[j] = (short)h;
            lo[j] = (short)f2bf(acc[j] - bf2f(h));
        }
        *(s16x8*)(outHi + (size_t)wid * HH_ + lane * 8) = hi;
        *(s16x8*)(outLo + (size_t)wid * HH_ + lane * 8) = lo;
    } else {
        float* o = outF + (size_t)wid * ldo + lane * 8;
        *(float4*)(o)     = make_float4(acc[0], acc[1], acc[2], acc[3]);
        *(float4*)(o + 4) = make_float4(acc[4], acc[5], acc[6], acc[7]);
    }
}

// ===========================================================================
extern "C" void kernel_launch(void* const* d_in, const int* in_sizes, int n_in,
                              void* d_out, int out_size, void* d_ws, size_t ws_size,
                              hipStream_t stream)
{
    const float* x_A    = (const float*)d_in[0];
    const float* x_B    = (const float*)d_in[1];
    const int*   eAB    = (const int*)d_in[2];
    const int*   eBA    = (const int*)d_in[3];
    const float* W_inA  = (const float*)d_in[4];  const float* b_inA  = (const float*)d_in[5];
    const float* W_inB  = (const float*)d_in[6];  const float* b_inB  = (const float*)d_in[7];
    const float* W_in2A = (const float*)d_in[8];  const float* b_in2A = (const float*)d_in[9];
    const float* W_in2B = (const float*)d_in[10]; const float* b_in2B = (const float*)d_in[11];
    const float* Wg1    = (const float*)d_in[12]; const float* a_src1 = (const float*)d_in[13];
    const float* a_dst1 = (const float*)d_in[14]; const float* bg1    = (const float*)d_in[15];
    const float* Wg2    = (const float*)d_in[16]; const float* a_src2 = (const float*)d_in[17];
    const float* a_dst2 = (const float*)d_in[18]; const float* bg2    = (const float*)d_in[19];
    const float* Wqkv   = (const float*)d_in[20]; const float* bqkv   = (const float*)d_in[21];
    const float* Wo     = (const float*)d_in[22]; const float* bo     = (const float*)d_in[23];

    float* out = (float*)d_out;

    char* base = (char*)d_ws;
    size_t off = 0;
    auto alloc = [&](size_t nb) -> char* {
        char* p = base + off;
        off = (off + nb + 255) & ~(size_t)255;
        return p;
    };

    // bufA and bufB MUST be adjacent: Sb (32MB) spans both during attention.
    float*          bufA  = (float*)alloc((size_t)NN_ * 512 * 4);
    float*          bufB  = (float*)alloc((size_t)NN_ * 512 * 4);
    float*          bufC  = (float*)alloc((size_t)NN_ * 512 * 4);
    float*          as_   = (float*)alloc(NN_ * 4);
    float*          ad_   = (float*)alloc(NN_ * 4);
    // mkey..cdn contiguous: one initial memset covers all five
    unsigned*       mkey  = (unsigned*)alloc(NN_ * 4);
    float*          denom = (float*)alloc(NN_ * 4);
    int*            deg   = (int*)alloc(NN_ * 4);
    int*            cursor= (int*)alloc(NN_ * 4);
    float*          cdn   = (float*)alloc(NN_ * 4);    // per-chunk attn denoms
    int*            rowst = (int*)alloc((NN_ + 1) * 4);
    float*          evals = (float*)alloc((size_t)NE_ * 4);
    int*            csrs  = (int*)alloc((size_t)NE_ * 4);   // src per CSR slot
    int*            pos   = (int*)alloc((size_t)NE_ * 4);   // edge -> CSR slot
    float*          evs   = (float*)alloc((size_t)NE_ * 4); // exp in CSR order
    unsigned short* xbA   = (unsigned short*)alloc((size_t)NA_ * 256 * 2);
    unsigned short* xbB   = (unsigned short*)alloc((size_t)NB_ * 256 * 2);
    unsigned short* WbinA = (unsigned short*)alloc((size_t)512 * 256 * 2);
    unsigned short* WbinB = (unsigned short*)alloc((size_t)512 * 256 * 2);
    unsigned short* Wbin2A= (unsigned short*)alloc((size_t)512 * 256 * 2);
    unsigned short* Wbin2B= (unsigned short*)alloc((size_t)512 * 256 * 2);
    unsigned short* Wbqkv = (unsigned short*)alloc((size_t)1536 * 512 * 2);
    unsigned short* Wbo   = (unsigned short*)alloc((size_t)512 * 512 * 2);
    unsigned short* Wg1hi = (unsigned short*)alloc((size_t)512 * 512 * 2);
    unsigned short* Wg1lo = (unsigned short*)alloc((size_t)512 * 512 * 2);
    unsigned short* Wg2hi = (unsigned short*)alloc((size_t)512 * 512 * 2);
    unsigned short* Wg2lo = (unsigned short*)alloc((size_t)512 * 512 * 2);
    unsigned short* qb    = (unsigned short*)alloc((size_t)NN_ * 512 * 2);
    unsigned short* kb    = (unsigned short*)alloc((size_t)NN_ * 512 * 2);
    unsigned short* vT    = (unsigned short*)alloc((size_t)512 * NN_ * 2);
    unsigned short* ab    = (unsigned short*)alloc((size_t)NN_ * 512 * 2);

    // overlays
    unsigned short* hb = vT;                              // bf16 h (local branch)
    unsigned short* gb = (unsigned short*)bufC;           // g bf16 (global, pre-loop)
    unsigned short* vb = gb + (size_t)NN_ * 512;          // v bf16 (global, pre-loop)
    unsigned short* Sb = (unsigned short*)bufA;           // scores: bufA+bufB = 32MB
    unsigned short* pv = (unsigned short*)bufC;           // PV bf16 partials (16MB)

    const int R = 2048, SEGS = 8, KSEG = 8192 / SEGS;
    const int EG = (NE_ + 255) / 256;
    const float scale2 = 0.044194173824159216f * 1.4426950408889634f; // /sqrt(512)*log2e

    // -------- all weight/input casts in ONE launch --------------------------
    CvtJobs jobs;
    jobs.j[0] = { x_A,    xbA,    nullptr, NA_ * 256 / 4 };
    jobs.j[1] = { x_B,    xbB,    nullptr, NB_ * 256 / 4 };
    jobs.j[2] = { W_inA,  WbinA,  nullptr, 512 * 256 / 4 };
    jobs.j[3] = { W_inB,  WbinB,  nullptr, 512 * 256 / 4 };
    jobs.j[4] = { W_in2A, Wbin2A, nullptr, 512 * 256 / 4 };
    jobs.j[5] = { W_in2B, Wbin2B, nullptr, 512 * 256 / 4 };
    jobs.j[6] = { Wqkv,   Wbqkv,  nullptr, 1536 * 512 / 4 };
    jobs.j[7] = { Wo,     Wbo,    nullptr, 512 * 512 / 4 };
    jobs.j[8] = { Wg1,    Wg1hi,  Wg1lo,   512 * 512 / 4 };
    jobs.j[9] = { Wg2,    Wg2hi,  Wg2lo,   512 * 512 / 4 };
    cvt_all_k<<<dim3(NA_ * 256 / 4 / 256, 10), 256, 0, stream>>>(jobs);

    // zero mkey, denom, deg, cursor, cdn in one shot
    hipMemsetAsync(mkey, 0, (size_t)NN_ * 4 * 5, stream);

    // -------- CSR build -----------------------------------------------------
    count_deg_k<<<EG, 256, 0, stream>>>(eAB, eBA, deg);
    scan_k<<<1, 256, 0, stream>>>(deg, rowst);
    fill_csr_k<<<EG, 256, 0, stream>>>(eAB, eBA, rowst, cursor, csrs, pos);

    // -------- local branch --------------------------------------------------
    mgemm_in_k<true><<<dim3(4, 64), 256, 0, stream>>>(
        xbA, xbB, WbinA, WbinB, b_inA, b_inB, qb, kb);
    mgemm3_k<<<dim3(4, 64), 256, 0, stream>>>(qb, kb, Wg1hi, Wg1lo,
                                              bufB, hb, 512, 512, 512, 512);
    node_dots_k<<<NN_/4, 256, 0, stream>>>(bufB, a_src1, a_dst1, as_, ad_);
    edge_pass1_k<<<EG, 256, 0, stream>>>(eAB, eBA, as_, ad_, evals, mkey);
    edge_pass2_k<<<EG, 256, 0, stream>>>(eAB, eBA, mkey, evals, pos, evs, denom);
    gat_agg_k<true><<<NN_/4, 256, 0, stream>>>(rowst, csrs, evs, denom,
                                               hb, bg1, nullptr, 0, qb, kb);
    mgemm3_k<<<dim3(4, 64), 256, 0, stream>>>(qb, kb, Wg2hi, Wg2lo,
                                              bufB, hb, 512, 512, 512, 512);
    node_dots_k<<<NN_/4, 256, 0, stream>>>(bufB, a_src2, a_dst2, as_, ad_);
    hipMemsetAsync(mkey, 0, NN_ * 8, stream);           // mkey + denom
    edge_pass1_k<<<EG, 256, 0, stream>>>(eAB, eBA, as_, ad_, evals, mkey);
    edge_pass2_k<<<EG, 256, 0, stream>>>(eAB, eBA, mkey, evals, pos, evs, denom);
    // layer-2 aggregation writes the local half of d_out directly (ldo=1024)
    gat_agg_k<false><<<NN_/4, 256, 0, stream>>>(rowst, csrs, evs, denom,
                                                hb, bg2, out, 1024, nullptr, nullptr);

    // -------- global branch -------------------------------------------------
    mgemm_in_k<false><<<dim3(4, 64), 256, 0, stream>>>(
        xbA, xbB, Wbin2A, Wbin2B, b_in2A, b_in2B, gb, nullptr);
    mgemm_qkv_k<<<dim3(12, 64), 256, 0, stream>>>(gb, Wbqkv, bqkv, scale2, qb, kb, vb);
    trT_k<<<dim3(8, 128), 256, 0, stream>>>(vb, vT);
    for (int c0 = 0; c0 < 8192; c0 += R) {
        float* dn = cdn + c0;   // this chunk's 2048 denominators (pre-zeroed)
        mgemm_qk_k<<<dim3(64, R/128), 256, 0, stream>>>(
            qb + (size_t)c0 * 512, kb, Sb, dn);
        mgemm_pv_k<<<dim3(4, R/128, SEGS), 256, 0, stream>>>(
            Sb, vT, pv, KSEG, (size_t)R * 512);
        radd_k<<<(R*512/8 + 255)/256, 256, 0, stream>>>(
            pv, ab + (size_t)c0 * 512, dn, R*512/8, SEGS, (size_t)R*512/8);
    }
    // Wo GEMM writes the global half of d_out directly (ldc=1024, col offset 512)
    mgemm_k<128,128,true,float><<<dim3(4, 64), 256, 0, stream>>>(
        ab, Wbo, bo, out + 512, 512, 512, 512, 1024);
}

// Round 13
// 611.405 us; speedup vs baseline: 1.1494x; 1.0652x over previous
//
#include <hip/hip_runtime.h>
#include <hip/hip_bf16.h>

#define NA_ 4096
#define NB_ 4096
#define NN_ 8192            // total nodes
#define EE_ 131072          // edges per direction
#define NE_ (2*EE_ + NN_)   // homogeneous edges incl. self loops = 270336
#define HH_ 512
#define NEG_SLOPE_ 0.2f

typedef __attribute__((ext_vector_type(4))) float f32x4;
typedef __attribute__((ext_vector_type(8))) short s16x8;

__device__ inline unsigned short f2bf(float v) {
    __hip_bfloat16 h = __float2bfloat16(v);
    return __builtin_bit_cast(unsigned short, h);
}
__device__ inline float bf2f(unsigned short u) {
    return __uint_as_float(((unsigned)u) << 16);
}

// ---------------- float-order <-> unsigned-order mapping for atomic max ----
__device__ inline unsigned fkey(float f) {
    unsigned b = __float_as_uint(f);
    return (b & 0x80000000u) ? ~b : (b | 0x80000000u);
}
__device__ inline float finv(unsigned k) {
    return (k & 0x80000000u) ? __uint_as_float(k & 0x7fffffffu)
                             : __uint_as_float(~k);
}

// ---------------- homogeneous edge id -> (src, dst) ------------------------
__device__ inline void edge_sd(int i, const int* __restrict__ eAB,
                               const int* __restrict__ eBA, int& s, int& d) {
    if (i < EE_)            { s = eAB[i];            d = eAB[EE_ + i] + NA_; }
    else if (i < 2 * EE_)   { int j = i - EE_; s = eBA[j] + NA_; d = eBA[EE_ + j]; }
    else                    { s = i - 2 * EE_;       d = s; }
}

// ---------------- batched f32 -> bf16 (optionally split hi/lo) casts --------
struct CvtJob { const float* s; unsigned short* hi; unsigned short* lo; int n4; };
struct CvtJobs { CvtJob j[10]; };

__global__ __launch_bounds__(256) void cvt_all_k(CvtJobs jobs) {
    const CvtJob jb = jobs.j[blockIdx.y];
    int i = blockIdx.x * 256 + threadIdx.x;
    if (i >= jb.n4) return;
    float4 v = ((const float4*)jb.s)[i];
    ushort4 h;
    h.x = f2bf(v.x); h.y = f2bf(v.y); h.z = f2bf(v.z); h.w = f2bf(v.w);
    ((ushort4*)jb.hi)[i] = h;
    if (jb.lo) {
        ushort4 l;
        l.x = f2bf(v.x - bf2f(h.x));
        l.y = f2bf(v.y - bf2f(h.y));
        l.z = f2bf(v.z - bf2f(h.z));
        l.w = f2bf(v.w - bf2f(h.w));
        ((ushort4*)jb.lo)[i] = l;
    }
}

// ---------------- MFMA bf16 GEMM: C[M,N] = A @ B^T (+bias) -----------------
template<int BM, int BN, bool BIAS, typename OutT>
__global__ __launch_bounds__(256) void mgemm_k(
    const unsigned short* __restrict__ A, const unsigned short* __restrict__ B,
    const float* __restrict__ bias, OutT* __restrict__ C,
    int K, int lda, int ldb, int ldc)
{
    constexpr int BK = 32;
    constexpr int WM = BM / 2, WN = BN / 2;
    constexpr int AM = WM / 16, AN = WN / 16;
    constexpr int AISS = BM * 4 / 256, BISS = BN * 4 / 256;
    __shared__ unsigned short sA[BM * BK];
    __shared__ unsigned short sB[BN * BK];
    const int t = threadIdx.x, lane = t & 63, w = t >> 6;
    const int wr = w >> 1, wc = w & 1;
    const int fr = lane & 15, fq = lane >> 4;
    const int bm = blockIdx.y * BM, bn = blockIdx.x * BN;

    f32x4 acc[AM][AN];
    #pragma unroll
    for (int m = 0; m < AM; m++)
        #pragma unroll
        for (int n = 0; n < AN; n++)
            #pragma unroll
            for (int r = 0; r < 4; r++) acc[m][n][r] = 0.f;

    for (int k0 = 0; k0 < K; k0 += BK) {
        __syncthreads();
        #pragma unroll
        for (int i = 0; i < AISS; i++) {
            int slot = i * 256 + t;
            __builtin_amdgcn_global_load_lds(
                (const __attribute__((address_space(1))) unsigned int*)
                    (A + (size_t)(bm + (slot >> 2)) * lda + k0 + (slot & 3) * 8),
                (__attribute__((address_space(3))) unsigned int*)
                    (sA + (i * 256 + w * 64) * 8), 16, 0, 0);
        }
        #pragma unroll
        for (int i = 0; i < BISS; i++) {
            int slot = i * 256 + t;
            __builtin_amdgcn_global_load_lds(
                (const __attribute__((address_space(1))) unsigned int*)
                    (B + (size_t)(bn + (slot >> 2)) * ldb + k0 + (slot & 3) * 8),
                (__attribute__((address_space(3))) unsigned int*)
                    (sB + (i * 256 + w * 64) * 8), 16, 0, 0);
        }
        __syncthreads();
        s16x8 a[AM], b[AN];
        #pragma unroll
        for (int m = 0; m < AM; m++)
            a[m] = *(const s16x8*)&sA[(wr * WM + m * 16 + fr) * BK + fq * 8];
        #pragma unroll
        for (int n = 0; n < AN; n++)
            b[n] = *(const s16x8*)&sB[(wc * WN + n * 16 + fr) * BK + fq * 8];
        #pragma unroll
        for (int m = 0; m < AM; m++)
            #pragma unroll
            for (int n = 0; n < AN; n++)
                acc[m][n] = __builtin_amdgcn_mfma_f32_16x16x32_bf16(a[m], b[n], acc[m][n], 0, 0, 0);
    }

    // C/D layout: col = lane&15, row = (lane>>4)*4 + reg
    #pragma unroll
    for (int m = 0; m < AM; m++) {
        const int row = bm + wr * WM + m * 16 + fq * 4;
        #pragma unroll
        for (int n = 0; n < AN; n++) {
            const int col = bn + wc * WN + n * 16 + fr;
            const float bv = BIAS ? bias[col] : 0.f;
            #pragma unroll
            for (int r = 0; r < 4; r++) {
                float v = acc[m][n][r] + bv;
                if constexpr (sizeof(OutT) == 2)
                    C[(size_t)(row + r) * ldc + col] = (OutT)f2bf(v);
                else
                    C[(size_t)(row + r) * ldc + col] = v;
            }
        }
    }
}

// ---------------- QK^T: 256x256 tile, 8 waves, BK=64, swizzled LDS ----------
// q pre-scaled by scale*log2e -> P = 2^(q.k); denom[row] += row-sum (atomic).
// LDS swizzle: physical cc = logical cc ^ (row&7); source pre-swizzled so
// global_load_lds stays linear (m173 pattern).
__global__ __launch_bounds__(512) void mgemm_qk_k(
    const unsigned short* __restrict__ A, const unsigned short* __restrict__ B,
    unsigned short* __restrict__ C, float* __restrict__ denom)
{
    constexpr int BK = 64;
    __shared__ unsigned short sA[256 * BK];   // 32KB
    __shared__ unsigned short sB[256 * BK];   // 32KB
    const int t = threadIdx.x, lane = t & 63, w = t >> 6;   // 8 waves
    const int wr = w >> 2, wc = w & 3;        // 2 (M) x 4 (N)
    const int fr = lane & 15, fq = lane >> 4;
    const int bm = blockIdx.y * 256, bn = blockIdx.x * 256;

    f32x4 acc[8][4];
    #pragma unroll
    for (int m = 0; m < 8; m++)
        #pragma unroll
        for (int n = 0; n < 4; n++)
            #pragma unroll
            for (int r = 0; r < 4; r++) acc[m][n][r] = 0.f;

    for (int k0 = 0; k0 < 512; k0 += BK) {
        __syncthreads();
        #pragma unroll
        for (int i = 0; i < 4; i++) {
            int s = i * 512 + t;              // 2048 slots = 256 rows x 8 cc
            int row = s >> 3, cc = s & 7;
            int gc = k0 + ((cc ^ (row & 7)) << 3);
            __builtin_amdgcn_global_load_lds(
                (const __attribute__((address_space(1))) unsigned int*)
                    (A + (size_t)(bm + row) * 512 + gc),
                (__attribute__((address_space(3))) unsigned int*)
                    (sA + (i * 512 + w * 64) * 8), 16, 0, 0);
            __builtin_amdgcn_global_load_lds(
                (const __attribute__((address_space(1))) unsigned int*)
                    (B + (size_t)(bn + row) * 512 + gc),
                (__attribute__((address_space(3))) unsigned int*)
                    (sB + (i * 512 + w * 64) * 8), 16, 0, 0);
        }
        __syncthreads();
        #pragma unroll
        for (int kk = 0; kk < 2; kk++) {
            s16x8 a[8], b[4];
            #pragma unroll
            for (int m = 0; m < 8; m++) {
                int row = wr * 128 + m * 16 + fr;
                a[m] = *(const s16x8*)&sA[row * BK + (((kk * 4 + fq) ^ (row & 7)) << 3)];
            }
            #pragma unroll
            for (int n = 0; n < 4; n++) {
                int row = wc * 64 + n * 16 + fr;
                b[n] = *(const s16x8*)&sB[row * BK + (((kk * 4 + fq) ^ (row & 7)) << 3)];
            }
            #pragma unroll
            for (int m = 0; m < 8; m++)
                #pragma unroll
                for (int n = 0; n < 4; n++)
                    acc[m][n] = __builtin_amdgcn_mfma_f32_16x16x32_bf16(a[m], b[n], acc[m][n], 0, 0, 0);
        }
    }

    #pragma unroll
    for (int m = 0; m < 8; m++) {
        #pragma unroll
        for (int r = 0; r < 4; r++) {
            const int row = bm + wr * 128 + m * 16 + fq * 4 + r;   // chunk-local
            float rsum = 0.f;
            #pragma unroll
            for (int n = 0; n < 4; n++) {
                const int col = bn + wc * 64 + n * 16 + fr;
                float p = exp2f(acc[m][n][r]);
                rsum += p;
                C[(size_t)row * 8192 + col] = f2bf(p);
            }
            rsum += __shfl_xor(rsum, 1);
            rsum += __shfl_xor(rsum, 2);
            rsum += __shfl_xor(rsum, 4);
            rsum += __shfl_xor(rsum, 8);
            if (fr == 0) atomicAdd(&denom[row], rsum);
        }
    }
}

// ---------------- merged per-type input linear (A rows 0..4095, B rows 4096+)
template<bool SPLIT>
__global__ __launch_bounds__(256) void mgemm_in_k(
    const unsigned short* __restrict__ xA, const unsigned short* __restrict__ xB,
    const unsigned short* __restrict__ WA, const unsigned short* __restrict__ WB,
    const float* __restrict__ biasA, const float* __restrict__ biasB,
    unsigned short* __restrict__ o1, unsigned short* __restrict__ o2)
{
    constexpr int BK = 32;
    __shared__ unsigned short sA[128 * BK];
    __shared__ unsigned short sB[128 * BK];
    const int t = threadIdx.x, lane = t & 63, w = t >> 6;
    const int wr = w >> 1, wc = w & 1;
    const int fr = lane & 15, fq = lane >> 4;
    const int bm = blockIdx.y * 128, bn = blockIdx.x * 128;
    const bool isB = bm >= NA_;
    const unsigned short* A = isB ? xB : xA;
    const unsigned short* W = isB ? WB : WA;
    const float* bias = isB ? biasB : biasA;
    const int bml = bm - (isB ? NA_ : 0);

    f32x4 acc[4][4];
    #pragma unroll
    for (int m = 0; m < 4; m++)
        #pragma unroll
        for (int n = 0; n < 4; n++)
            #pragma unroll
            for (int r = 0; r < 4; r++) acc[m][n][r] = 0.f;

    for (int k0 = 0; k0 < 256; k0 += BK) {
        __syncthreads();
        #pragma unroll
        for (int i = 0; i < 2; i++) {
            int slot = i * 256 + t;
            __builtin_amdgcn_global_load_lds(
                (const __attribute__((address_space(1))) unsigned int*)
                    (A + (size_t)(bml + (slot >> 2)) * 256 + k0 + (slot & 3) * 8),
                (__attribute__((address_space(3))) unsigned int*)
                    (sA + (i * 256 + w * 64) * 8), 16, 0, 0);
            __builtin_amdgcn_global_load_lds(
                (const __attribute__((address_space(1))) unsigned int*)
                    (W + (size_t)(bn + (slot >> 2)) * 256 + k0 + (slot & 3) * 8),
                (__attribute__((address_space(3))) unsigned int*)
                    (sB + (i * 256 + w * 64) * 8), 16, 0, 0);
        }
        __syncthreads();
        s16x8 a[4], b[4];
        #pragma unroll
        for (int m = 0; m < 4; m++)
            a[m] = *(const s16x8*)&sA[(wr * 64 + m * 16 + fr) * BK + fq * 8];
        #pragma unroll
        for (int n = 0; n < 4; n++)
            b[n] = *(const s16x8*)&sB[(wc * 64 + n * 16 + fr) * BK + fq * 8];
        #pragma unroll
        for (int m = 0; m < 4; m++)
            #pragma unroll
            for (int n = 0; n < 4; n++)
                acc[m][n] = __builtin_amdgcn_mfma_f32_16x16x32_bf16(a[m], b[n], acc[m][n], 0, 0, 0);
    }

    #pragma unroll
    for (int m = 0; m < 4; m++) {
        const int row = bm + wr * 64 + m * 16 + fq * 4;
        #pragma unroll
        for (int n = 0; n < 4; n++) {
            const int col = bn + wc * 64 + n * 16 + fr;
            const float bv = bias[col];
            #pragma unroll
            for (int r = 0; r < 4; r++) {
                float v = acc[m][n][r] + bv;
                unsigned short hi = f2bf(v);
                o1[(size_t)(row + r) * 512 + col] = hi;
                if (SPLIT)
                    o2[(size_t)(row + r) * 512 + col] = f2bf(v - bf2f(hi));
            }
        }
    }
}

// ---------------- split-precision MFMA GEMM (~f32 accuracy, bf16 out only) --
__global__ __launch_bounds__(256) void mgemm3_k(
    const unsigned short* __restrict__ Ahi, const unsigned short* __restrict__ Alo,
    const unsigned short* __restrict__ Bhi, const unsigned short* __restrict__ Blo,
    unsigned short* __restrict__ Cb, int K, int lda, int ldb)
{
    constexpr int BM = 128, BN = 128, BK = 32;
    __shared__ unsigned short sAh[BM * BK], sAl[BM * BK];
    __shared__ unsigned short sBh[BN * BK], sBl[BN * BK];
    const int t = threadIdx.x, lane = t & 63, w = t >> 6;
    const int wr = w >> 1, wc = w & 1;
    const int fr = lane & 15, fq = lane >> 4;
    const int bm = blockIdx.y * BM, bn = blockIdx.x * BN;

    f32x4 acc[4][4];
    #pragma unroll
    for (int m = 0; m < 4; m++)
        #pragma unroll
        for (int n = 0; n < 4; n++)
            #pragma unroll
            for (int r = 0; r < 4; r++) acc[m][n][r] = 0.f;

    for (int k0 = 0; k0 < K; k0 += BK) {
        __syncthreads();
        #pragma unroll
        for (int i = 0; i < 2; i++) {
            int slot = i * 256 + t;
            size_t ga = (size_t)(bm + (slot >> 2)) * lda + k0 + (slot & 3) * 8;
            size_t gb = (size_t)(bn + (slot >> 2)) * ldb + k0 + (slot & 3) * 8;
            unsigned loff = (unsigned)(i * 256 + w * 64) * 8;
            __builtin_amdgcn_global_load_lds(
                (const __attribute__((address_space(1))) unsigned int*)(Ahi + ga),
                (__attribute__((address_space(3))) unsigned int*)(sAh + loff), 16, 0, 0);
            __builtin_amdgcn_global_load_lds(
                (const __attribute__((address_space(1))) unsigned int*)(Alo + ga),
                (__attribute__((address_space(3))) unsigned int*)(sAl + loff), 16, 0, 0);
            __builtin_amdgcn_global_load_lds(
                (const __attribute__((address_space(1))) unsigned int*)(Bhi + gb),
                (__attribute__((address_space(3))) unsigned int*)(sBh + loff), 16, 0, 0);
            __builtin_amdgcn_global_load_lds(
                (const __attribute__((address_space(1))) unsigned int*)(Blo + gb),
                (__attribute__((address_space(3))) unsigned int*)(sBl + loff), 16, 0, 0);
        }
        __syncthreads();
        s16x8 ah[4], al[4], bh[4], bl[4];
        #pragma unroll
        for (int m = 0; m < 4; m++) {
            int o = (wr * 64 + m * 16 + fr) * BK + fq * 8;
            ah[m] = *(const s16x8*)&sAh[o];
            al[m] = *(const s16x8*)&sAl[o];
        }
        #pragma unroll
        for (int n = 0; n < 4; n++) {
            int o = (wc * 64 + n * 16 + fr) * BK + fq * 8;
            bh[n] = *(const s16x8*)&sBh[o];
            bl[n] = *(const s16x8*)&sBl[o];
        }
        #pragma unroll
        for (int m = 0; m < 4; m++)
            #pragma unroll
            for (int n = 0; n < 4; n++) {
                acc[m][n] = __builtin_amdgcn_mfma_f32_16x16x32_bf16(ah[m], bh[n], acc[m][n], 0, 0, 0);
                acc[m][n] = __builtin_amdgcn_mfma_f32_16x16x32_bf16(ah[m], bl[n], acc[m][n], 0, 0, 0);
                acc[m][n] = __builtin_amdgcn_mfma_f32_16x16x32_bf16(al[m], bh[n], acc[m][n], 0, 0, 0);
            }
    }

    #pragma unroll
    for (int m = 0; m < 4; m++) {
        const int row = bm + wr * 64 + m * 16 + fq * 4;
        #pragma unroll
        for (int n = 0; n < 4; n++) {
            const int col = bn + wc * 64 + n * 16 + fr;
            #pragma unroll
            for (int r = 0; r < 4; r++)
                Cb[(size_t)(row + r) * 512 + col] = f2bf(acc[m][n][r]);
        }
    }
}

// ---------------- PV split-K MFMA GEMM (BK=64, swizzled LDS, XCD swizzle) ---
__global__ __launch_bounds__(256) void mgemm_pv_k(
    const unsigned short* __restrict__ A, const unsigned short* __restrict__ B,
    unsigned short* __restrict__ C, int kseg, size_t segstride)
{
    constexpr int BK = 64;
    __shared__ unsigned short sA[128 * BK];
    __shared__ unsigned short sB[128 * BK];
    const int t = threadIdx.x, lane = t & 63, w = t >> 6;
    const int wr = w >> 1, wc = w & 1;
    const int fr = lane & 15, fq = lane >> 4;
    const int L  = blockIdx.x + (blockIdx.y << 2) + (blockIdx.z << 6);
    const int xs = L >> 7;
    const int ys = (L & 127) & 15;
    const int zs = (L & 127) >> 4;
    const int bm = ys * 128, bn = xs * 128;
    const int kofs = zs * kseg;

    f32x4 acc[4][4];
    #pragma unroll
    for (int m = 0; m < 4; m++)
        #pragma unroll
        for (int n = 0; n < 4; n++)
            #pragma unroll
            for (int r = 0; r < 4; r++) acc[m][n][r] = 0.f;

    for (int k0 = 0; k0 < kseg; k0 += BK) {
        __syncthreads();
        #pragma unroll
        for (int i = 0; i < 4; i++) {
            int s = i * 256 + t;              // 1024 slots = 128 rows x 8 cc
            int row = s >> 3, cc = s & 7;
            int gc = kofs + k0 + ((cc ^ (row & 7)) << 3);
            __builtin_amdgcn_global_load_lds(
                (const __attribute__((address_space(1))) unsigned int*)
                    (A + (size_t)(bm + row) * 8192 + gc),
                (__attribute__((address_space(3))) unsigned int*)
                    (sA + (i * 256 + w * 64) * 8), 16, 0, 0);
            __builtin_amdgcn_global_load_lds(
                (const __attribute__((address_space(1))) unsigned int*)
                    (B + (size_t)(bn + row) * 8192 + gc),
                (__attribute__((address_space(3))) unsigned int*)
                    (sB + (i * 256 + w * 64) * 8), 16, 0, 0);
        }
        __syncthreads();
        #pragma unroll
        for (int kk = 0; kk < 2; kk++) {
            s16x8 a[4], b[4];
            #pragma unroll
            for (int m = 0; m < 4; m++) {
                int row = wr * 64 + m * 16 + fr;
                a[m] = *(const s16x8*)&sA[row * BK + (((kk * 4 + fq) ^ (row & 7)) << 3)];
            }
            #pragma unroll
            for (int n = 0; n < 4; n++) {
                int row = wc * 64 + n * 16 + fr;
                b[n] = *(const s16x8*)&sB[row * BK + (((kk * 4 + fq) ^ (row & 7)) << 3)];
            }
            #pragma unroll
            for (int m = 0; m < 4; m++)
                #pragma unroll
                for (int n = 0; n < 4; n++)
                    acc[m][n] = __builtin_amdgcn_mfma_f32_16x16x32_bf16(a[m], b[n], acc[m][n], 0, 0, 0);
        }
    }

    unsigned short* Cz = C + (size_t)zs * segstride;
    #pragma unroll
    for (int m = 0; m < 4; m++) {
        const int row = bm + wr * 64 + m * 16 + fq * 4;
        #pragma unroll
        for (int n = 0; n < 4; n++) {
            const int col = bn + wc * 64 + n * 16 + fr;
            #pragma unroll
            for (int r = 0; r < 4; r++)
                Cz[(size_t)(row + r) * 512 + col] = f2bf(acc[m][n][r]);
        }
    }
}

// ---------------- reduce bf16 split-K partials, divide by denom -> bf16 ----
__global__ __launch_bounds__(256) void radd_k(const unsigned short* __restrict__ src,
                                              unsigned short* __restrict__ dst,
                                              const float* __restrict__ dn,
                                              int n8, int segs, size_t stride8) {
    int i = blockIdx.x * 256 + threadIdx.x;
    if (i >= n8) return;
    float acc[8] = {0,0,0,0,0,0,0,0};
    for (int s = 0; s < segs; s++) {
        s16x8 v = ((const s16x8*)src)[i + s * stride8];
        #pragma unroll
        for (int j = 0; j < 8; j++) acc[j] += bf2f((unsigned short)v[j]);
    }
    const float rd = 1.0f / dn[i >> 6];    // 64 groups of 8 per 512-col row
    s16x8 o;
    #pragma unroll
    for (int j = 0; j < 8; j++) o[j] = (short)f2bf(acc[j] * rd);
    ((s16x8*)dst)[i] = o;
}

// ---------------- qkv MFMA GEMM with split epilogue (scale folded into q) ---
__global__ __launch_bounds__(256) void mgemm_qkv_k(
    const unsigned short* __restrict__ A, const unsigned short* __restrict__ B,
    const float* __restrict__ bias, float scale,
    unsigned short* __restrict__ qb, unsigned short* __restrict__ kb,
    unsigned short* __restrict__ vb)
{
    constexpr int BM = 128, BN = 128, BK = 32;
    __shared__ unsigned short sA[BM * BK];
    __shared__ unsigned short sB[BN * BK];
    const int t = threadIdx.x, lane = t & 63, w = t >> 6;
    const int wr = w >> 1, wc = w & 1;
    const int fr = lane & 15, fq = lane >> 4;
    const int bm = blockIdx.y * BM, bn = blockIdx.x * BN;

    f32x4 acc[4][4];
    #pragma unroll
    for (int m = 0; m < 4; m++)
        #pragma unroll
        for (int n = 0; n < 4; n++)
            #pragma unroll
            for (int r = 0; r < 4; r++) acc[m][n][r] = 0.f;

    for (int k0 = 0; k0 < 512; k0 += BK) {
        __syncthreads();
        #pragma unroll
        for (int i = 0; i < 2; i++) {
            int slot = i * 256 + t;
            __builtin_amdgcn_global_load_lds(
                (const __attribute__((address_space(1))) unsigned int*)
                    (A + (size_t)(bm + (slot >> 2)) * 512 + k0 + (slot & 3) * 8),
                (__attribute__((address_space(3))) unsigned int*)
                    (sA + (i * 256 + w * 64) * 8), 16, 0, 0);
            __builtin_amdgcn_global_load_lds(
                (const __attribute__((address_space(1))) unsigned int*)
                    (B + (size_t)(bn + (slot >> 2)) * 512 + k0 + (slot & 3) * 8),
                (__attribute__((address_space(3))) unsigned int*)
                    (sB + (i * 256 + w * 64) * 8), 16, 0, 0);
        }
        __syncthreads();
        s16x8 a[4], b[4];
        #pragma unroll
        for (int m = 0; m < 4; m++)
            a[m] = *(const s16x8*)&sA[(wr * 64 + m * 16 + fr) * BK + fq * 8];
        #pragma unroll
        for (int n = 0; n < 4; n++)
            b[n] = *(const s16x8*)&sB[(wc * 64 + n * 16 + fr) * BK + fq * 8];
        #pragma unroll
        for (int m = 0; m < 4; m++)
            #pragma unroll
            for (int n = 0; n < 4; n++)
                acc[m][n] = __builtin_amdgcn_mfma_f32_16x16x32_bf16(a[m], b[n], acc[m][n], 0, 0, 0);
    }

    #pragma unroll
    for (int m = 0; m < 4; m++) {
        const int row = bm + wr * 64 + m * 16 + fq * 4;
        #pragma unroll
        for (int n = 0; n < 4; n++) {
            const int col = bn + wc * 64 + n * 16 + fr;
            const float bv = bias[col];
            #pragma unroll
            for (int r = 0; r < 4; r++) {
                float v = acc[m][n][r] + bv;
                if (col < 512)
                    qb[(size_t)(row + r) * 512 + col] = f2bf(v * scale);
                else if (col < 1024)
                    kb[(size_t)(row + r) * 512 + (col - 512)] = f2bf(v);
                else
                    vb[(size_t)(row + r) * 512 + (col - 1024)] = f2bf(v);
            }
        }
    }
}

// ---------------- bf16 transpose: vb[8192][512] -> vT[512][8192] ------------
__global__ __launch_bounds__(256) void trT_k(const unsigned short* __restrict__ vb,
                                             unsigned short* __restrict__ vT) {
    __shared__ unsigned short s[64][65];
    const int t = threadIdx.x;
    const int rowo = blockIdx.y * 64;
    const int colo = blockIdx.x * 64;
    {
        int r = t >> 2, cg = (t & 3) * 16;
        const s16x8* src = (const s16x8*)(vb + (size_t)(rowo + r) * 512 + colo + cg);
        s16x8 u0 = src[0], u1 = src[1];
        #pragma unroll
        for (int j = 0; j < 8; j++) {
            s[r][cg + j]     = (unsigned short)u0[j];
            s[r][cg + 8 + j] = (unsigned short)u1[j];
        }
    }
    __syncthreads();
    {
        int c = t >> 2, rg = (t & 3) * 16;
        s16x8 o0, o1;
        #pragma unroll
        for (int j = 0; j < 8; j++) {
            o0[j] = (short)s[rg + j][c];
            o1[j] = (short)s[rg + 8 + j][c];
        }
        s16x8* dst = (s16x8*)(vT + (size_t)(colo + c) * 8192 + rowo + rg);
        dst[0] = o0; dst[1] = o1;
    }
}

// ---------------- per-node attention dots (wave per node, bf16 h) -----------
__global__ __launch_bounds__(256) void node_dots_k(
    const unsigned short* __restrict__ hb, const float* __restrict__ a_src,
    const float* __restrict__ a_dst, float* __restrict__ as_, float* __restrict__ ad_)
{
    int wid  = (blockIdx.x * 256 + threadIdx.x) >> 6;
    int lane = threadIdx.x & 63;
    if (wid >= NN_) return;
    s16x8 hv = *(const s16x8*)(hb + (size_t)wid * HH_ + lane * 8);
    float s1 = 0.f, s2 = 0.f;
    #pragma unroll
    for (int j = 0; j < 8; j++) {
        float v = bf2f((unsigned short)hv[j]);
        s1 = fmaf(v, a_src[lane * 8 + j], s1);
        s2 = fmaf(v, a_dst[lane * 8 + j], s2);
    }
    #pragma unroll
    for (int off = 32; off; off >>= 1) {
        s1 += __shfl_down(s1, off);
        s2 += __shfl_down(s2, off);
    }
    if (lane == 0) { as_[wid] = s1; ad_[wid] = s2; }
}

// ---------------- CSR build ------------------------------------------------
__global__ void count_deg_k(const int* eAB, const int* eBA, int* deg) {
    int i = blockIdx.x * 256 + threadIdx.x;
    if (i >= NE_) return;
    int s, d; edge_sd(i, eAB, eBA, s, d);
    atomicAdd(&deg[d], 1);
}

__global__ __launch_bounds__(256) void scan_k(const int* __restrict__ deg, int* rowstart) {
    __shared__ int part[256];
    int t = threadIdx.x;
    int base = t * 32;
    int loc[32]; int s = 0;
    #pragma unroll
    for (int j = 0; j < 32; j++) { loc[j] = s; s += deg[base + j]; }
    part[t] = s;
    __syncthreads();
    if (t == 0) {
        int a = 0;
        for (int i = 0; i < 256; i++) { int v = part[i]; part[i] = a; a += v; }
        rowstart[NN_] = a;
    }
    __syncthreads();
    int off = part[t];
    #pragma unroll
    for (int j = 0; j < 32; j++) rowstart[base + j] = off + loc[j];
}

// stores src node per CSR slot + slot index per edge (kills indirection later)
__global__ void fill_csr_k(const int* eAB, const int* eBA,
                           const int* __restrict__ rowstart, int* cursor,
                           int* csr_src, int* pos) {
    int i = blockIdx.x * 256 + threadIdx.x;
    if (i >= NE_) return;
    int s, d; edge_sd(i, eAB, eBA, s, d);
    int p = atomicAdd(&cursor[d], 1);
    int slot = rowstart[d] + p;
    csr_src[slot] = s;
    pos[i] = slot;
}

// ---------------- GAT edge passes ------------------------------------------
__global__ void edge_pass1_k(const int* eAB, const int* eBA,
                             const float* __restrict__ as_, const float* __restrict__ ad_,
                             float* evals, unsigned* mkey) {
    int i = blockIdx.x * 256 + threadIdx.x;
    if (i >= NE_) return;
    int s, d; edge_sd(i, eAB, eBA, s, d);
    float e = as_[s] + ad_[d];
    e = (e >= 0.f) ? e : NEG_SLOPE_ * e;
    evals[i] = e;
    atomicMax(&mkey[d], fkey(e));
}

// scatters exp into CSR order (evs) + accumulates denom
__global__ void edge_pass2_k(const int* eAB, const int* eBA,
                             const unsigned* __restrict__ mkey,
                             const float* __restrict__ evals,
                             const int* __restrict__ pos,
                             float* __restrict__ evs, float* denom) {
    int i = blockIdx.x * 256 + threadIdx.x;
    if (i >= NE_) return;
    int s, d; edge_sd(i, eAB, eBA, s, d);
    float m = finv(mkey[d]);
    float ex = expf(evals[i] - m);
    evs[pos[i]] = ex;
    atomicAdd(&denom[d], ex);
}

// ---------------- GAT aggregation: single pass, streaming CSR ---------------
template<bool SPLIT>
__global__ __launch_bounds__(256) void gat_agg_k(
    const int* __restrict__ rowstart, const int* __restrict__ csr_src,
    const float* __restrict__ evs, const float* __restrict__ denom,
    const unsigned short* __restrict__ hb, const float* __restrict__ bias,
    float* __restrict__ outF, int ldo,
    unsigned short* __restrict__ outHi, unsigned short* __restrict__ outLo)
{
    int wid  = (blockIdx.x * 256 + threadIdx.x) >> 6;
    int lane = threadIdx.x & 63;
    if (wid >= NN_) return;
    float acc[8] = {0.f,0.f,0.f,0.f,0.f,0.f,0.f,0.f};
    int beg = rowstart[wid], end = rowstart[wid + 1];
    float rden = 1.0f / denom[wid];
    for (int p = beg; p < end; p++) {
        int s = csr_src[p];
        float alpha = evs[p] * rden;
        s16x8 hv = *(const s16x8*)(hb + (size_t)s * HH_ + lane * 8);
        #pragma unroll
        for (int j = 0; j < 8; j++)
            acc[j] = fmaf(alpha, bf2f((unsigned short)hv[j]), acc[j]);
    }
    #pragma unroll
    for (int j = 0; j < 8; j++) acc[j] += bias[lane * 8 + j];
    if (SPLIT) {
        s16x8 hi, lo;
        #pragma unroll
        for (int j = 0; j < 8; j++) {
            unsigned short h = f2bf(acc[j]);
            hi[j] = (short)h;
            lo[j] = (short)f2bf(acc[j] - bf2f(h));
        }
        *(s16x8*)(outHi + (size_t)wid * HH_ + lane * 8) = hi;
        *(s16x8*)(outLo + (size_t)wid * HH_ + lane * 8) = lo;
    } else {
        float* o = outF + (size_t)wid * ldo + lane * 8;
        *(float4*)(o)     = make_float4(acc[0], acc[1], acc[2], acc[3]);
        *(float4*)(o + 4) = make_float4(acc[4], acc[5], acc[6], acc[7]);
    }
}

// ===========================================================================
extern "C" void kernel_launch(void* const* d_in, const int* in_sizes, int n_in,
                              void* d_out, int out_size, void* d_ws, size_t ws_size,
                              hipStream_t stream)
{
    const float* x_A    = (const float*)d_in[0];
    const float* x_B    = (const float*)d_in[1];
    const int*   eAB    = (const int*)d_in[2];
    const int*   eBA    = (const int*)d_in[3];
    const float* W_inA  = (const float*)d_in[4];  const float* b_inA  = (const float*)d_in[5];
    const float* W_inB  = (const float*)d_in[6];  const float* b_inB  = (const float*)d_in[7];
    const float* W_in2A = (const float*)d_in[8];  const float* b_in2A = (const float*)d_in[9];
    const float* W_in2B = (const float*)d_in[10]; const float* b_in2B = (const float*)d_in[11];
    const float* Wg1    = (const float*)d_in[12]; const float* a_src1 = (const float*)d_in[13];
    const float* a_dst1 = (const float*)d_in[14]; const float* bg1    = (const float*)d_in[15];
    const float* Wg2    = (const float*)d_in[16]; const float* a_src2 = (const float*)d_in[17];
    const float* a_dst2 = (const float*)d_in[18]; const float* bg2    = (const float*)d_in[19];
    const float* Wqkv   = (const float*)d_in[20]; const float* bqkv   = (const float*)d_in[21];
    const float* Wo     = (const float*)d_in[22]; const float* bo     = (const float*)d_in[23];

    float* out = (float*)d_out;

    char* base = (char*)d_ws;
    size_t off = 0;
    auto alloc = [&](size_t nb) -> char* {
        char* p = base + off;
        off = (off + nb + 255) & ~(size_t)255;
        return p;
    };

    // bufA and bufB MUST be adjacent: Sb (32MB) spans both during attention.
    float*          bufA  = (float*)alloc((size_t)NN_ * 512 * 4);
    float*          bufB  = (float*)alloc((size_t)NN_ * 512 * 4);
    float*          bufC  = (float*)alloc((size_t)NN_ * 512 * 4);
    float*          as_   = (float*)alloc(NN_ * 4);
    float*          ad_   = (float*)alloc(NN_ * 4);
    // mkey..cdn contiguous: one initial memset covers all five
    unsigned*       mkey  = (unsigned*)alloc(NN_ * 4);
    float*          denom = (float*)alloc(NN_ * 4);
    int*            deg   = (int*)alloc(NN_ * 4);
    int*            cursor= (int*)alloc(NN_ * 4);
    float*          cdn   = (float*)alloc(NN_ * 4);    // per-chunk attn denoms
    int*            rowst = (int*)alloc((NN_ + 1) * 4);
    float*          evals = (float*)alloc((size_t)NE_ * 4);
    int*            csrs  = (int*)alloc((size_t)NE_ * 4);   // src per CSR slot
    int*            pos   = (int*)alloc((size_t)NE_ * 4);   // edge -> CSR slot
    float*          evs   = (float*)alloc((size_t)NE_ * 4); // exp in CSR order
    unsigned short* xbA   = (unsigned short*)alloc((size_t)NA_ * 256 * 2);
    unsigned short* xbB   = (unsigned short*)alloc((size_t)NB_ * 256 * 2);
    unsigned short* WbinA = (unsigned short*)alloc((size_t)512 * 256 * 2);
    unsigned short* WbinB = (unsigned short*)alloc((size_t)512 * 256 * 2);
    unsigned short* Wbin2A= (unsigned short*)alloc((size_t)512 * 256 * 2);
    unsigned short* Wbin2B= (unsigned short*)alloc((size_t)512 * 256 * 2);
    unsigned short* Wbqkv = (unsigned short*)alloc((size_t)1536 * 512 * 2);
    unsigned short* Wbo   = (unsigned short*)alloc((size_t)512 * 512 * 2);
    unsigned short* Wg1hi = (unsigned short*)alloc((size_t)512 * 512 * 2);
    unsigned short* Wg1lo = (unsigned short*)alloc((size_t)512 * 512 * 2);
    unsigned short* Wg2hi = (unsigned short*)alloc((size_t)512 * 512 * 2);
    unsigned short* Wg2lo = (unsigned short*)alloc((size_t)512 * 512 * 2);
    unsigned short* qb    = (unsigned short*)alloc((size_t)NN_ * 512 * 2);
    unsigned short* kb    = (unsigned short*)alloc((size_t)NN_ * 512 * 2);
    unsigned short* vT    = (unsigned short*)alloc((size_t)512 * NN_ * 2);
    unsigned short* ab    = (unsigned short*)alloc((size_t)NN_ * 512 * 2);

    // overlays
    unsigned short* hb = vT;                              // bf16 h (local branch)
    unsigned short* gb = (unsigned short*)bufC;           // g bf16 (global, pre-loop)
    unsigned short* vb = gb + (size_t)NN_ * 512;          // v bf16 (global, pre-loop)
    unsigned short* Sb = (unsigned short*)bufA;           // scores: bufA+bufB = 32MB
    unsigned short* pv = (unsigned short*)bufC;           // PV bf16 partials (16MB)

    const int R = 2048, SEGS = 8, KSEG = 8192 / SEGS;
    const int EG = (NE_ + 255) / 256;
    const float scale2 = 0.044194173824159216f * 1.4426950408889634f; // /sqrt(512)*log2e

    // -------- all weight/input casts in ONE launch --------------------------
    CvtJobs jobs;
    jobs.j[0] = { x_A,    xbA,    nullptr, NA_ * 256 / 4 };
    jobs.j[1] = { x_B,    xbB,    nullptr, NB_ * 256 / 4 };
    jobs.j[2] = { W_inA,  WbinA,  nullptr, 512 * 256 / 4 };
    jobs.j[3] = { W_inB,  WbinB,  nullptr, 512 * 256 / 4 };
    jobs.j[4] = { W_in2A, Wbin2A, nullptr, 512 * 256 / 4 };
    jobs.j[5] = { W_in2B, Wbin2B, nullptr, 512 * 256 / 4 };
    jobs.j[6] = { Wqkv,   Wbqkv,  nullptr, 1536 * 512 / 4 };
    jobs.j[7] = { Wo,     Wbo,    nullptr, 512 * 512 / 4 };
    jobs.j[8] = { Wg1,    Wg1hi,  Wg1lo,   512 * 512 / 4 };
    jobs.j[9] = { Wg2,    Wg2hi,  Wg2lo,   512 * 512 / 4 };
    cvt_all_k<<<dim3(NA_ * 256 / 4 / 256, 10), 256, 0, stream>>>(jobs);

    // zero mkey, denom, deg, cursor, cdn in one shot
    hipMemsetAsync(mkey, 0, (size_t)NN_ * 4 * 5, stream);

    // -------- CSR build -----------------------------------------------------
    count_deg_k<<<EG, 256, 0, stream>>>(eAB, eBA, deg);
    scan_k<<<1, 256, 0, stream>>>(deg, rowst);
    fill_csr_k<<<EG, 256, 0, stream>>>(eAB, eBA, rowst, cursor, csrs, pos);

    // -------- local branch --------------------------------------------------
    mgemm_in_k<true><<<dim3(4, 64), 256, 0, stream>>>(
        xbA, xbB, WbinA, WbinB, b_inA, b_inB, qb, kb);
    mgemm3_k<<<dim3(4, 64), 256, 0, stream>>>(qb, kb, Wg1hi, Wg1lo,
                                              hb, 512, 512, 512);
    node_dots_k<<<NN_/4, 256, 0, stream>>>(hb, a_src1, a_dst1, as_, ad_);
    edge_pass1_k<<<EG, 256, 0, stream>>>(eAB, eBA, as_, ad_, evals, mkey);
    edge_pass2_k<<<EG, 256, 0, stream>>>(eAB, eBA, mkey, evals, pos, evs, denom);
    gat_agg_k<true><<<NN_/4, 256, 0, stream>>>(rowst, csrs, evs, denom,
                                               hb, bg1, nullptr, 0, qb, kb);
    mgemm3_k<<<dim3(4, 64), 256, 0, stream>>>(qb, kb, Wg2hi, Wg2lo,
                                              hb, 512, 512, 512);
    node_dots_k<<<NN_/4, 256, 0, stream>>>(hb, a_src2, a_dst2, as_, ad_);
    hipMemsetAsync(mkey, 0, NN_ * 8, stream);           // mkey + denom
    edge_pass1_k<<<EG, 256, 0, stream>>>(eAB, eBA, as_, ad_, evals, mkey);
    edge_pass2_k<<<EG, 256, 0, stream>>>(eAB, eBA, mkey, evals, pos, evs, denom);
    // layer-2 aggregation writes the local half of d_out directly (ldo=1024)
    gat_agg_k<false><<<NN_/4, 256, 0, stream>>>(rowst, csrs, evs, denom,
                                                hb, bg2, out, 1024, nullptr, nullptr);

    // -------- global branch -------------------------------------------------
    mgemm_in_k<false><<<dim3(4, 64), 256, 0, stream>>>(
        xbA, xbB, Wbin2A, Wbin2B, b_in2A, b_in2B, gb, nullptr);
    mgemm_qkv_k<<<dim3(12, 64), 256, 0, stream>>>(gb, Wbqkv, bqkv, scale2, qb, kb, vb);
    trT_k<<<dim3(8, 128), 256, 0, stream>>>(vb, vT);
    for (int c0 = 0; c0 < 8192; c0 += R) {
        float* dn = cdn + c0;   // this chunk's 2048 denominators (pre-zeroed)
        mgemm_qk_k<<<dim3(32, 8), 512, 0, stream>>>(
            qb + (size_t)c0 * 512, kb, Sb, dn);
        mgemm_pv_k<<<dim3(4, R/128, SEGS), 256, 0, stream>>>(
            Sb, vT, pv, KSEG, (size_t)R * 512);
        radd_k<<<(R*512/8 + 255)/256, 256, 0, stream>>>(
            pv, ab + (size_t)c0 * 512, dn, R*512/8, SEGS, (size_t)R*512/8);
    }
    // Wo GEMM writes the global half of d_out directly (ldc=1024, col offset 512)
    mgemm_k<128,128,true,float><<<dim3(4, 64), 256, 0, stream>>>(
        ab, Wbo, bo, out + 512, 512, 512, 512, 1024);
}

// Round 14
// 603.840 us; speedup vs baseline: 1.1638x; 1.0125x over previous
//
#include <hip/hip_runtime.h>
#include <hip/hip_bf16.h>

#define NA_ 4096
#define NB_ 4096
#define NN_ 8192            // total nodes
#define EE_ 131072          // edges per direction
#define NE_ (2*EE_ + NN_)   // homogeneous edges incl. self loops = 270336
#define HH_ 512
#define NEG_SLOPE_ 0.2f

typedef __attribute__((ext_vector_type(4))) float f32x4;
typedef __attribute__((ext_vector_type(8))) short s16x8;

__device__ inline unsigned short f2bf(float v) {
    __hip_bfloat16 h = __float2bfloat16(v);
    return __builtin_bit_cast(unsigned short, h);
}
__device__ inline float bf2f(unsigned short u) {
    return __uint_as_float(((unsigned)u) << 16);
}

// ---------------- float-order <-> unsigned-order mapping for atomic max ----
__device__ inline unsigned fkey(float f) {
    unsigned b = __float_as_uint(f);
    return (b & 0x80000000u) ? ~b : (b | 0x80000000u);
}
__device__ inline float finv(unsigned k) {
    return (k & 0x80000000u) ? __uint_as_float(k & 0x7fffffffu)
                             : __uint_as_float(~k);
}

// ---------------- homogeneous edge id -> (src, dst) ------------------------
__device__ inline void edge_sd(int i, const int* __restrict__ eAB,
                               const int* __restrict__ eBA, int& s, int& d) {
    if (i < EE_)            { s = eAB[i];            d = eAB[EE_ + i] + NA_; }
    else if (i < 2 * EE_)   { int j = i - EE_; s = eBA[j] + NA_; d = eBA[EE_ + j]; }
    else                    { s = i - 2 * EE_;       d = s; }
}

// ---------------- batched f32 -> bf16 (optionally split hi/lo) casts --------
struct CvtJob { const float* s; unsigned short* hi; unsigned short* lo; int n4; };
struct CvtJobs { CvtJob j[10]; };

__global__ __launch_bounds__(256) void cvt_all_k(CvtJobs jobs) {
    const CvtJob jb = jobs.j[blockIdx.y];
    int i = blockIdx.x * 256 + threadIdx.x;
    if (i >= jb.n4) return;
    float4 v = ((const float4*)jb.s)[i];
    ushort4 h;
    h.x = f2bf(v.x); h.y = f2bf(v.y); h.z = f2bf(v.z); h.w = f2bf(v.w);
    ((ushort4*)jb.hi)[i] = h;
    if (jb.lo) {
        ushort4 l;
        l.x = f2bf(v.x - bf2f(h.x));
        l.y = f2bf(v.y - bf2f(h.y));
        l.z = f2bf(v.z - bf2f(h.z));
        l.w = f2bf(v.w - bf2f(h.w));
        ((ushort4*)jb.lo)[i] = l;
    }
}

// ---------------- MFMA bf16 GEMM: C[M,N] = A @ B^T (+bias) -----------------
template<int BM, int BN, bool BIAS, typename OutT>
__global__ __launch_bounds__(256) void mgemm_k(
    const unsigned short* __restrict__ A, const unsigned short* __restrict__ B,
    const float* __restrict__ bias, OutT* __restrict__ C,
    int K, int lda, int ldb, int ldc)
{
    constexpr int BK = 32;
    constexpr int WM = BM / 2, WN = BN / 2;
    constexpr int AM = WM / 16, AN = WN / 16;
    constexpr int AISS = BM * 4 / 256, BISS = BN * 4 / 256;
    __shared__ unsigned short sA[BM * BK];
    __shared__ unsigned short sB[BN * BK];
    const int t = threadIdx.x, lane = t & 63, w = t >> 6;
    const int wr = w >> 1, wc = w & 1;
    const int fr = lane & 15, fq = lane >> 4;
    const int bm = blockIdx.y * BM, bn = blockIdx.x * BN;

    f32x4 acc[AM][AN];
    #pragma unroll
    for (int m = 0; m < AM; m++)
        #pragma unroll
        for (int n = 0; n < AN; n++)
            #pragma unroll
            for (int r = 0; r < 4; r++) acc[m][n][r] = 0.f;

    for (int k0 = 0; k0 < K; k0 += BK) {
        __syncthreads();
        #pragma unroll
        for (int i = 0; i < AISS; i++) {
            int slot = i * 256 + t;
            __builtin_amdgcn_global_load_lds(
                (const __attribute__((address_space(1))) unsigned int*)
                    (A + (size_t)(bm + (slot >> 2)) * lda + k0 + (slot & 3) * 8),
                (__attribute__((address_space(3))) unsigned int*)
                    (sA + (i * 256 + w * 64) * 8), 16, 0, 0);
        }
        #pragma unroll
        for (int i = 0; i < BISS; i++) {
            int slot = i * 256 + t;
            __builtin_amdgcn_global_load_lds(
                (const __attribute__((address_space(1))) unsigned int*)
                    (B + (size_t)(bn + (slot >> 2)) * ldb + k0 + (slot & 3) * 8),
                (__attribute__((address_space(3))) unsigned int*)
                    (sB + (i * 256 + w * 64) * 8), 16, 0, 0);
        }
        __syncthreads();
        s16x8 a[AM], b[AN];
        #pragma unroll
        for (int m = 0; m < AM; m++)
            a[m] = *(const s16x8*)&sA[(wr * WM + m * 16 + fr) * BK + fq * 8];
        #pragma unroll
        for (int n = 0; n < AN; n++)
            b[n] = *(const s16x8*)&sB[(wc * WN + n * 16 + fr) * BK + fq * 8];
        #pragma unroll
        for (int m = 0; m < AM; m++)
            #pragma unroll
            for (int n = 0; n < AN; n++)
                acc[m][n] = __builtin_amdgcn_mfma_f32_16x16x32_bf16(a[m], b[n], acc[m][n], 0, 0, 0);
    }

    // C/D layout: col = lane&15, row = (lane>>4)*4 + reg
    #pragma unroll
    for (int m = 0; m < AM; m++) {
        const int row = bm + wr * WM + m * 16 + fq * 4;
        #pragma unroll
        for (int n = 0; n < AN; n++) {
            const int col = bn + wc * WN + n * 16 + fr;
            const float bv = BIAS ? bias[col] : 0.f;
            #pragma unroll
            for (int r = 0; r < 4; r++) {
                float v = acc[m][n][r] + bv;
                if constexpr (sizeof(OutT) == 2)
                    C[(size_t)(row + r) * ldc + col] = (OutT)f2bf(v);
                else
                    C[(size_t)(row + r) * ldc + col] = v;
            }
        }
    }
}

// ---------------- QK^T: 256x256 tile, 8 waves, BK=64, swizzled LDS ----------
// q pre-scaled by scale*log2e -> P = 2^(q.k); denom[row] += row-sum (atomic).
// Epilogue stages 64-row bands of exp2'd P in LDS, then stores 16B-coalesced.
__global__ __launch_bounds__(512) void mgemm_qk_k(
    const unsigned short* __restrict__ A, const unsigned short* __restrict__ B,
    unsigned short* __restrict__ C, float* __restrict__ denom)
{
    constexpr int BK = 64;
    __shared__ unsigned short smem[32768];    // 64KB: sA|sB, reused as P-tile
    unsigned short* sA = smem;
    unsigned short* sB = smem + 16384;
    unsigned short* tile = smem;              // 64 x 264 (33KB) in epilogue
    const int t = threadIdx.x, lane = t & 63, w = t >> 6;   // 8 waves
    const int wr = w >> 2, wc = w & 3;        // 2 (M) x 4 (N)
    const int fr = lane & 15, fq = lane >> 4;
    const int bm = blockIdx.y * 256, bn = blockIdx.x * 256;

    f32x4 acc[8][4];
    #pragma unroll
    for (int m = 0; m < 8; m++)
        #pragma unroll
        for (int n = 0; n < 4; n++)
            #pragma unroll
            for (int r = 0; r < 4; r++) acc[m][n][r] = 0.f;

    for (int k0 = 0; k0 < 512; k0 += BK) {
        __syncthreads();
        #pragma unroll
        for (int i = 0; i < 4; i++) {
            int s = i * 512 + t;              // 2048 slots = 256 rows x 8 cc
            int row = s >> 3, cc = s & 7;
            int gc = k0 + ((cc ^ (row & 7)) << 3);
            __builtin_amdgcn_global_load_lds(
                (const __attribute__((address_space(1))) unsigned int*)
                    (A + (size_t)(bm + row) * 512 + gc),
                (__attribute__((address_space(3))) unsigned int*)
                    (sA + (i * 512 + w * 64) * 8), 16, 0, 0);
            __builtin_amdgcn_global_load_lds(
                (const __attribute__((address_space(1))) unsigned int*)
                    (B + (size_t)(bn + row) * 512 + gc),
                (__attribute__((address_space(3))) unsigned int*)
                    (sB + (i * 512 + w * 64) * 8), 16, 0, 0);
        }
        __syncthreads();
        #pragma unroll
        for (int kk = 0; kk < 2; kk++) {
            s16x8 a[8], b[4];
            #pragma unroll
            for (int m = 0; m < 8; m++) {
                int row = wr * 128 + m * 16 + fr;
                a[m] = *(const s16x8*)&sA[row * BK + (((kk * 4 + fq) ^ (row & 7)) << 3)];
            }
            #pragma unroll
            for (int n = 0; n < 4; n++) {
                int row = wc * 64 + n * 16 + fr;
                b[n] = *(const s16x8*)&sB[row * BK + (((kk * 4 + fq) ^ (row & 7)) << 3)];
            }
            #pragma unroll
            for (int m = 0; m < 8; m++)
                #pragma unroll
                for (int n = 0; n < 4; n++)
                    acc[m][n] = __builtin_amdgcn_mfma_f32_16x16x32_bf16(a[m], b[n], acc[m][n], 0, 0, 0);
        }
    }

    // epilogue: 4 phases, each 64 rows (m-pair) staged in LDS, coalesced store
    #pragma unroll
    for (int h = 0; h < 4; h++) {
        __syncthreads();
        #pragma unroll
        for (int mm = 0; mm < 2; mm++) {
            const int m = h * 2 + mm;
            #pragma unroll
            for (int r = 0; r < 4; r++) {
                float rsum = 0.f;
                #pragma unroll
                for (int n = 0; n < 4; n++) {
                    float p = exp2f(acc[m][n][r]);
                    rsum += p;
                    tile[(wr * 32 + mm * 16 + fq * 4 + r) * 264 + wc * 64 + n * 16 + fr]
                        = f2bf(p);
                }
                rsum += __shfl_xor(rsum, 1);
                rsum += __shfl_xor(rsum, 2);
                rsum += __shfl_xor(rsum, 4);
                rsum += __shfl_xor(rsum, 8);
                if (fr == 0)
                    atomicAdd(&denom[bm + wr * 128 + h * 32 + mm * 16 + fq * 4 + r], rsum);
            }
        }
        __syncthreads();
        #pragma unroll
        for (int j = 0; j < 4; j++) {
            int cj = j * 512 + t;             // 2048 chunks = 64 rows x 32
            int row_l = cj >> 5, c16 = cj & 31;
            int grow = bm + (row_l >> 5) * 128 + h * 32 + (row_l & 31);
            *(s16x8*)(C + (size_t)grow * 8192 + bn + c16 * 8)
                = *(const s16x8*)&tile[row_l * 264 + c16 * 8];
        }
    }
}

// ---------------- merged per-type input linear (A rows 0..4095, B rows 4096+)
template<bool SPLIT>
__global__ __launch_bounds__(256) void mgemm_in_k(
    const unsigned short* __restrict__ xA, const unsigned short* __restrict__ xB,
    const unsigned short* __restrict__ WA, const unsigned short* __restrict__ WB,
    const float* __restrict__ biasA, const float* __restrict__ biasB,
    unsigned short* __restrict__ o1, unsigned short* __restrict__ o2)
{
    constexpr int BK = 32;
    __shared__ unsigned short sA[128 * BK];
    __shared__ unsigned short sB[128 * BK];
    const int t = threadIdx.x, lane = t & 63, w = t >> 6;
    const int wr = w >> 1, wc = w & 1;
    const int fr = lane & 15, fq = lane >> 4;
    const int bm = blockIdx.y * 128, bn = blockIdx.x * 128;
    const bool isB = bm >= NA_;
    const unsigned short* A = isB ? xB : xA;
    const unsigned short* W = isB ? WB : WA;
    const float* bias = isB ? biasB : biasA;
    const int bml = bm - (isB ? NA_ : 0);

    f32x4 acc[4][4];
    #pragma unroll
    for (int m = 0; m < 4; m++)
        #pragma unroll
        for (int n = 0; n < 4; n++)
            #pragma unroll
            for (int r = 0; r < 4; r++) acc[m][n][r] = 0.f;

    for (int k0 = 0; k0 < 256; k0 += BK) {
        __syncthreads();
        #pragma unroll
        for (int i = 0; i < 2; i++) {
            int slot = i * 256 + t;
            __builtin_amdgcn_global_load_lds(
                (const __attribute__((address_space(1))) unsigned int*)
                    (A + (size_t)(bml + (slot >> 2)) * 256 + k0 + (slot & 3) * 8),
                (__attribute__((address_space(3))) unsigned int*)
                    (sA + (i * 256 + w * 64) * 8), 16, 0, 0);
            __builtin_amdgcn_global_load_lds(
                (const __attribute__((address_space(1))) unsigned int*)
                    (W + (size_t)(bn + (slot >> 2)) * 256 + k0 + (slot & 3) * 8),
                (__attribute__((address_space(3))) unsigned int*)
                    (sB + (i * 256 + w * 64) * 8), 16, 0, 0);
        }
        __syncthreads();
        s16x8 a[4], b[4];
        #pragma unroll
        for (int m = 0; m < 4; m++)
            a[m] = *(const s16x8*)&sA[(wr * 64 + m * 16 + fr) * BK + fq * 8];
        #pragma unroll
        for (int n = 0; n < 4; n++)
            b[n] = *(const s16x8*)&sB[(wc * 64 + n * 16 + fr) * BK + fq * 8];
        #pragma unroll
        for (int m = 0; m < 4; m++)
            #pragma unroll
            for (int n = 0; n < 4; n++)
                acc[m][n] = __builtin_amdgcn_mfma_f32_16x16x32_bf16(a[m], b[n], acc[m][n], 0, 0, 0);
    }

    #pragma unroll
    for (int m = 0; m < 4; m++) {
        const int row = bm + wr * 64 + m * 16 + fq * 4;
        #pragma unroll
        for (int n = 0; n < 4; n++) {
            const int col = bn + wc * 64 + n * 16 + fr;
            const float bv = bias[col];
            #pragma unroll
            for (int r = 0; r < 4; r++) {
                float v = acc[m][n][r] + bv;
                unsigned short hi = f2bf(v);
                o1[(size_t)(row + r) * 512 + col] = hi;
                if (SPLIT)
                    o2[(size_t)(row + r) * 512 + col] = f2bf(v - bf2f(hi));
            }
        }
    }
}

// ---------------- split-precision MFMA GEMM + fused attention dots ----------
// Cb = bf16(h); as_[row] += h[row,:].a_src (partial per col-block, atomic);
// ad_ likewise. as_/ad_ must be pre-zeroed.
__global__ __launch_bounds__(256) void mgemm3_k(
    const unsigned short* __restrict__ Ahi, const unsigned short* __restrict__ Alo,
    const unsigned short* __restrict__ Bhi, const unsigned short* __restrict__ Blo,
    unsigned short* __restrict__ Cb, const float* __restrict__ a_src,
    const float* __restrict__ a_dst, float* __restrict__ as_,
    float* __restrict__ ad_, int K, int lda, int ldb)
{
    constexpr int BM = 128, BN = 128, BK = 32;
    __shared__ unsigned short sAh[BM * BK], sAl[BM * BK];
    __shared__ unsigned short sBh[BN * BK], sBl[BN * BK];
    const int t = threadIdx.x, lane = t & 63, w = t >> 6;
    const int wr = w >> 1, wc = w & 1;
    const int fr = lane & 15, fq = lane >> 4;
    const int bm = blockIdx.y * BM, bn = blockIdx.x * BN;

    f32x4 acc[4][4];
    #pragma unroll
    for (int m = 0; m < 4; m++)
        #pragma unroll
        for (int n = 0; n < 4; n++)
            #pragma unroll
            for (int r = 0; r < 4; r++) acc[m][n][r] = 0.f;

    for (int k0 = 0; k0 < K; k0 += BK) {
        __syncthreads();
        #pragma unroll
        for (int i = 0; i < 2; i++) {
            int slot = i * 256 + t;
            size_t ga = (size_t)(bm + (slot >> 2)) * lda + k0 + (slot & 3) * 8;
            size_t gb = (size_t)(bn + (slot >> 2)) * ldb + k0 + (slot & 3) * 8;
            unsigned loff = (unsigned)(i * 256 + w * 64) * 8;
            __builtin_amdgcn_global_load_lds(
                (const __attribute__((address_space(1))) unsigned int*)(Ahi + ga),
                (__attribute__((address_space(3))) unsigned int*)(sAh + loff), 16, 0, 0);
            __builtin_amdgcn_global_load_lds(
                (const __attribute__((address_space(1))) unsigned int*)(Alo + ga),
                (__attribute__((address_space(3))) unsigned int*)(sAl + loff), 16, 0, 0);
            __builtin_amdgcn_global_load_lds(
                (const __attribute__((address_space(1))) unsigned int*)(Bhi + gb),
                (__attribute__((address_space(3))) unsigned int*)(sBh + loff), 16, 0, 0);
            __builtin_amdgcn_global_load_lds(
                (const __attribute__((address_space(1))) unsigned int*)(Blo + gb),
                (__attribute__((address_space(3))) unsigned int*)(sBl + loff), 16, 0, 0);
        }
        __syncthreads();
        s16x8 ah[4], al[4], bh[4], bl[4];
        #pragma unroll
        for (int m = 0; m < 4; m++) {
            int o = (wr * 64 + m * 16 + fr) * BK + fq * 8;
            ah[m] = *(const s16x8*)&sAh[o];
            al[m] = *(const s16x8*)&sAl[o];
        }
        #pragma unroll
        for (int n = 0; n < 4; n++) {
            int o = (wc * 64 + n * 16 + fr) * BK + fq * 8;
            bh[n] = *(const s16x8*)&sBh[o];
            bl[n] = *(const s16x8*)&sBl[o];
        }
        #pragma unroll
        for (int m = 0; m < 4; m++)
            #pragma unroll
            for (int n = 0; n < 4; n++) {
                acc[m][n] = __builtin_amdgcn_mfma_f32_16x16x32_bf16(ah[m], bh[n], acc[m][n], 0, 0, 0);
                acc[m][n] = __builtin_amdgcn_mfma_f32_16x16x32_bf16(ah[m], bl[n], acc[m][n], 0, 0, 0);
                acc[m][n] = __builtin_amdgcn_mfma_f32_16x16x32_bf16(al[m], bh[n], acc[m][n], 0, 0, 0);
            }
    }

    float asv[4], adv[4];
    #pragma unroll
    for (int n = 0; n < 4; n++) {
        const int col = bn + wc * 64 + n * 16 + fr;
        asv[n] = a_src[col];
        adv[n] = a_dst[col];
    }

    #pragma unroll
    for (int m = 0; m < 4; m++) {
        const int row = bm + wr * 64 + m * 16 + fq * 4;
        #pragma unroll
        for (int r = 0; r < 4; r++) {
            float s1 = 0.f, s2 = 0.f;
            #pragma unroll
            for (int n = 0; n < 4; n++) {
                const int col = bn + wc * 64 + n * 16 + fr;
                float v = acc[m][n][r];
                Cb[(size_t)(row + r) * 512 + col] = f2bf(v);
                s1 = fmaf(v, asv[n], s1);
                s2 = fmaf(v, adv[n], s2);
            }
            s1 += __shfl_xor(s1, 1); s2 += __shfl_xor(s2, 1);
            s1 += __shfl_xor(s1, 2); s2 += __shfl_xor(s2, 2);
            s1 += __shfl_xor(s1, 4); s2 += __shfl_xor(s2, 4);
            s1 += __shfl_xor(s1, 8); s2 += __shfl_xor(s2, 8);
            if (fr == 0) {
                atomicAdd(&as_[row + r], s1);
                atomicAdd(&ad_[row + r], s2);
            }
        }
    }
}

// ---------------- PV split-K MFMA GEMM (BK=64, swizzled LDS, XCD swizzle) ---
__global__ __launch_bounds__(256) void mgemm_pv_k(
    const unsigned short* __restrict__ A, const unsigned short* __restrict__ B,
    unsigned short* __restrict__ C, int kseg, size_t segstride)
{
    constexpr int BK = 64;
    __shared__ unsigned short sA[128 * BK];
    __shared__ unsigned short sB[128 * BK];
    const int t = threadIdx.x, lane = t & 63, w = t >> 6;
    const int wr = w >> 1, wc = w & 1;
    const int fr = lane & 15, fq = lane >> 4;
    const int L  = blockIdx.x + (blockIdx.y << 2) + (blockIdx.z << 6);
    const int xs = L >> 7;
    const int ys = (L & 127) & 15;
    const int zs = (L & 127) >> 4;
    const int bm = ys * 128, bn = xs * 128;
    const int kofs = zs * kseg;

    f32x4 acc[4][4];
    #pragma unroll
    for (int m = 0; m < 4; m++)
        #pragma unroll
        for (int n = 0; n < 4; n++)
            #pragma unroll
            for (int r = 0; r < 4; r++) acc[m][n][r] = 0.f;

    for (int k0 = 0; k0 < kseg; k0 += BK) {
        __syncthreads();
        #pragma unroll
        for (int i = 0; i < 4; i++) {
            int s = i * 256 + t;              // 1024 slots = 128 rows x 8 cc
            int row = s >> 3, cc = s & 7;
            int gc = kofs + k0 + ((cc ^ (row & 7)) << 3);
            __builtin_amdgcn_global_load_lds(
                (const __attribute__((address_space(1))) unsigned int*)
                    (A + (size_t)(bm + row) * 8192 + gc),
                (__attribute__((address_space(3))) unsigned int*)
                    (sA + (i * 256 + w * 64) * 8), 16, 0, 0);
            __builtin_amdgcn_global_load_lds(
                (const __attribute__((address_space(1))) unsigned int*)
                    (B + (size_t)(bn + row) * 8192 + gc),
                (__attribute__((address_space(3))) unsigned int*)
                    (sB + (i * 256 + w * 64) * 8), 16, 0, 0);
        }
        __syncthreads();
        #pragma unroll
        for (int kk = 0; kk < 2; kk++) {
            s16x8 a[4], b[4];
            #pragma unroll
            for (int m = 0; m < 4; m++) {
                int row = wr * 64 + m * 16 + fr;
                a[m] = *(const s16x8*)&sA[row * BK + (((kk * 4 + fq) ^ (row & 7)) << 3)];
            }
            #pragma unroll
            for (int n = 0; n < 4; n++) {
                int row = wc * 64 + n * 16 + fr;
                b[n] = *(const s16x8*)&sB[row * BK + (((kk * 4 + fq) ^ (row & 7)) << 3)];
            }
            #pragma unroll
            for (int m = 0; m < 4; m++)
                #pragma unroll
                for (int n = 0; n < 4; n++)
                    acc[m][n] = __builtin_amdgcn_mfma_f32_16x16x32_bf16(a[m], b[n], acc[m][n], 0, 0, 0);
        }
    }

    unsigned short* Cz = C + (size_t)zs * segstride;
    #pragma unroll
    for (int m = 0; m < 4; m++) {
        const int row = bm + wr * 64 + m * 16 + fq * 4;
        #pragma unroll
        for (int n = 0; n < 4; n++) {
            const int col = bn + wc * 64 + n * 16 + fr;
            #pragma unroll
            for (int r = 0; r < 4; r++)
                Cz[(size_t)(row + r) * 512 + col] = f2bf(acc[m][n][r]);
        }
    }
}

// ---------------- reduce bf16 split-K partials, divide by denom -> bf16 ----
__global__ __launch_bounds__(256) void radd_k(const unsigned short* __restrict__ src,
                                              unsigned short* __restrict__ dst,
                                              const float* __restrict__ dn,
                                              int n8, int segs, size_t stride8) {
    int i = blockIdx.x * 256 + threadIdx.x;
    if (i >= n8) return;
    float acc[8] = {0,0,0,0,0,0,0,0};
    for (int s = 0; s < segs; s++) {
        s16x8 v = ((const s16x8*)src)[i + s * stride8];
        #pragma unroll
        for (int j = 0; j < 8; j++) acc[j] += bf2f((unsigned short)v[j]);
    }
    const float rd = 1.0f / dn[i >> 6];    // 64 groups of 8 per 512-col row
    s16x8 o;
    #pragma unroll
    for (int j = 0; j < 8; j++) o[j] = (short)f2bf(acc[j] * rd);
    ((s16x8*)dst)[i] = o;
}

// ---------------- qkv MFMA GEMM with split epilogue (scale folded into q) ---
__global__ __launch_bounds__(256) void mgemm_qkv_k(
    const unsigned short* __restrict__ A, const unsigned short* __restrict__ B,
    const float* __restrict__ bias, float scale,
    unsigned short* __restrict__ qb, unsigned short* __restrict__ kb,
    unsigned short* __restrict__ vb)
{
    constexpr int BM = 128, BN = 128, BK = 32;
    __shared__ unsigned short sA[BM * BK];
    __shared__ unsigned short sB[BN * BK];
    const int t = threadIdx.x, lane = t & 63, w = t >> 6;
    const int wr = w >> 1, wc = w & 1;
    const int fr = lane & 15, fq = lane >> 4;
    const int bm = blockIdx.y * BM, bn = blockIdx.x * BN;

    f32x4 acc[4][4];
    #pragma unroll
    for (int m = 0; m < 4; m++)
        #pragma unroll
        for (int n = 0; n < 4; n++)
            #pragma unroll
            for (int r = 0; r < 4; r++) acc[m][n][r] = 0.f;

    for (int k0 = 0; k0 < 512; k0 += BK) {
        __syncthreads();
        #pragma unroll
        for (int i = 0; i < 2; i++) {
            int slot = i * 256 + t;
            __builtin_amdgcn_global_load_lds(
                (const __attribute__((address_space(1))) unsigned int*)
                    (A + (size_t)(bm + (slot >> 2)) * 512 + k0 + (slot & 3) * 8),
                (__attribute__((address_space(3))) unsigned int*)
                    (sA + (i * 256 + w * 64) * 8), 16, 0, 0);
            __builtin_amdgcn_global_load_lds(
                (const __attribute__((address_space(1))) unsigned int*)
                    (B + (size_t)(bn + (slot >> 2)) * 512 + k0 + (slot & 3) * 8),
                (__attribute__((address_space(3))) unsigned int*)
                    (sB + (i * 256 + w * 64) * 8), 16, 0, 0);
        }
        __syncthreads();
        s16x8 a[4], b[4];
        #pragma unroll
        for (int m = 0; m < 4; m++)
            a[m] = *(const s16x8*)&sA[(wr * 64 + m * 16 + fr) * BK + fq * 8];
        #pragma unroll
        for (int n = 0; n < 4; n++)
            b[n] = *(const s16x8*)&sB[(wc * 64 + n * 16 + fr) * BK + fq * 8];
        #pragma unroll
        for (int m = 0; m < 4; m++)
            #pragma unroll
            for (int n = 0; n < 4; n++)
                acc[m][n] = __builtin_amdgcn_mfma_f32_16x16x32_bf16(a[m], b[n], acc[m][n], 0, 0, 0);
    }

    #pragma unroll
    for (int m = 0; m < 4; m++) {
        const int row = bm + wr * 64 + m * 16 + fq * 4;
        #pragma unroll
        for (int n = 0; n < 4; n++) {
            const int col = bn + wc * 64 + n * 16 + fr;
            const float bv = bias[col];
            #pragma unroll
            for (int r = 0; r < 4; r++) {
                float v = acc[m][n][r] + bv;
                if (col < 512)
                    qb[(size_t)(row + r) * 512 + col] = f2bf(v * scale);
                else if (col < 1024)
                    kb[(size_t)(row + r) * 512 + (col - 512)] = f2bf(v);
                else
                    vb[(size_t)(row + r) * 512 + (col - 1024)] = f2bf(v);
            }
        }
    }
}

// ---------------- bf16 transpose: vb[8192][512] -> vT[512][8192] ------------
__global__ __launch_bounds__(256) void trT_k(const unsigned short* __restrict__ vb,
                                             unsigned short* __restrict__ vT) {
    __shared__ unsigned short s[64][65];
    const int t = threadIdx.x;
    const int rowo = blockIdx.y * 64;
    const int colo = blockIdx.x * 64;
    {
        int r = t >> 2, cg = (t & 3) * 16;
        const s16x8* src = (const s16x8*)(vb + (size_t)(rowo + r) * 512 + colo + cg);
        s16x8 u0 = src[0], u1 = src[1];
        #pragma unroll
        for (int j = 0; j < 8; j++) {
            s[r][cg + j]     = (unsigned short)u0[j];
            s[r][cg + 8 + j] = (unsigned short)u1[j];
        }
    }
    __syncthreads();
    {
        int c = t >> 2, rg = (t & 3) * 16;
        s16x8 o0, o1;
        #pragma unroll
        for (int j = 0; j < 8; j++) {
            o0[j] = (short)s[rg + j][c];
            o1[j] = (short)s[rg + 8 + j][c];
        }
        s16x8* dst = (s16x8*)(vT + (size_t)(colo + c) * 8192 + rowo + rg);
        dst[0] = o0; dst[1] = o1;
    }
}

// ---------------- CSR build ------------------------------------------------
__global__ void count_deg_k(const int* eAB, const int* eBA, int* deg) {
    int i = blockIdx.x * 256 + threadIdx.x;
    if (i >= NE_) return;
    int s, d; edge_sd(i, eAB, eBA, s, d);
    atomicAdd(&deg[d], 1);
}

__global__ __launch_bounds__(256) void scan_k(const int* __restrict__ deg, int* rowstart) {
    __shared__ int part[256];
    int t = threadIdx.x;
    int base = t * 32;
    int loc[32]; int s = 0;
    #pragma unroll
    for (int j = 0; j < 32; j++) { loc[j] = s; s += deg[base + j]; }
    part[t] = s;
    __syncthreads();
    if (t == 0) {
        int a = 0;
        for (int i = 0; i < 256; i++) { int v = part[i]; part[i] = a; a += v; }
        rowstart[NN_] = a;
    }
    __syncthreads();
    int off = part[t];
    #pragma unroll
    for (int j = 0; j < 32; j++) rowstart[base + j] = off + loc[j];
}

// stores src node per CSR slot + slot index per edge (kills indirection later)
__global__ void fill_csr_k(const int* eAB, const int* eBA,
                           const int* __restrict__ rowstart, int* cursor,
                           int* csr_src, int* pos) {
    int i = blockIdx.x * 256 + threadIdx.x;
    if (i >= NE_) return;
    int s, d; edge_sd(i, eAB, eBA, s, d);
    int p = atomicAdd(&cursor[d], 1);
    int slot = rowstart[d] + p;
    csr_src[slot] = s;
    pos[i] = slot;
}

// ---------------- GAT edge passes ------------------------------------------
__global__ void edge_pass1_k(const int* eAB, const int* eBA,
                             const float* __restrict__ as_, const float* __restrict__ ad_,
                             float* evals, unsigned* mkey) {
    int i = blockIdx.x * 256 + threadIdx.x;
    if (i >= NE_) return;
    int s, d; edge_sd(i, eAB, eBA, s, d);
    float e = as_[s] + ad_[d];
    e = (e >= 0.f) ? e : NEG_SLOPE_ * e;
    evals[i] = e;
    atomicMax(&mkey[d], fkey(e));
}

// scatters exp into CSR order (evs) + accumulates denom
__global__ void edge_pass2_k(const int* eAB, const int* eBA,
                             const unsigned* __restrict__ mkey,
                             const float* __restrict__ evals,
                             const int* __restrict__ pos,
                             float* __restrict__ evs, float* denom) {
    int i = blockIdx.x * 256 + threadIdx.x;
    if (i >= NE_) return;
    int s, d; edge_sd(i, eAB, eBA, s, d);
    float m = finv(mkey[d]);
    float ex = expf(evals[i] - m);
    evs[pos[i]] = ex;
    atomicAdd(&denom[d], ex);
}

// ---------------- GAT aggregation: single pass, streaming CSR ---------------
template<bool SPLIT>
__global__ __launch_bounds__(256) void gat_agg_k(
    const int* __restrict__ rowstart, const int* __restrict__ csr_src,
    const float* __restrict__ evs, const float* __restrict__ denom,
    const unsigned short* __restrict__ hb, const float* __restrict__ bias,
    float* __restrict__ outF, int ldo,
    unsigned short* __restrict__ outHi, unsigned short* __restrict__ outLo)
{
    int wid  = (blockIdx.x * 256 + threadIdx.x) >> 6;
    int lane = threadIdx.x & 63;
    if (wid >= NN_) return;
    float acc[8] = {0.f,0.f,0.f,0.f,0.f,0.f,0.f,0.f};
    int beg = rowstart[wid], end = rowstart[wid + 1];
    float rden = 1.0f / denom[wid];
    for (int p = beg; p < end; p++) {
        int s = csr_src[p];
        float alpha = evs[p] * rden;
        s16x8 hv = *(const s16x8*)(hb + (size_t)s * HH_ + lane * 8);
        #pragma unroll
        for (int j = 0; j < 8; j++)
            acc[j] = fmaf(alpha, bf2f((unsigned short)hv[j]), acc[j]);
    }
    #pragma unroll
    for (int j = 0; j < 8; j++) acc[j] += bias[lane * 8 + j];
    if (SPLIT) {
        s16x8 hi, lo;
        #pragma unroll
        for (int j = 0; j < 8; j++) {
            unsigned short h = f2bf(acc[j]);
            hi[j] = (short)h;
            lo[j] = (short)f2bf(acc[j] - bf2f(h));
        }
        *(s16x8*)(outHi + (size_t)wid * HH_ + lane * 8) = hi;
        *(s16x8*)(outLo + (size_t)wid * HH_ + lane * 8) = lo;
    } else {
        float* o = outF + (size_t)wid * ldo + lane * 8;
        *(float4*)(o)     = make_float4(acc[0], acc[1], acc[2], acc[3]);
        *(float4*)(o + 4) = make_float4(acc[4], acc[5], acc[6], acc[7]);
    }
}

// ===========================================================================
extern "C" void kernel_launch(void* const* d_in, const int* in_sizes, int n_in,
                              void* d_out, int out_size, void* d_ws, size_t ws_size,
                              hipStream_t stream)
{
    const float* x_A    = (const float*)d_in[0];
    const float* x_B    = (const float*)d_in[1];
    const int*   eAB    = (const int*)d_in[2];
    const int*   eBA    = (const int*)d_in[3];
    const float* W_inA  = (const float*)d_in[4];  const float* b_inA  = (const float*)d_in[5];
    const float* W_inB  = (const float*)d_in[6];  const float* b_inB  = (const float*)d_in[7];
    const float* W_in2A = (const float*)d_in[8];  const float* b_in2A = (const float*)d_in[9];
    const float* W_in2B = (const float*)d_in[10]; const float* b_in2B = (const float*)d_in[11];
    const float* Wg1    = (const float*)d_in[12]; const float* a_src1 = (const float*)d_in[13];
    const float* a_dst1 = (const float*)d_in[14]; const float* bg1    = (const float*)d_in[15];
    const float* Wg2    = (const float*)d_in[16]; const float* a_src2 = (const float*)d_in[17];
    const float* a_dst2 = (const float*)d_in[18]; const float* bg2    = (const float*)d_in[19];
    const float* Wqkv   = (const float*)d_in[20]; const float* bqkv   = (const float*)d_in[21];
    const float* Wo     = (const float*)d_in[22]; const float* bo     = (const float*)d_in[23];

    float* out = (float*)d_out;

    char* base = (char*)d_ws;
    size_t off = 0;
    auto alloc = [&](size_t nb) -> char* {
        char* p = base + off;
        off = (off + nb + 255) & ~(size_t)255;
        return p;
    };

    // bufA and bufB MUST be adjacent: Sb (32MB) spans both during attention.
    float*          bufA  = (float*)alloc((size_t)NN_ * 512 * 4);
    float*          bufB  = (float*)alloc((size_t)NN_ * 512 * 4);
    float*          bufC  = (float*)alloc((size_t)NN_ * 512 * 4);
    // as_..cdn contiguous: one initial memset covers all seven
    float*          as_   = (float*)alloc(NN_ * 4);
    float*          ad_   = (float*)alloc(NN_ * 4);
    unsigned*       mkey  = (unsigned*)alloc(NN_ * 4);
    float*          denom = (float*)alloc(NN_ * 4);
    int*            deg   = (int*)alloc(NN_ * 4);
    int*            cursor= (int*)alloc(NN_ * 4);
    float*          cdn   = (float*)alloc(NN_ * 4);    // per-chunk attn denoms
    int*            rowst = (int*)alloc((NN_ + 1) * 4);
    float*          evals = (float*)alloc((size_t)NE_ * 4);
    int*            csrs  = (int*)alloc((size_t)NE_ * 4);   // src per CSR slot
    int*            pos   = (int*)alloc((size_t)NE_ * 4);   // edge -> CSR slot
    float*          evs   = (float*)alloc((size_t)NE_ * 4); // exp in CSR order
    unsigned short* xbA   = (unsigned short*)alloc((size_t)NA_ * 256 * 2);
    unsigned short* xbB   = (unsigned short*)alloc((size_t)NB_ * 256 * 2);
    unsigned short* WbinA = (unsigned short*)alloc((size_t)512 * 256 * 2);
    unsigned short* WbinB = (unsigned short*)alloc((size_t)512 * 256 * 2);
    unsigned short* Wbin2A= (unsigned short*)alloc((size_t)512 * 256 * 2);
    unsigned short* Wbin2B= (unsigned short*)alloc((size_t)512 * 256 * 2);
    unsigned short* Wbqkv = (unsigned short*)alloc((size_t)1536 * 512 * 2);
    unsigned short* Wbo   = (unsigned short*)alloc((size_t)512 * 512 * 2);
    unsigned short* Wg1hi = (unsigned short*)alloc((size_t)512 * 512 * 2);
    unsigned short* Wg1lo = (unsigned short*)alloc((size_t)512 * 512 * 2);
    unsigned short* Wg2hi = (unsigned short*)alloc((size_t)512 * 512 * 2);
    unsigned short* Wg2lo = (unsigned short*)alloc((size_t)512 * 512 * 2);
    unsigned short* qb    = (unsigned short*)alloc((size_t)NN_ * 512 * 2);
    unsigned short* kb    = (unsigned short*)alloc((size_t)NN_ * 512 * 2);
    unsigned short* vT    = (unsigned short*)alloc((size_t)512 * NN_ * 2);
    unsigned short* ab    = (unsigned short*)alloc((size_t)NN_ * 512 * 2);

    // overlays
    unsigned short* hb = vT;                              // bf16 h (local branch)
    unsigned short* gb = (unsigned short*)bufC;           // g bf16 (global, pre-loop)
    unsigned short* vb = gb + (size_t)NN_ * 512;          // v bf16 (global, pre-loop)
    unsigned short* Sb = (unsigned short*)bufA;           // scores: bufA+bufB = 32MB
    unsigned short* pv = (unsigned short*)bufC;           // PV bf16 partials (16MB)

    const int R = 2048, SEGS = 8, KSEG = 8192 / SEGS;
    const int EG = (NE_ + 255) / 256;
    const float scale2 = 0.044194173824159216f * 1.4426950408889634f; // /sqrt(512)*log2e

    // -------- all weight/input casts in ONE launch --------------------------
    CvtJobs jobs;
    jobs.j[0] = { x_A,    xbA,    nullptr, NA_ * 256 / 4 };
    jobs.j[1] = { x_B,    xbB,    nullptr, NB_ * 256 / 4 };
    jobs.j[2] = { W_inA,  WbinA,  nullptr, 512 * 256 / 4 };
    jobs.j[3] = { W_inB,  WbinB,  nullptr, 512 * 256 / 4 };
    jobs.j[4] = { W_in2A, Wbin2A, nullptr, 512 * 256 / 4 };
    jobs.j[5] = { W_in2B, Wbin2B, nullptr, 512 * 256 / 4 };
    jobs.j[6] = { Wqkv,   Wbqkv,  nullptr, 1536 * 512 / 4 };
    jobs.j[7] = { Wo,     Wbo,    nullptr, 512 * 512 / 4 };
    jobs.j[8] = { Wg1,    Wg1hi,  Wg1lo,   512 * 512 / 4 };
    jobs.j[9] = { Wg2,    Wg2hi,  Wg2lo,   512 * 512 / 4 };
    cvt_all_k<<<dim3(NA_ * 256 / 4 / 256, 10), 256, 0, stream>>>(jobs);

    // zero as_, ad_, mkey, denom, deg, cursor, cdn in one shot
    hipMemsetAsync(as_, 0, (size_t)NN_ * 4 * 7, stream);

    // -------- CSR build -----------------------------------------------------
    count_deg_k<<<EG, 256, 0, stream>>>(eAB, eBA, deg);
    scan_k<<<1, 256, 0, stream>>>(deg, rowst);
    fill_csr_k<<<EG, 256, 0, stream>>>(eAB, eBA, rowst, cursor, csrs, pos);

    // -------- local branch --------------------------------------------------
    mgemm_in_k<true><<<dim3(4, 64), 256, 0, stream>>>(
        xbA, xbB, WbinA, WbinB, b_inA, b_inB, qb, kb);
    mgemm3_k<<<dim3(4, 64), 256, 0, stream>>>(qb, kb, Wg1hi, Wg1lo,
                                              hb, a_src1, a_dst1, as_, ad_,
                                              512, 512, 512);
    edge_pass1_k<<<EG, 256, 0, stream>>>(eAB, eBA, as_, ad_, evals, mkey);
    edge_pass2_k<<<EG, 256, 0, stream>>>(eAB, eBA, mkey, evals, pos, evs, denom);
    gat_agg_k<true><<<NN_/4, 256, 0, stream>>>(rowst, csrs, evs, denom,
                                               hb, bg1, nullptr, 0, qb, kb);
    hipMemsetAsync(as_, 0, NN_ * 16, stream);           // as_, ad_, mkey, denom
    mgemm3_k<<<dim3(4, 64), 256, 0, stream>>>(qb, kb, Wg2hi, Wg2lo,
                                              hb, a_src2, a_dst2, as_, ad_,
                                              512, 512, 512);
    edge_pass1_k<<<EG, 256, 0, stream>>>(eAB, eBA, as_, ad_, evals, mkey);
    edge_pass2_k<<<EG, 256, 0, stream>>>(eAB, eBA, mkey, evals, pos, evs, denom);
    // layer-2 aggregation writes the local half of d_out directly (ldo=1024)
    gat_agg_k<false><<<NN_/4, 256, 0, stream>>>(rowst, csrs, evs, denom,
                                                hb, bg2, out, 1024, nullptr, nullptr);

    // -------- global branch -------------------------------------------------
    mgemm_in_k<false><<<dim3(4, 64), 256, 0, stream>>>(
        xbA, xbB, Wbin2A, Wbin2B, b_in2A, b_in2B, gb, nullptr);
    mgemm_qkv_k<<<dim3(12, 64), 256, 0, stream>>>(gb, Wbqkv, bqkv, scale2, qb, kb, vb);
    trT_k<<<dim3(8, 128), 256, 0, stream>>>(vb, vT);
    for (int c0 = 0; c0 < 8192; c0 += R) {
        float* dn = cdn + c0;   // this chunk's 2048 denominators (pre-zeroed)
        mgemm_qk_k<<<dim3(32, 8), 512, 0, stream>>>(
            qb + (size_t)c0 * 512, kb, Sb, dn);
        mgemm_pv_k<<<dim3(4, R/128, SEGS), 256, 0, stream>>>(
            Sb, vT, pv, KSEG, (size_t)R * 512);
        radd_k<<<(R*512/8 + 255)/256, 256, 0, stream>>>(
            pv, ab + (size_t)c0 * 512, dn, R*512/8, SEGS, (size_t)R*512/8);
    }
    // Wo GEMM writes the global half of d_out directly (ldc=1024, col offset 512)
    mgemm_k<128,128,true,float><<<dim3(4, 64), 256, 0, stream>>>(
        ab, Wbo, bo, out + 512, 512, 512, 512, 1024);
}

// Round 15
// 563.210 us; speedup vs baseline: 1.2478x; 1.0721x over previous
//
#include <hip/hip_runtime.h>
#include <hip/hip_bf16.h>

#define NA_ 4096
#define NB_ 4096
#define NN_ 8192            // total nodes
#define EE_ 131072          // edges per direction
#define NE_ (2*EE_ + NN_)   // homogeneous edges incl. self loops = 270336
#define HH_ 512
#define NEG_SLOPE_ 0.2f

typedef __attribute__((ext_vector_type(4))) float f32x4;
typedef __attribute__((ext_vector_type(8))) short s16x8;

__device__ inline unsigned short f2bf(float v) {
    __hip_bfloat16 h = __float2bfloat16(v);
    return __builtin_bit_cast(unsigned short, h);
}
__device__ inline float bf2f(unsigned short u) {
    return __uint_as_float(((unsigned)u) << 16);
}

// ---------------- homogeneous edge id -> (src, dst) ------------------------
__device__ inline void edge_sd(int i, const int* __restrict__ eAB,
                               const int* __restrict__ eBA, int& s, int& d) {
    if (i < EE_)            { s = eAB[i];            d = eAB[EE_ + i] + NA_; }
    else if (i < 2 * EE_)   { int j = i - EE_; s = eBA[j] + NA_; d = eBA[EE_ + j]; }
    else                    { s = i - 2 * EE_;       d = s; }
}

// ---------------- batched f32 -> bf16 (optionally split hi/lo) casts --------
struct CvtJob { const float* s; unsigned short* hi; unsigned short* lo; int n4; };
struct CvtJobs { CvtJob j[10]; };

__global__ __launch_bounds__(256) void cvt_all_k(CvtJobs jobs) {
    const CvtJob jb = jobs.j[blockIdx.y];
    int i = blockIdx.x * 256 + threadIdx.x;
    if (i >= jb.n4) return;
    float4 v = ((const float4*)jb.s)[i];
    ushort4 h;
    h.x = f2bf(v.x); h.y = f2bf(v.y); h.z = f2bf(v.z); h.w = f2bf(v.w);
    ((ushort4*)jb.hi)[i] = h;
    if (jb.lo) {
        ushort4 l;
        l.x = f2bf(v.x - bf2f(h.x));
        l.y = f2bf(v.y - bf2f(h.y));
        l.z = f2bf(v.z - bf2f(h.z));
        l.w = f2bf(v.w - bf2f(h.w));
        ((ushort4*)jb.lo)[i] = l;
    }
}

// ---------------- MFMA bf16 GEMM: C[M,N] = A @ B^T (+bias) -----------------
template<int BM, int BN, bool BIAS, typename OutT>
__global__ __launch_bounds__(256) void mgemm_k(
    const unsigned short* __restrict__ A, const unsigned short* __restrict__ B,
    const float* __restrict__ bias, OutT* __restrict__ C,
    int K, int lda, int ldb, int ldc)
{
    constexpr int BK = 32;
    constexpr int WM = BM / 2, WN = BN / 2;
    constexpr int AM = WM / 16, AN = WN / 16;
    constexpr int AISS = BM * 4 / 256, BISS = BN * 4 / 256;
    __shared__ unsigned short sA[BM * BK];
    __shared__ unsigned short sB[BN * BK];
    const int t = threadIdx.x, lane = t & 63, w = t >> 6;
    const int wr = w >> 1, wc = w & 1;
    const int fr = lane & 15, fq = lane >> 4;
    const int bm = blockIdx.y * BM, bn = blockIdx.x * BN;

    f32x4 acc[AM][AN];
    #pragma unroll
    for (int m = 0; m < AM; m++)
        #pragma unroll
        for (int n = 0; n < AN; n++)
            #pragma unroll
            for (int r = 0; r < 4; r++) acc[m][n][r] = 0.f;

    for (int k0 = 0; k0 < K; k0 += BK) {
        __syncthreads();
        #pragma unroll
        for (int i = 0; i < AISS; i++) {
            int slot = i * 256 + t;
            __builtin_amdgcn_global_load_lds(
                (const __attribute__((address_space(1))) unsigned int*)
                    (A + (size_t)(bm + (slot >> 2)) * lda + k0 + (slot & 3) * 8),
                (__attribute__((address_space(3))) unsigned int*)
                    (sA + (i * 256 + w * 64) * 8), 16, 0, 0);
        }
        #pragma unroll
        for (int i = 0; i < BISS; i++) {
            int slot = i * 256 + t;
            __builtin_amdgcn_global_load_lds(
                (const __attribute__((address_space(1))) unsigned int*)
                    (B + (size_t)(bn + (slot >> 2)) * ldb + k0 + (slot & 3) * 8),
                (__attribute__((address_space(3))) unsigned int*)
                    (sB + (i * 256 + w * 64) * 8), 16, 0, 0);
        }
        __syncthreads();
        s16x8 a[AM], b[AN];
        #pragma unroll
        for (int m = 0; m < AM; m++)
            a[m] = *(const s16x8*)&sA[(wr * WM + m * 16 + fr) * BK + fq * 8];
        #pragma unroll
        for (int n = 0; n < AN; n++)
            b[n] = *(const s16x8*)&sB[(wc * WN + n * 16 + fr) * BK + fq * 8];
        #pragma unroll
        for (int m = 0; m < AM; m++)
            #pragma unroll
            for (int n = 0; n < AN; n++)
                acc[m][n] = __builtin_amdgcn_mfma_f32_16x16x32_bf16(a[m], b[n], acc[m][n], 0, 0, 0);
    }

    // C/D layout: col = lane&15, row = (lane>>4)*4 + reg
    #pragma unroll
    for (int m = 0; m < AM; m++) {
        const int row = bm + wr * WM + m * 16 + fq * 4;
        #pragma unroll
        for (int n = 0; n < AN; n++) {
            const int col = bn + wc * WN + n * 16 + fr;
            const float bv = BIAS ? bias[col] : 0.f;
            #pragma unroll
            for (int r = 0; r < 4; r++) {
                float v = acc[m][n][r] + bv;
                if constexpr (sizeof(OutT) == 2)
                    C[(size_t)(row + r) * ldc + col] = (OutT)f2bf(v);
                else
                    C[(size_t)(row + r) * ldc + col] = v;
            }
        }
    }
}

// ---------------- QK^T: 256x256 tile, 8 waves, BK=64, swizzled LDS ----------
// q pre-scaled by scale*log2e -> P = 2^(q.k); denom[row] += row-sum (atomic).
// Epilogue stages 64-row bands of exp2'd P in LDS, then stores 16B-coalesced.
__global__ __launch_bounds__(512) void mgemm_qk_k(
    const unsigned short* __restrict__ A, const unsigned short* __restrict__ B,
    unsigned short* __restrict__ C, float* __restrict__ denom)
{
    constexpr int BK = 64;
    __shared__ unsigned short smem[32768];    // 64KB: sA|sB, reused as P-tile
    unsigned short* sA = smem;
    unsigned short* sB = smem + 16384;
    unsigned short* tile = smem;              // 64 x 264 (33KB) in epilogue
    const int t = threadIdx.x, lane = t & 63, w = t >> 6;   // 8 waves
    const int wr = w >> 2, wc = w & 3;        // 2 (M) x 4 (N)
    const int fr = lane & 15, fq = lane >> 4;
    const int bm = blockIdx.y * 256, bn = blockIdx.x * 256;

    f32x4 acc[8][4];
    #pragma unroll
    for (int m = 0; m < 8; m++)
        #pragma unroll
        for (int n = 0; n < 4; n++)
            #pragma unroll
            for (int r = 0; r < 4; r++) acc[m][n][r] = 0.f;

    for (int k0 = 0; k0 < 512; k0 += BK) {
        __syncthreads();
        #pragma unroll
        for (int i = 0; i < 4; i++) {
            int s = i * 512 + t;              // 2048 slots = 256 rows x 8 cc
            int row = s >> 3, cc = s & 7;
            int gc = k0 + ((cc ^ (row & 7)) << 3);
            __builtin_amdgcn_global_load_lds(
                (const __attribute__((address_space(1))) unsigned int*)
                    (A + (size_t)(bm + row) * 512 + gc),
                (__attribute__((address_space(3))) unsigned int*)
                    (sA + (i * 512 + w * 64) * 8), 16, 0, 0);
            __builtin_amdgcn_global_load_lds(
                (const __attribute__((address_space(1))) unsigned int*)
                    (B + (size_t)(bn + row) * 512 + gc),
                (__attribute__((address_space(3))) unsigned int*)
                    (sB + (i * 512 + w * 64) * 8), 16, 0, 0);
        }
        __syncthreads();
        #pragma unroll
        for (int kk = 0; kk < 2; kk++) {
            s16x8 a[8], b[4];
            #pragma unroll
            for (int m = 0; m < 8; m++) {
                int row = wr * 128 + m * 16 + fr;
                a[m] = *(const s16x8*)&sA[row * BK + (((kk * 4 + fq) ^ (row & 7)) << 3)];
            }
            #pragma unroll
            for (int n = 0; n < 4; n++) {
                int row = wc * 64 + n * 16 + fr;
                b[n] = *(const s16x8*)&sB[row * BK + (((kk * 4 + fq) ^ (row & 7)) << 3)];
            }
            #pragma unroll
            for (int m = 0; m < 8; m++)
                #pragma unroll
                for (int n = 0; n < 4; n++)
                    acc[m][n] = __builtin_amdgcn_mfma_f32_16x16x32_bf16(a[m], b[n], acc[m][n], 0, 0, 0);
        }
    }

    // epilogue: 4 phases, each 64 rows (m-pair) staged in LDS, coalesced store
    #pragma unroll
    for (int h = 0; h < 4; h++) {
        __syncthreads();
        #pragma unroll
        for (int mm = 0; mm < 2; mm++) {
            const int m = h * 2 + mm;
            #pragma unroll
            for (int r = 0; r < 4; r++) {
                float rsum = 0.f;
                #pragma unroll
                for (int n = 0; n < 4; n++) {
                    float p = exp2f(acc[m][n][r]);
                    rsum += p;
                    tile[(wr * 32 + mm * 16 + fq * 4 + r) * 264 + wc * 64 + n * 16 + fr]
                        = f2bf(p);
                }
                rsum += __shfl_xor(rsum, 1);
                rsum += __shfl_xor(rsum, 2);
                rsum += __shfl_xor(rsum, 4);
                rsum += __shfl_xor(rsum, 8);
                if (fr == 0)
                    atomicAdd(&denom[bm + wr * 128 + h * 32 + mm * 16 + fq * 4 + r], rsum);
            }
        }
        __syncthreads();
        #pragma unroll
        for (int j = 0; j < 4; j++) {
            int cj = j * 512 + t;             // 2048 chunks = 64 rows x 32
            int row_l = cj >> 5, c16 = cj & 31;
            int grow = bm + (row_l >> 5) * 128 + h * 32 + (row_l & 31);
            *(s16x8*)(C + (size_t)grow * 8192 + bn + c16 * 8)
                = *(const s16x8*)&tile[row_l * 264 + c16 * 8];
        }
    }
}

// ---------------- merged per-type input linear (A rows 0..4095, B rows 4096+)
template<bool SPLIT>
__global__ __launch_bounds__(256) void mgemm_in_k(
    const unsigned short* __restrict__ xA, const unsigned short* __restrict__ xB,
    const unsigned short* __restrict__ WA, const unsigned short* __restrict__ WB,
    const float* __restrict__ biasA, const float* __restrict__ biasB,
    unsigned short* __restrict__ o1, unsigned short* __restrict__ o2)
{
    constexpr int BK = 32;
    __shared__ unsigned short sA[128 * BK];
    __shared__ unsigned short sB[128 * BK];
    const int t = threadIdx.x, lane = t & 63, w = t >> 6;
    const int wr = w >> 1, wc = w & 1;
    const int fr = lane & 15, fq = lane >> 4;
    const int bm = blockIdx.y * 128, bn = blockIdx.x * 128;
    const bool isB = bm >= NA_;
    const unsigned short* A = isB ? xB : xA;
    const unsigned short* W = isB ? WB : WA;
    const float* bias = isB ? biasB : biasA;
    const int bml = bm - (isB ? NA_ : 0);

    f32x4 acc[4][4];
    #pragma unroll
    for (int m = 0; m < 4; m++)
        #pragma unroll
        for (int n = 0; n < 4; n++)
            #pragma unroll
            for (int r = 0; r < 4; r++) acc[m][n][r] = 0.f;

    for (int k0 = 0; k0 < 256; k0 += BK) {
        __syncthreads();
        #pragma unroll
        for (int i = 0; i < 2; i++) {
            int slot = i * 256 + t;
            __builtin_amdgcn_global_load_lds(
                (const __attribute__((address_space(1))) unsigned int*)
                    (A + (size_t)(bml + (slot >> 2)) * 256 + k0 + (slot & 3) * 8),
                (__attribute__((address_space(3))) unsigned int*)
                    (sA + (i * 256 + w * 64) * 8), 16, 0, 0);
            __builtin_amdgcn_global_load_lds(
                (const __attribute__((address_space(1))) unsigned int*)
                    (W + (size_t)(bn + (slot >> 2)) * 256 + k0 + (slot & 3) * 8),
                (__attribute__((address_space(3))) unsigned int*)
                    (sB + (i * 256 + w * 64) * 8), 16, 0, 0);
        }
        __syncthreads();
        s16x8 a[4], b[4];
        #pragma unroll
        for (int m = 0; m < 4; m++)
            a[m] = *(const s16x8*)&sA[(wr * 64 + m * 16 + fr) * BK + fq * 8];
        #pragma unroll
        for (int n = 0; n < 4; n++)
            b[n] = *(const s16x8*)&sB[(wc * 64 + n * 16 + fr) * BK + fq * 8];
        #pragma unroll
        for (int m = 0; m < 4; m++)
            #pragma unroll
            for (int n = 0; n < 4; n++)
                acc[m][n] = __builtin_amdgcn_mfma_f32_16x16x32_bf16(a[m], b[n], acc[m][n], 0, 0, 0);
    }

    #pragma unroll
    for (int m = 0; m < 4; m++) {
        const int row = bm + wr * 64 + m * 16 + fq * 4;
        #pragma unroll
        for (int n = 0; n < 4; n++) {
            const int col = bn + wc * 64 + n * 16 + fr;
            const float bv = bias[col];
            #pragma unroll
            for (int r = 0; r < 4; r++) {
                float v = acc[m][n][r] + bv;
                unsigned short hi = f2bf(v);
                o1[(size_t)(row + r) * 512 + col] = hi;
                if (SPLIT)
                    o2[(size_t)(row + r) * 512 + col] = f2bf(v - bf2f(hi));
            }
        }
    }
}

// ---------------- split-A MFMA GEMM (2 MFMA) + fused attention dots ---------
// C = (Ahi+Alo) @ Bhi^T ; Cb = bf16(C); as_/ad_ += partial row dots (atomic).
__global__ __launch_bounds__(256) void mgemm3_k(
    const unsigned short* __restrict__ Ahi, const unsigned short* __restrict__ Alo,
    const unsigned short* __restrict__ Bhi,
    unsigned short* __restrict__ Cb, const float* __restrict__ a_src,
    const float* __restrict__ a_dst, float* __restrict__ as_,
    float* __restrict__ ad_, int K, int lda, int ldb)
{
    constexpr int BM = 128, BN = 128, BK = 32;
    __shared__ unsigned short sAh[BM * BK], sAl[BM * BK];
    __shared__ unsigned short sBh[BN * BK];
    const int t = threadIdx.x, lane = t & 63, w = t >> 6;
    const int wr = w >> 1, wc = w & 1;
    const int fr = lane & 15, fq = lane >> 4;
    const int bm = blockIdx.y * BM, bn = blockIdx.x * BN;

    f32x4 acc[4][4];
    #pragma unroll
    for (int m = 0; m < 4; m++)
        #pragma unroll
        for (int n = 0; n < 4; n++)
            #pragma unroll
            for (int r = 0; r < 4; r++) acc[m][n][r] = 0.f;

    for (int k0 = 0; k0 < K; k0 += BK) {
        __syncthreads();
        #pragma unroll
        for (int i = 0; i < 2; i++) {
            int slot = i * 256 + t;
            size_t ga = (size_t)(bm + (slot >> 2)) * lda + k0 + (slot & 3) * 8;
            size_t gb = (size_t)(bn + (slot >> 2)) * ldb + k0 + (slot & 3) * 8;
            unsigned loff = (unsigned)(i * 256 + w * 64) * 8;
            __builtin_amdgcn_global_load_lds(
                (const __attribute__((address_space(1))) unsigned int*)(Ahi + ga),
                (__attribute__((address_space(3))) unsigned int*)(sAh + loff), 16, 0, 0);
            __builtin_amdgcn_global_load_lds(
                (const __attribute__((address_space(1))) unsigned int*)(Alo + ga),
                (__attribute__((address_space(3))) unsigned int*)(sAl + loff), 16, 0, 0);
            __builtin_amdgcn_global_load_lds(
                (const __attribute__((address_space(1))) unsigned int*)(Bhi + gb),
                (__attribute__((address_space(3))) unsigned int*)(sBh + loff), 16, 0, 0);
        }
        __syncthreads();
        s16x8 ah[4], al[4], bh[4];
        #pragma unroll
        for (int m = 0; m < 4; m++) {
            int o = (wr * 64 + m * 16 + fr) * BK + fq * 8;
            ah[m] = *(const s16x8*)&sAh[o];
            al[m] = *(const s16x8*)&sAl[o];
        }
        #pragma unroll
        for (int n = 0; n < 4; n++)
            bh[n] = *(const s16x8*)&sBh[(wc * 64 + n * 16 + fr) * BK + fq * 8];
        #pragma unroll
        for (int m = 0; m < 4; m++)
            #pragma unroll
            for (int n = 0; n < 4; n++) {
                acc[m][n] = __builtin_amdgcn_mfma_f32_16x16x32_bf16(ah[m], bh[n], acc[m][n], 0, 0, 0);
                acc[m][n] = __builtin_amdgcn_mfma_f32_16x16x32_bf16(al[m], bh[n], acc[m][n], 0, 0, 0);
            }
    }

    float asv[4], adv[4];
    #pragma unroll
    for (int n = 0; n < 4; n++) {
        const int col = bn + wc * 64 + n * 16 + fr;
        asv[n] = a_src[col];
        adv[n] = a_dst[col];
    }

    #pragma unroll
    for (int m = 0; m < 4; m++) {
        const int row = bm + wr * 64 + m * 16 + fq * 4;
        #pragma unroll
        for (int r = 0; r < 4; r++) {
            float s1 = 0.f, s2 = 0.f;
            #pragma unroll
            for (int n = 0; n < 4; n++) {
                const int col = bn + wc * 64 + n * 16 + fr;
                float v = acc[m][n][r];
                Cb[(size_t)(row + r) * 512 + col] = f2bf(v);
                s1 = fmaf(v, asv[n], s1);
                s2 = fmaf(v, adv[n], s2);
            }
            s1 += __shfl_xor(s1, 1); s2 += __shfl_xor(s2, 1);
            s1 += __shfl_xor(s1, 2); s2 += __shfl_xor(s2, 2);
            s1 += __shfl_xor(s1, 4); s2 += __shfl_xor(s2, 4);
            s1 += __shfl_xor(s1, 8); s2 += __shfl_xor(s2, 8);
            if (fr == 0) {
                atomicAdd(&as_[row + r], s1);
                atomicAdd(&ad_[row + r], s2);
            }
        }
    }
}

// ---------------- PV split-K MFMA GEMM (BK=64, swizzled LDS, XCD swizzle) ---
__global__ __launch_bounds__(256) void mgemm_pv_k(
    const unsigned short* __restrict__ A, const unsigned short* __restrict__ B,
    unsigned short* __restrict__ C, int kseg, size_t segstride)
{
    constexpr int BK = 64;
    __shared__ unsigned short sA[128 * BK];
    __shared__ unsigned short sB[128 * BK];
    const int t = threadIdx.x, lane = t & 63, w = t >> 6;
    const int wr = w >> 1, wc = w & 1;
    const int fr = lane & 15, fq = lane >> 4;
    const int L  = blockIdx.x + (blockIdx.y << 2) + (blockIdx.z << 6);
    const int xs = L >> 7;
    const int ys = (L & 127) & 15;
    const int zs = (L & 127) >> 4;
    const int bm = ys * 128, bn = xs * 128;
    const int kofs = zs * kseg;

    f32x4 acc[4][4];
    #pragma unroll
    for (int m = 0; m < 4; m++)
        #pragma unroll
        for (int n = 0; n < 4; n++)
            #pragma unroll
            for (int r = 0; r < 4; r++) acc[m][n][r] = 0.f;

    for (int k0 = 0; k0 < kseg; k0 += BK) {
        __syncthreads();
        #pragma unroll
        for (int i = 0; i < 4; i++) {
            int s = i * 256 + t;              // 1024 slots = 128 rows x 8 cc
            int row = s >> 3, cc = s & 7;
            int gc = kofs + k0 + ((cc ^ (row & 7)) << 3);
            __builtin_amdgcn_global_load_lds(
                (const __attribute__((address_space(1))) unsigned int*)
                    (A + (size_t)(bm + row) * 8192 + gc),
                (__attribute__((address_space(3))) unsigned int*)
                    (sA + (i * 256 + w * 64) * 8), 16, 0, 0);
            __builtin_amdgcn_global_load_lds(
                (const __attribute__((address_space(1))) unsigned int*)
                    (B + (size_t)(bn + row) * 8192 + gc),
                (__attribute__((address_space(3))) unsigned int*)
                    (sB + (i * 256 + w * 64) * 8), 16, 0, 0);
        }
        __syncthreads();
        #pragma unroll
        for (int kk = 0; kk < 2; kk++) {
            s16x8 a[4], b[4];
            #pragma unroll
            for (int m = 0; m < 4; m++) {
                int row = wr * 64 + m * 16 + fr;
                a[m] = *(const s16x8*)&sA[row * BK + (((kk * 4 + fq) ^ (row & 7)) << 3)];
            }
            #pragma unroll
            for (int n = 0; n < 4; n++) {
                int row = wc * 64 + n * 16 + fr;
                b[n] = *(const s16x8*)&sB[row * BK + (((kk * 4 + fq) ^ (row & 7)) << 3)];
            }
            #pragma unroll
            for (int m = 0; m < 4; m++)
                #pragma unroll
                for (int n = 0; n < 4; n++)
                    acc[m][n] = __builtin_amdgcn_mfma_f32_16x16x32_bf16(a[m], b[n], acc[m][n], 0, 0, 0);
        }
    }

    unsigned short* Cz = C + (size_t)zs * segstride;
    #pragma unroll
    for (int m = 0; m < 4; m++) {
        const int row = bm + wr * 64 + m * 16 + fq * 4;
        #pragma unroll
        for (int n = 0; n < 4; n++) {
            const int col = bn + wc * 64 + n * 16 + fr;
            #pragma unroll
            for (int r = 0; r < 4; r++)
                Cz[(size_t)(row + r) * 512 + col] = f2bf(acc[m][n][r]);
        }
    }
}

// ---------------- reduce bf16 split-K partials, divide by denom -> bf16 ----
__global__ __launch_bounds__(256) void radd_k(const unsigned short* __restrict__ src,
                                              unsigned short* __restrict__ dst,
                                              const float* __restrict__ dn,
                                              int n8, int segs, size_t stride8) {
    int i = blockIdx.x * 256 + threadIdx.x;
    if (i >= n8) return;
    float acc[8] = {0,0,0,0,0,0,0,0};
    for (int s = 0; s < segs; s++) {
        s16x8 v = ((const s16x8*)src)[i + s * stride8];
        #pragma unroll
        for (int j = 0; j < 8; j++) acc[j] += bf2f((unsigned short)v[j]);
    }
    const float rd = 1.0f / dn[i >> 6];    // 64 groups of 8 per 512-col row
    s16x8 o;
    #pragma unroll
    for (int j = 0; j < 8; j++) o[j] = (short)f2bf(acc[j] * rd);
    ((s16x8*)dst)[i] = o;
}

// ---------------- qkv MFMA GEMM with split epilogue (scale folded into q) ---
__global__ __launch_bounds__(256) void mgemm_qkv_k(
    const unsigned short* __restrict__ A, const unsigned short* __restrict__ B,
    const float* __restrict__ bias, float scale,
    unsigned short* __restrict__ qb, unsigned short* __restrict__ kb,
    unsigned short* __restrict__ vb)
{
    constexpr int BM = 128, BN = 128, BK = 32;
    __shared__ unsigned short sA[BM * BK];
    __shared__ unsigned short sB[BN * BK];
    const int t = threadIdx.x, lane = t & 63, w = t >> 6;
    const int wr = w >> 1, wc = w & 1;
    const int fr = lane & 15, fq = lane >> 4;
    const int bm = blockIdx.y * BM, bn = blockIdx.x * BN;

    f32x4 acc[4][4];
    #pragma unroll
    for (int m = 0; m < 4; m++)
        #pragma unroll
        for (int n = 0; n < 4; n++)
            #pragma unroll
            for (int r = 0; r < 4; r++) acc[m][n][r] = 0.f;

    for (int k0 = 0; k0 < 512; k0 += BK) {
        __syncthreads();
        #pragma unroll
        for (int i = 0; i < 2; i++) {
            int slot = i * 256 + t;
            __builtin_amdgcn_global_load_lds(
                (const __attribute__((address_space(1))) unsigned int*)
                    (A + (size_t)(bm + (slot >> 2)) * 512 + k0 + (slot & 3) * 8),
                (__attribute__((address_space(3))) unsigned int*)
                    (sA + (i * 256 + w * 64) * 8), 16, 0, 0);
            __builtin_amdgcn_global_load_lds(
                (const __attribute__((address_space(1))) unsigned int*)
                    (B + (size_t)(bn + (slot >> 2)) * 512 + k0 + (slot & 3) * 8),
                (__attribute__((address_space(3))) unsigned int*)
                    (sB + (i * 256 + w * 64) * 8), 16, 0, 0);
        }
        __syncthreads();
        s16x8 a[4], b[4];
        #pragma unroll
        for (int m = 0; m < 4; m++)
            a[m] = *(const s16x8*)&sA[(wr * 64 + m * 16 + fr) * BK + fq * 8];
        #pragma unroll
        for (int n = 0; n < 4; n++)
            b[n] = *(const s16x8*)&sB[(wc * 64 + n * 16 + fr) * BK + fq * 8];
        #pragma unroll
        for (int m = 0; m < 4; m++)
            #pragma unroll
            for (int n = 0; n < 4; n++)
                acc[m][n] = __builtin_amdgcn_mfma_f32_16x16x32_bf16(a[m], b[n], acc[m][n], 0, 0, 0);
    }

    #pragma unroll
    for (int m = 0; m < 4; m++) {
        const int row = bm + wr * 64 + m * 16 + fq * 4;
        #pragma unroll
        for (int n = 0; n < 4; n++) {
            const int col = bn + wc * 64 + n * 16 + fr;
            const float bv = bias[col];
            #pragma unroll
            for (int r = 0; r < 4; r++) {
                float v = acc[m][n][r] + bv;
                if (col < 512)
                    qb[(size_t)(row + r) * 512 + col] = f2bf(v * scale);
                else if (col < 1024)
                    kb[(size_t)(row + r) * 512 + (col - 512)] = f2bf(v);
                else
                    vb[(size_t)(row + r) * 512 + (col - 1024)] = f2bf(v);
            }
        }
    }
}

// ---------------- bf16 transpose: vb[8192][512] -> vT[512][8192] ------------
__global__ __launch_bounds__(256) void trT_k(const unsigned short* __restrict__ vb,
                                             unsigned short* __restrict__ vT) {
    __shared__ unsigned short s[64][65];
    const int t = threadIdx.x;
    const int rowo = blockIdx.y * 64;
    const int colo = blockIdx.x * 64;
    {
        int r = t >> 2, cg = (t & 3) * 16;
        const s16x8* src = (const s16x8*)(vb + (size_t)(rowo + r) * 512 + colo + cg);
        s16x8 u0 = src[0], u1 = src[1];
        #pragma unroll
        for (int j = 0; j < 8; j++) {
            s[r][cg + j]     = (unsigned short)u0[j];
            s[r][cg + 8 + j] = (unsigned short)u1[j];
        }
    }
    __syncthreads();
    {
        int c = t >> 2, rg = (t & 3) * 16;
        s16x8 o0, o1;
        #pragma unroll
        for (int j = 0; j < 8; j++) {
            o0[j] = (short)s[rg + j][c];
            o1[j] = (short)s[rg + 8 + j][c];
        }
        s16x8* dst = (s16x8*)(vT + (size_t)(colo + c) * 8192 + rowo + rg);
        dst[0] = o0; dst[1] = o1;
    }
}

// ---------------- CSR build ------------------------------------------------
__global__ void count_deg_k(const int* eAB, const int* eBA, int* deg) {
    int i = blockIdx.x * 256 + threadIdx.x;
    if (i >= NE_) return;
    int s, d; edge_sd(i, eAB, eBA, s, d);
    atomicAdd(&deg[d], 1);
}

__global__ __launch_bounds__(256) void scan_k(const int* __restrict__ deg, int* rowstart) {
    __shared__ int part[256];
    int t = threadIdx.x;
    int base = t * 32;
    int loc[32]; int s = 0;
    #pragma unroll
    for (int j = 0; j < 32; j++) { loc[j] = s; s += deg[base + j]; }
    part[t] = s;
    __syncthreads();
    if (t == 0) {
        int a = 0;
        for (int i = 0; i < 256; i++) { int v = part[i]; part[i] = a; a += v; }
        rowstart[NN_] = a;
    }
    __syncthreads();
    int off = part[t];
    #pragma unroll
    for (int j = 0; j < 32; j++) rowstart[base + j] = off + loc[j];
}

// stores src node per CSR slot + slot index per edge
__global__ void fill_csr_k(const int* eAB, const int* eBA,
                           const int* __restrict__ rowstart, int* cursor,
                           int* csr_src, int* pos) {
    int i = blockIdx.x * 256 + threadIdx.x;
    if (i >= NE_) return;
    int s, d; edge_sd(i, eAB, eBA, s, d);
    int p = atomicAdd(&cursor[d], 1);
    int slot = rowstart[d] + p;
    csr_src[slot] = s;
    pos[i] = slot;
}

// ---------------- fused GAT edge pass: e -> exp(e) scatter + denom ----------
// No segment-max: e = LeakyReLU(as+ad) is bounded (|e| <~ 10), f32 exp safe.
__global__ void edge_fused_k(const int* eAB, const int* eBA,
                             const float* __restrict__ as_, const float* __restrict__ ad_,
                             const int* __restrict__ pos,
                             float* __restrict__ evs, float* __restrict__ denom) {
    int i = blockIdx.x * 256 + threadIdx.x;
    if (i >= NE_) return;
    int s, d; edge_sd(i, eAB, eBA, s, d);
    float e = as_[s] + ad_[d];
    e = (e >= 0.f) ? e : NEG_SLOPE_ * e;
    float ex = expf(e);
    evs[pos[i]] = ex;
    atomicAdd(&denom[d], ex);
}

// ---------------- GAT aggregation: streaming CSR, 2-edge unrolled -----------
template<bool SPLIT>
__global__ __launch_bounds__(256) void gat_agg_k(
    const int* __restrict__ rowstart, const int* __restrict__ csr_src,
    const float* __restrict__ evs, const float* __restrict__ denom,
    const unsigned short* __restrict__ hb, const float* __restrict__ bias,
    float* __restrict__ outF, int ldo,
    unsigned short* __restrict__ outHi, unsigned short* __restrict__ outLo)
{
    int wid  = (blockIdx.x * 256 + threadIdx.x) >> 6;
    int lane = threadIdx.x & 63;
    if (wid >= NN_) return;
    float acc[8] = {0.f,0.f,0.f,0.f,0.f,0.f,0.f,0.f};
    int beg = rowstart[wid], end = rowstart[wid + 1];
    float rden = 1.0f / denom[wid];
    int p = beg;
    for (; p + 1 < end; p += 2) {
        int s0 = csr_src[p], s1 = csr_src[p + 1];
        float al0 = evs[p] * rden, al1 = evs[p + 1] * rden;
        s16x8 h0 = *(const s16x8*)(hb + (size_t)s0 * HH_ + lane * 8);
        s16x8 h1 = *(const s16x8*)(hb + (size_t)s1 * HH_ + lane * 8);
        #pragma unroll
        for (int j = 0; j < 8; j++)
            acc[j] = fmaf(al1, bf2f((unsigned short)h1[j]),
                     fmaf(al0, bf2f((unsigned short)h0[j]), acc[j]));
    }
    if (p < end) {
        int s0 = csr_src[p];
        float al0 = evs[p] * rden;
        s16x8 h0 = *(const s16x8*)(hb + (size_t)s0 * HH_ + lane * 8);
        #pragma unroll
        for (int j = 0; j < 8; j++)
            acc[j] = fmaf(al0, bf2f((unsigned short)h0[j]), acc[j]);
    }
    #pragma unroll
    for (int j = 0; j < 8; j++) acc[j] += bias[lane * 8 + j];
    if (SPLIT) {
        s16x8 hi, lo;
        #pragma unroll
        for (int j = 0; j < 8; j++) {
            unsigned short h = f2bf(acc[j]);
            hi[j] = (short)h;
            lo[j] = (short)f2bf(acc[j] - bf2f(h));
        }
        *(s16x8*)(outHi + (size_t)wid * HH_ + lane * 8) = hi;
        *(s16x8*)(outLo + (size_t)wid * HH_ + lane * 8) = lo;
    } else {
        float* o = outF + (size_t)wid * ldo + lane * 8;
        *(float4*)(o)     = make_float4(acc[0], acc[1], acc[2], acc[3]);
        *(float4*)(o + 4) = make_float4(acc[4], acc[5], acc[6], acc[7]);
    }
}

// ===========================================================================
extern "C" void kernel_launch(void* const* d_in, const int* in_sizes, int n_in,
                              void* d_out, int out_size, void* d_ws, size_t ws_size,
                              hipStream_t stream)
{
    const float* x_A    = (const float*)d_in[0];
    const float* x_B    = (const float*)d_in[1];
    const int*   eAB    = (const int*)d_in[2];
    const int*   eBA    = (const int*)d_in[3];
    const float* W_inA  = (const float*)d_in[4];  const float* b_inA  = (const float*)d_in[5];
    const float* W_inB  = (const float*)d_in[6];  const float* b_inB  = (const float*)d_in[7];
    const float* W_in2A = (const float*)d_in[8];  const float* b_in2A = (const float*)d_in[9];
    const float* W_in2B = (const float*)d_in[10]; const float* b_in2B = (const float*)d_in[11];
    const float* Wg1    = (const float*)d_in[12]; const float* a_src1 = (const float*)d_in[13];
    const float* a_dst1 = (const float*)d_in[14]; const float* bg1    = (const float*)d_in[15];
    const float* Wg2    = (const float*)d_in[16]; const float* a_src2 = (const float*)d_in[17];
    const float* a_dst2 = (const float*)d_in[18]; const float* bg2    = (const float*)d_in[19];
    const float* Wqkv   = (const float*)d_in[20]; const float* bqkv   = (const float*)d_in[21];
    const float* Wo     = (const float*)d_in[22]; const float* bo     = (const float*)d_in[23];

    float* out = (float*)d_out;

    char* base = (char*)d_ws;
    size_t off = 0;
    auto alloc = [&](size_t nb) -> char* {
        char* p = base + off;
        off = (off + nb + 255) & ~(size_t)255;
        return p;
    };

    // bufA and bufB MUST be adjacent: Sb (32MB) spans both during attention.
    float*          bufA  = (float*)alloc((size_t)NN_ * 512 * 4);
    float*          bufB  = (float*)alloc((size_t)NN_ * 512 * 4);
    float*          bufC  = (float*)alloc((size_t)NN_ * 512 * 4);
    // as_..cdn contiguous: first memset covers all six; re-zero covers first 3
    float*          as_   = (float*)alloc(NN_ * 4);
    float*          ad_   = (float*)alloc(NN_ * 4);
    float*          denom = (float*)alloc(NN_ * 4);
    int*            deg   = (int*)alloc(NN_ * 4);
    int*            cursor= (int*)alloc(NN_ * 4);
    float*          cdn   = (float*)alloc(NN_ * 4);    // per-chunk attn denoms
    int*            rowst = (int*)alloc((NN_ + 1) * 4);
    int*            csrs  = (int*)alloc((size_t)NE_ * 4);   // src per CSR slot
    int*            pos   = (int*)alloc((size_t)NE_ * 4);   // edge -> CSR slot
    float*          evs   = (float*)alloc((size_t)NE_ * 4); // exp in CSR order
    unsigned short* xbA   = (unsigned short*)alloc((size_t)NA_ * 256 * 2);
    unsigned short* xbB   = (unsigned short*)alloc((size_t)NB_ * 256 * 2);
    unsigned short* WbinA = (unsigned short*)alloc((size_t)512 * 256 * 2);
    unsigned short* WbinB = (unsigned short*)alloc((size_t)512 * 256 * 2);
    unsigned short* Wbin2A= (unsigned short*)alloc((size_t)512 * 256 * 2);
    unsigned short* Wbin2B= (unsigned short*)alloc((size_t)512 * 256 * 2);
    unsigned short* Wbqkv = (unsigned short*)alloc((size_t)1536 * 512 * 2);
    unsigned short* Wbo   = (unsigned short*)alloc((size_t)512 * 512 * 2);
    unsigned short* Wg1b  = (unsigned short*)alloc((size_t)512 * 512 * 2);
    unsigned short* Wg2b  = (unsigned short*)alloc((size_t)512 * 512 * 2);
    unsigned short* qb    = (unsigned short*)alloc((size_t)NN_ * 512 * 2);
    unsigned short* kb    = (unsigned short*)alloc((size_t)NN_ * 512 * 2);
    unsigned short* vT    = (unsigned short*)alloc((size_t)512 * NN_ * 2);
    unsigned short* ab    = (unsigned short*)alloc((size_t)NN_ * 512 * 2);

    // overlays
    unsigned short* hb = vT;                              // bf16 h (local branch)
    unsigned short* gb = (unsigned short*)bufC;           // g bf16 (global, pre-loop)
    unsigned short* vb = gb + (size_t)NN_ * 512;          // v bf16 (global, pre-loop)
    unsigned short* Sb = (unsigned short*)bufA;           // scores: bufA+bufB = 32MB
    unsigned short* pv = (unsigned short*)bufC;           // PV bf16 partials (16MB)

    const int R = 2048, SEGS = 8, KSEG = 8192 / SEGS;
    const int EG = (NE_ + 255) / 256;
    const float scale2 = 0.044194173824159216f * 1.4426950408889634f; // /sqrt(512)*log2e

    // -------- all weight/input casts in ONE launch --------------------------
    CvtJobs jobs;
    jobs.j[0] = { x_A,    xbA,    nullptr, NA_ * 256 / 4 };
    jobs.j[1] = { x_B,    xbB,    nullptr, NB_ * 256 / 4 };
    jobs.j[2] = { W_inA,  WbinA,  nullptr, 512 * 256 / 4 };
    jobs.j[3] = { W_inB,  WbinB,  nullptr, 512 * 256 / 4 };
    jobs.j[4] = { W_in2A, Wbin2A, nullptr, 512 * 256 / 4 };
    jobs.j[5] = { W_in2B, Wbin2B, nullptr, 512 * 256 / 4 };
    jobs.j[6] = { Wqkv,   Wbqkv,  nullptr, 1536 * 512 / 4 };
    jobs.j[7] = { Wo,     Wbo,    nullptr, 512 * 512 / 4 };
    jobs.j[8] = { Wg1,    Wg1b,   nullptr, 512 * 512 / 4 };
    jobs.j[9] = { Wg2,    Wg2b,   nullptr, 512 * 512 / 4 };
    cvt_all_k<<<dim3(NA_ * 256 / 4 / 256, 10), 256, 0, stream>>>(jobs);

    // zero as_, ad_, denom, deg, cursor, cdn in one shot
    hipMemsetAsync(as_, 0, (size_t)NN_ * 4 * 6, stream);

    // -------- CSR build -----------------------------------------------------
    count_deg_k<<<EG, 256, 0, stream>>>(eAB, eBA, deg);
    scan_k<<<1, 256, 0, stream>>>(deg, rowst);
    fill_csr_k<<<EG, 256, 0, stream>>>(eAB, eBA, rowst, cursor, csrs, pos);

    // -------- local branch --------------------------------------------------
    mgemm_in_k<true><<<dim3(4, 64), 256, 0, stream>>>(
        xbA, xbB, WbinA, WbinB, b_inA, b_inB, qb, kb);
    mgemm3_k<<<dim3(4, 64), 256, 0, stream>>>(qb, kb, Wg1b,
                                              hb, a_src1, a_dst1, as_, ad_,
                                              512, 512, 512);
    edge_fused_k<<<EG, 256, 0, stream>>>(eAB, eBA, as_, ad_, pos, evs, denom);
    gat_agg_k<true><<<NN_/4, 256, 0, stream>>>(rowst, csrs, evs, denom,
                                               hb, bg1, nullptr, 0, qb, kb);
    hipMemsetAsync(as_, 0, NN_ * 12, stream);           // as_, ad_, denom
    mgemm3_k<<<dim3(4, 64), 256, 0, stream>>>(qb, kb, Wg2b,
                                              hb, a_src2, a_dst2, as_, ad_,
                                              512, 512, 512);
    edge_fused_k<<<EG, 256, 0, stream>>>(eAB, eBA, as_, ad_, pos, evs, denom);
    // layer-2 aggregation writes the local half of d_out directly (ldo=1024)
    gat_agg_k<false><<<NN_/4, 256, 0, stream>>>(rowst, csrs, evs, denom,
                                                hb, bg2, out, 1024, nullptr, nullptr);

    // -------- global branch -------------------------------------------------
    mgemm_in_k<false><<<dim3(4, 64), 256, 0, stream>>>(
        xbA, xbB, Wbin2A, Wbin2B, b_in2A, b_in2B, gb, nullptr);
    mgemm_qkv_k<<<dim3(12, 64), 256, 0, stream>>>(gb, Wbqkv, bqkv, scale2, qb, kb, vb);
    trT_k<<<dim3(8, 128), 256, 0, stream>>>(vb, vT);
    for (int c0 = 0; c0 < 8192; c0 += R) {
        float* dn = cdn + c0;   // this chunk's 2048 denominators (pre-zeroed)
        mgemm_qk_k<<<dim3(32, 8), 512, 0, stream>>>(
            qb + (size_t)c0 * 512, kb, Sb, dn);
        mgemm_pv_k<<<dim3(4, R/128, SEGS), 256, 0, stream>>>(
            Sb, vT, pv, KSEG, (size_t)R * 512);
        radd_k<<<(R*512/8 + 255)/256, 256, 0, stream>>>(
            pv, ab + (size_t)c0 * 512, dn, R*512/8, SEGS, (size_t)R*512/8);
    }
    // Wo GEMM writes the global half of d_out directly (ldc=1024, col offset 512)
    mgemm_k<128,128,true,float><<<dim3(4, 64), 256, 0, stream>>>(
        ab, Wbo, bo, out + 512, 512, 512, 512, 1024);
}

// Round 16
// 539.872 us; speedup vs baseline: 1.3017x; 1.0432x over previous
//
#include <hip/hip_runtime.h>
#include <hip/hip_bf16.h>

#define NA_ 4096
#define NB_ 4096
#define NN_ 8192            // total nodes
#define EE_ 131072          // edges per direction
#define NE_ (2*EE_ + NN_)   // homogeneous edges incl. self loops = 270336
#define HH_ 512
#define NEG_SLOPE_ 0.2f

typedef __attribute__((ext_vector_type(4))) float f32x4;
typedef __attribute__((ext_vector_type(8))) short s16x8;

__device__ inline unsigned short f2bf(float v) {
    __hip_bfloat16 h = __float2bfloat16(v);
    return __builtin_bit_cast(unsigned short, h);
}
__device__ inline float bf2f(unsigned short u) {
    return __uint_as_float(((unsigned)u) << 16);
}

#define GLOAD16(gsrc, ldst)                                                    \
    __builtin_amdgcn_global_load_lds(                                          \
        (const __attribute__((address_space(1))) unsigned int*)(gsrc),         \
        (__attribute__((address_space(3))) unsigned int*)(ldst), 16, 0, 0)

// ---------------- homogeneous edge id -> (src, dst) ------------------------
__device__ inline void edge_sd(int i, const int* __restrict__ eAB,
                               const int* __restrict__ eBA, int& s, int& d) {
    if (i < EE_)            { s = eAB[i];            d = eAB[EE_ + i] + NA_; }
    else if (i < 2 * EE_)   { int j = i - EE_; s = eBA[j] + NA_; d = eBA[EE_ + j]; }
    else                    { s = i - 2 * EE_;       d = s; }
}

// ---------------- batched f32 -> bf16 (optionally split hi/lo) casts --------
struct CvtJob { const float* s; unsigned short* hi; unsigned short* lo; int n4; };
struct CvtJobs { CvtJob j[10]; };

__global__ __launch_bounds__(256) void cvt_all_k(CvtJobs jobs) {
    const CvtJob jb = jobs.j[blockIdx.y];
    int i = blockIdx.x * 256 + threadIdx.x;
    if (i >= jb.n4) return;
    float4 v = ((const float4*)jb.s)[i];
    ushort4 h;
    h.x = f2bf(v.x); h.y = f2bf(v.y); h.z = f2bf(v.z); h.w = f2bf(v.w);
    ((ushort4*)jb.hi)[i] = h;
    if (jb.lo) {
        ushort4 l;
        l.x = f2bf(v.x - bf2f(h.x));
        l.y = f2bf(v.y - bf2f(h.y));
        l.z = f2bf(v.z - bf2f(h.z));
        l.w = f2bf(v.w - bf2f(h.w));
        ((ushort4*)jb.lo)[i] = l;
    }
}

// ---------------- MFMA bf16 GEMM: C[M,N] = A @ B^T (+bias) -----------------
template<int BM, int BN, bool BIAS, typename OutT>
__global__ __launch_bounds__(256) void mgemm_k(
    const unsigned short* __restrict__ A, const unsigned short* __restrict__ B,
    const float* __restrict__ bias, OutT* __restrict__ C,
    int K, int lda, int ldb, int ldc)
{
    constexpr int BK = 32;
    constexpr int WM = BM / 2, WN = BN / 2;
    constexpr int AM = WM / 16, AN = WN / 16;
    constexpr int AISS = BM * 4 / 256, BISS = BN * 4 / 256;
    __shared__ unsigned short sA[BM * BK];
    __shared__ unsigned short sB[BN * BK];
    const int t = threadIdx.x, lane = t & 63, w = t >> 6;
    const int wr = w >> 1, wc = w & 1;
    const int fr = lane & 15, fq = lane >> 4;
    const int bm = blockIdx.y * BM, bn = blockIdx.x * BN;

    f32x4 acc[AM][AN];
    #pragma unroll
    for (int m = 0; m < AM; m++)
        #pragma unroll
        for (int n = 0; n < AN; n++)
            #pragma unroll
            for (int r = 0; r < 4; r++) acc[m][n][r] = 0.f;

    for (int k0 = 0; k0 < K; k0 += BK) {
        __syncthreads();
        #pragma unroll
        for (int i = 0; i < AISS; i++) {
            int slot = i * 256 + t;
            GLOAD16(A + (size_t)(bm + (slot >> 2)) * lda + k0 + (slot & 3) * 8,
                    sA + (i * 256 + w * 64) * 8);
        }
        #pragma unroll
        for (int i = 0; i < BISS; i++) {
            int slot = i * 256 + t;
            GLOAD16(B + (size_t)(bn + (slot >> 2)) * ldb + k0 + (slot & 3) * 8,
                    sB + (i * 256 + w * 64) * 8);
        }
        __syncthreads();
        s16x8 a[AM], b[AN];
        #pragma unroll
        for (int m = 0; m < AM; m++)
            a[m] = *(const s16x8*)&sA[(wr * WM + m * 16 + fr) * BK + fq * 8];
        #pragma unroll
        for (int n = 0; n < AN; n++)
            b[n] = *(const s16x8*)&sB[(wc * WN + n * 16 + fr) * BK + fq * 8];
        #pragma unroll
        for (int m = 0; m < AM; m++)
            #pragma unroll
            for (int n = 0; n < AN; n++)
                acc[m][n] = __builtin_amdgcn_mfma_f32_16x16x32_bf16(a[m], b[n], acc[m][n], 0, 0, 0);
    }

    #pragma unroll
    for (int m = 0; m < AM; m++) {
        const int row = bm + wr * WM + m * 16 + fq * 4;
        #pragma unroll
        for (int n = 0; n < AN; n++) {
            const int col = bn + wc * WN + n * 16 + fr;
            const float bv = BIAS ? bias[col] : 0.f;
            #pragma unroll
            for (int r = 0; r < 4; r++) {
                float v = acc[m][n][r] + bv;
                if constexpr (sizeof(OutT) == 2)
                    C[(size_t)(row + r) * ldc + col] = (OutT)f2bf(v);
                else
                    C[(size_t)(row + r) * ldc + col] = v;
            }
        }
    }
}

// ---------------- QK^T: 256x256, 8 waves, dbuf BK=32, prefetch pipeline -----
// q pre-scaled by scale*log2e -> P = 2^(q.k); denom[row] += row-sum (atomic).
// T3-minimum schedule: stage(next) BEFORE ds_read+MFMA(cur); raw s_barrier
// with vmcnt(0) AFTER the MFMA block (load latency hides under compute).
__global__ __launch_bounds__(512) void mgemm_qk_k(
    const unsigned short* __restrict__ A, const unsigned short* __restrict__ B,
    unsigned short* __restrict__ C, float* __restrict__ denom)
{
    constexpr int BK = 32;
    __shared__ unsigned short smem[32768];    // 64KB: 2 bufs x (A 16KB | B 16KB)
    unsigned short* tile = smem;              // 64 x 264 (33KB) in epilogue
    const int t = threadIdx.x, lane = t & 63, w = t >> 6;   // 8 waves
    const int wr = w >> 2, wc = w & 3;        // 2 (M) x 4 (N)
    const int fr = lane & 15, fq = lane >> 4;
    const int bm = blockIdx.y * 256, bn = blockIdx.x * 256;

    f32x4 acc[8][4];
    #pragma unroll
    for (int m = 0; m < 8; m++)
        #pragma unroll
        for (int n = 0; n < 4; n++)
            #pragma unroll
            for (int r = 0; r < 4; r++) acc[m][n][r] = 0.f;

    auto stage = [&](int buf, int k0) {
        unsigned short* dA = smem + buf * 16384;
        unsigned short* dB = dA + 8192;
        #pragma unroll
        for (int i = 0; i < 2; i++) {
            int s = i * 512 + t;              // 1024 slots = 256 rows x 4 cc
            int row = s >> 2, cc = s & 3;
            int gc = k0 + ((cc ^ (row & 3)) << 3);
            GLOAD16(A + (size_t)(bm + row) * 512 + gc, dA + (i * 512 + w * 64) * 8);
            GLOAD16(B + (size_t)(bn + row) * 512 + gc, dB + (i * 512 + w * 64) * 8);
        }
    };

    stage(0, 0);
    asm volatile("s_waitcnt vmcnt(0)" ::: "memory");
    __builtin_amdgcn_s_barrier();
    int cur = 0;
    for (int k0 = 0; k0 < 512; k0 += BK) {
        if (k0 + BK < 512) stage(cur ^ 1, k0 + BK);
        const unsigned short* rA = smem + cur * 16384;
        const unsigned short* rB = rA + 8192;
        s16x8 a[8], b[4];
        #pragma unroll
        for (int m = 0; m < 8; m++) {
            int row = wr * 128 + m * 16 + fr;
            a[m] = *(const s16x8*)&rA[row * BK + ((fq ^ (row & 3)) << 3)];
        }
        #pragma unroll
        for (int n = 0; n < 4; n++) {
            int row = wc * 64 + n * 16 + fr;
            b[n] = *(const s16x8*)&rB[row * BK + ((fq ^ (row & 3)) << 3)];
        }
        __builtin_amdgcn_s_setprio(1);
        #pragma unroll
        for (int m = 0; m < 8; m++)
            #pragma unroll
            for (int n = 0; n < 4; n++)
                acc[m][n] = __builtin_amdgcn_mfma_f32_16x16x32_bf16(a[m], b[n], acc[m][n], 0, 0, 0);
        __builtin_amdgcn_s_setprio(0);
        asm volatile("s_waitcnt vmcnt(0)" ::: "memory");
        __builtin_amdgcn_s_barrier();
        cur ^= 1;
    }

    // epilogue: 4 phases, each 64 rows staged in LDS, coalesced store
    #pragma unroll
    for (int h = 0; h < 4; h++) {
        __syncthreads();
        #pragma unroll
        for (int mm = 0; mm < 2; mm++) {
            const int m = h * 2 + mm;
            #pragma unroll
            for (int r = 0; r < 4; r++) {
                float rsum = 0.f;
                #pragma unroll
                for (int n = 0; n < 4; n++) {
                    float p = exp2f(acc[m][n][r]);
                    rsum += p;
                    tile[(wr * 32 + mm * 16 + fq * 4 + r) * 264 + wc * 64 + n * 16 + fr]
                        = f2bf(p);
                }
                rsum += __shfl_xor(rsum, 1);
                rsum += __shfl_xor(rsum, 2);
                rsum += __shfl_xor(rsum, 4);
                rsum += __shfl_xor(rsum, 8);
                if (fr == 0)
                    atomicAdd(&denom[bm + wr * 128 + h * 32 + mm * 16 + fq * 4 + r], rsum);
            }
        }
        __syncthreads();
        #pragma unroll
        for (int j = 0; j < 4; j++) {
            int cj = j * 512 + t;             // 2048 chunks = 64 rows x 32
            int row_l = cj >> 5, c16 = cj & 31;
            int grow = bm + (row_l >> 5) * 128 + h * 32 + (row_l & 31);
            *(s16x8*)(C + (size_t)grow * 8192 + bn + c16 * 8)
                = *(const s16x8*)&tile[row_l * 264 + c16 * 8];
        }
    }
}

// ---------------- merged per-type input linear (A rows 0..4095, B rows 4096+)
template<bool SPLIT>
__global__ __launch_bounds__(256) void mgemm_in_k(
    const unsigned short* __restrict__ xA, const unsigned short* __restrict__ xB,
    const unsigned short* __restrict__ WA, const unsigned short* __restrict__ WB,
    const float* __restrict__ biasA, const float* __restrict__ biasB,
    unsigned short* __restrict__ o1, unsigned short* __restrict__ o2)
{
    constexpr int BK = 32;
    __shared__ unsigned short sA[128 * BK];
    __shared__ unsigned short sB[128 * BK];
    const int t = threadIdx.x, lane = t & 63, w = t >> 6;
    const int wr = w >> 1, wc = w & 1;
    const int fr = lane & 15, fq = lane >> 4;
    const int bm = blockIdx.y * 128, bn = blockIdx.x * 128;
    const bool isB = bm >= NA_;
    const unsigned short* A = isB ? xB : xA;
    const unsigned short* W = isB ? WB : WA;
    const float* bias = isB ? biasB : biasA;
    const int bml = bm - (isB ? NA_ : 0);

    f32x4 acc[4][4];
    #pragma unroll
    for (int m = 0; m < 4; m++)
        #pragma unroll
        for (int n = 0; n < 4; n++)
            #pragma unroll
            for (int r = 0; r < 4; r++) acc[m][n][r] = 0.f;

    for (int k0 = 0; k0 < 256; k0 += BK) {
        __syncthreads();
        #pragma unroll
        for (int i = 0; i < 2; i++) {
            int slot = i * 256 + t;
            GLOAD16(A + (size_t)(bml + (slot >> 2)) * 256 + k0 + (slot & 3) * 8,
                    sA + (i * 256 + w * 64) * 8);
            GLOAD16(W + (size_t)(bn + (slot >> 2)) * 256 + k0 + (slot & 3) * 8,
                    sB + (i * 256 + w * 64) * 8);
        }
        __syncthreads();
        s16x8 a[4], b[4];
        #pragma unroll
        for (int m = 0; m < 4; m++)
            a[m] = *(const s16x8*)&sA[(wr * 64 + m * 16 + fr) * BK + fq * 8];
        #pragma unroll
        for (int n = 0; n < 4; n++)
            b[n] = *(const s16x8*)&sB[(wc * 64 + n * 16 + fr) * BK + fq * 8];
        #pragma unroll
        for (int m = 0; m < 4; m++)
            #pragma unroll
            for (int n = 0; n < 4; n++)
                acc[m][n] = __builtin_amdgcn_mfma_f32_16x16x32_bf16(a[m], b[n], acc[m][n], 0, 0, 0);
    }

    #pragma unroll
    for (int m = 0; m < 4; m++) {
        const int row = bm + wr * 64 + m * 16 + fq * 4;
        #pragma unroll
        for (int n = 0; n < 4; n++) {
            const int col = bn + wc * 64 + n * 16 + fr;
            const float bv = bias[col];
            #pragma unroll
            for (int r = 0; r < 4; r++) {
                float v = acc[m][n][r] + bv;
                unsigned short hi = f2bf(v);
                o1[(size_t)(row + r) * 512 + col] = hi;
                if (SPLIT)
                    o2[(size_t)(row + r) * 512 + col] = f2bf(v - bf2f(hi));
            }
        }
    }
}

// ---------------- split-A MFMA GEMM (2 MFMA), dbuf pipeline + fused dots ----
__global__ __launch_bounds__(256) void mgemm3_k(
    const unsigned short* __restrict__ Ahi, const unsigned short* __restrict__ Alo,
    const unsigned short* __restrict__ Bhi,
    unsigned short* __restrict__ Cb, const float* __restrict__ a_src,
    const float* __restrict__ a_dst, float* __restrict__ as_,
    float* __restrict__ ad_, int K, int lda, int ldb)
{
    constexpr int BK = 32;
    __shared__ unsigned short smem[24576];    // 48KB: 2 bufs x (Ah|Al|Bh) x 8KB
    const int t = threadIdx.x, lane = t & 63, w = t >> 6;
    const int wr = w >> 1, wc = w & 1;
    const int fr = lane & 15, fq = lane >> 4;
    const int bm = blockIdx.y * 128, bn = blockIdx.x * 128;

    f32x4 acc[4][4];
    #pragma unroll
    for (int m = 0; m < 4; m++)
        #pragma unroll
        for (int n = 0; n < 4; n++)
            #pragma unroll
            for (int r = 0; r < 4; r++) acc[m][n][r] = 0.f;

    auto stage = [&](int buf, int k0) {
        unsigned short* dAh = smem + buf * 12288;
        unsigned short* dAl = dAh + 4096;
        unsigned short* dBh = dAh + 8192;
        #pragma unroll
        for (int i = 0; i < 2; i++) {
            int s = i * 256 + t;              // 512 slots = 128 rows x 4 cc
            int row = s >> 2, cc = s & 3;
            int gco = (cc ^ (row & 3)) << 3;
            size_t ga = (size_t)(bm + row) * lda + k0 + gco;
            size_t gb = (size_t)(bn + row) * ldb + k0 + gco;
            unsigned loff = (unsigned)(i * 256 + w * 64) * 8;
            GLOAD16(Ahi + ga, dAh + loff);
            GLOAD16(Alo + ga, dAl + loff);
            GLOAD16(Bhi + gb, dBh + loff);
        }
    };

    stage(0, 0);
    asm volatile("s_waitcnt vmcnt(0)" ::: "memory");
    __builtin_amdgcn_s_barrier();
    int cur = 0;
    for (int k0 = 0; k0 < K; k0 += BK) {
        if (k0 + BK < K) stage(cur ^ 1, k0 + BK);
        const unsigned short* rAh = smem + cur * 12288;
        const unsigned short* rAl = rAh + 4096;
        const unsigned short* rBh = rAh + 8192;
        s16x8 ah[4], al[4], bh[4];
        #pragma unroll
        for (int m = 0; m < 4; m++) {
            int row = wr * 64 + m * 16 + fr;
            int o = row * BK + ((fq ^ (row & 3)) << 3);
            ah[m] = *(const s16x8*)&rAh[o];
            al[m] = *(const s16x8*)&rAl[o];
        }
        #pragma unroll
        for (int n = 0; n < 4; n++) {
            int row = wc * 64 + n * 16 + fr;
            bh[n] = *(const s16x8*)&rBh[row * BK + ((fq ^ (row & 3)) << 3)];
        }
        __builtin_amdgcn_s_setprio(1);
        #pragma unroll
        for (int m = 0; m < 4; m++)
            #pragma unroll
            for (int n = 0; n < 4; n++) {
                acc[m][n] = __builtin_amdgcn_mfma_f32_16x16x32_bf16(ah[m], bh[n], acc[m][n], 0, 0, 0);
                acc[m][n] = __builtin_amdgcn_mfma_f32_16x16x32_bf16(al[m], bh[n], acc[m][n], 0, 0, 0);
            }
        __builtin_amdgcn_s_setprio(0);
        asm volatile("s_waitcnt vmcnt(0)" ::: "memory");
        __builtin_amdgcn_s_barrier();
        cur ^= 1;
    }

    float asv[4], adv[4];
    #pragma unroll
    for (int n = 0; n < 4; n++) {
        const int col = bn + wc * 64 + n * 16 + fr;
        asv[n] = a_src[col];
        adv[n] = a_dst[col];
    }

    #pragma unroll
    for (int m = 0; m < 4; m++) {
        const int row = bm + wr * 64 + m * 16 + fq * 4;
        #pragma unroll
        for (int r = 0; r < 4; r++) {
            float s1 = 0.f, s2 = 0.f;
            #pragma unroll
            for (int n = 0; n < 4; n++) {
                const int col = bn + wc * 64 + n * 16 + fr;
                float v = acc[m][n][r];
                Cb[(size_t)(row + r) * 512 + col] = f2bf(v);
                s1 = fmaf(v, asv[n], s1);
                s2 = fmaf(v, adv[n], s2);
            }
            s1 += __shfl_xor(s1, 1); s2 += __shfl_xor(s2, 1);
            s1 += __shfl_xor(s1, 2); s2 += __shfl_xor(s2, 2);
            s1 += __shfl_xor(s1, 4); s2 += __shfl_xor(s2, 4);
            s1 += __shfl_xor(s1, 8); s2 += __shfl_xor(s2, 8);
            if (fr == 0) {
                atomicAdd(&as_[row + r], s1);
                atomicAdd(&ad_[row + r], s2);
            }
        }
    }
}

// ---------------- PV split-K: dbuf BK=32 pipeline, XCD swizzle --------------
__global__ __launch_bounds__(256) void mgemm_pv_k(
    const unsigned short* __restrict__ A, const unsigned short* __restrict__ B,
    unsigned short* __restrict__ C, int kseg, size_t segstride)
{
    constexpr int BK = 32;
    __shared__ unsigned short smem[16384];    // 32KB: 2 bufs x (A 8KB | B 8KB)
    const int t = threadIdx.x, lane = t & 63, w = t >> 6;
    const int wr = w >> 1, wc = w & 1;
    const int fr = lane & 15, fq = lane >> 4;
    const int L  = blockIdx.x + (blockIdx.y << 2) + (blockIdx.z << 6);
    const int xs = L >> 7;
    const int ys = (L & 127) & 15;
    const int zs = (L & 127) >> 4;
    const int bm = ys * 128, bn = xs * 128;
    const int kofs = zs * kseg;

    f32x4 acc[4][4];
    #pragma unroll
    for (int m = 0; m < 4; m++)
        #pragma unroll
        for (int n = 0; n < 4; n++)
            #pragma unroll
            for (int r = 0; r < 4; r++) acc[m][n][r] = 0.f;

    auto stage = [&](int buf, int k0) {
        unsigned short* dA = smem + buf * 8192;
        unsigned short* dB = dA + 4096;
        #pragma unroll
        for (int i = 0; i < 2; i++) {
            int s = i * 256 + t;              // 512 slots = 128 rows x 4 cc
            int row = s >> 2, cc = s & 3;
            int gc = kofs + k0 + ((cc ^ (row & 3)) << 3);
            GLOAD16(A + (size_t)(bm + row) * 8192 + gc, dA + (i * 256 + w * 64) * 8);
            GLOAD16(B + (size_t)(bn + row) * 8192 + gc, dB + (i * 256 + w * 64) * 8);
        }
    };

    stage(0, 0);
    asm volatile("s_waitcnt vmcnt(0)" ::: "memory");
    __builtin_amdgcn_s_barrier();
    int cur = 0;
    for (int k0 = 0; k0 < kseg; k0 += BK) {
        if (k0 + BK < kseg) stage(cur ^ 1, k0 + BK);
        const unsigned short* rA = smem + cur * 8192;
        const unsigned short* rB = rA + 4096;
        s16x8 a[4], b[4];
        #pragma unroll
        for (int m = 0; m < 4; m++) {
            int row = wr * 64 + m * 16 + fr;
            a[m] = *(const s16x8*)&rA[row * BK + ((fq ^ (row & 3)) << 3)];
        }
        #pragma unroll
        for (int n = 0; n < 4; n++) {
            int row = wc * 64 + n * 16 + fr;
            b[n] = *(const s16x8*)&rB[row * BK + ((fq ^ (row & 3)) << 3)];
        }
        __builtin_amdgcn_s_setprio(1);
        #pragma unroll
        for (int m = 0; m < 4; m++)
            #pragma unroll
            for (int n = 0; n < 4; n++)
                acc[m][n] = __builtin_amdgcn_mfma_f32_16x16x32_bf16(a[m], b[n], acc[m][n], 0, 0, 0);
        __builtin_amdgcn_s_setprio(0);
        asm volatile("s_waitcnt vmcnt(0)" ::: "memory");
        __builtin_amdgcn_s_barrier();
        cur ^= 1;
    }

    unsigned short* Cz = C + (size_t)zs * segstride;
    #pragma unroll
    for (int m = 0; m < 4; m++) {
        const int row = bm + wr * 64 + m * 16 + fq * 4;
        #pragma unroll
        for (int n = 0; n < 4; n++) {
            const int col = bn + wc * 64 + n * 16 + fr;
            #pragma unroll
            for (int r = 0; r < 4; r++)
                Cz[(size_t)(row + r) * 512 + col] = f2bf(acc[m][n][r]);
        }
    }
}

// ---------------- reduce bf16 split-K partials, divide by denom -> bf16 ----
__global__ __launch_bounds__(256) void radd_k(const unsigned short* __restrict__ src,
                                              unsigned short* __restrict__ dst,
                                              const float* __restrict__ dn,
                                              int n8, int segs, size_t stride8) {
    int i = blockIdx.x * 256 + threadIdx.x;
    if (i >= n8) return;
    float acc[8] = {0,0,0,0,0,0,0,0};
    for (int s = 0; s < segs; s++) {
        s16x8 v = ((const s16x8*)src)[i + s * stride8];
        #pragma unroll
        for (int j = 0; j < 8; j++) acc[j] += bf2f((unsigned short)v[j]);
    }
    const float rd = 1.0f / dn[i >> 6];    // 64 groups of 8 per 512-col row
    s16x8 o;
    #pragma unroll
    for (int j = 0; j < 8; j++) o[j] = (short)f2bf(acc[j] * rd);
    ((s16x8*)dst)[i] = o;
}

// ---------------- qkv MFMA GEMM with split epilogue (scale folded into q) ---
__global__ __launch_bounds__(256) void mgemm_qkv_k(
    const unsigned short* __restrict__ A, const unsigned short* __restrict__ B,
    const float* __restrict__ bias, float scale,
    unsigned short* __restrict__ qb, unsigned short* __restrict__ kb,
    unsigned short* __restrict__ vb)
{
    constexpr int BM = 128, BN = 128, BK = 32;
    __shared__ unsigned short sA[BM * BK];
    __shared__ unsigned short sB[BN * BK];
    const int t = threadIdx.x, lane = t & 63, w = t >> 6;
    const int wr = w >> 1, wc = w & 1;
    const int fr = lane & 15, fq = lane >> 4;
    const int bm = blockIdx.y * BM, bn = blockIdx.x * BN;

    f32x4 acc[4][4];
    #pragma unroll
    for (int m = 0; m < 4; m++)
        #pragma unroll
        for (int n = 0; n < 4; n++)
            #pragma unroll
            for (int r = 0; r < 4; r++) acc[m][n][r] = 0.f;

    for (int k0 = 0; k0 < 512; k0 += BK) {
        __syncthreads();
        #pragma unroll
        for (int i = 0; i < 2; i++) {
            int slot = i * 256 + t;
            GLOAD16(A + (size_t)(bm + (slot >> 2)) * 512 + k0 + (slot & 3) * 8,
                    sA + (i * 256 + w * 64) * 8);
            GLOAD16(B + (size_t)(bn + (slot >> 2)) * 512 + k0 + (slot & 3) * 8,
                    sB + (i * 256 + w * 64) * 8);
        }
        __syncthreads();
        s16x8 a[4], b[4];
        #pragma unroll
        for (int m = 0; m < 4; m++)
            a[m] = *(const s16x8*)&sA[(wr * 64 + m * 16 + fr) * BK + fq * 8];
        #pragma unroll
        for (int n = 0; n < 4; n++)
            b[n] = *(const s16x8*)&sB[(wc * 64 + n * 16 + fr) * BK + fq * 8];
        #pragma unroll
        for (int m = 0; m < 4; m++)
            #pragma unroll
            for (int n = 0; n < 4; n++)
                acc[m][n] = __builtin_amdgcn_mfma_f32_16x16x32_bf16(a[m], b[n], acc[m][n], 0, 0, 0);
    }

    #pragma unroll
    for (int m = 0; m < 4; m++) {
        const int row = bm + wr * 64 + m * 16 + fq * 4;
        #pragma unroll
        for (int n = 0; n < 4; n++) {
            const int col = bn + wc * 64 + n * 16 + fr;
            const float bv = bias[col];
            #pragma unroll
            for (int r = 0; r < 4; r++) {
                float v = acc[m][n][r] + bv;
                if (col < 512)
                    qb[(size_t)(row + r) * 512 + col] = f2bf(v * scale);
                else if (col < 1024)
                    kb[(size_t)(row + r) * 512 + (col - 512)] = f2bf(v);
                else
                    vb[(size_t)(row + r) * 512 + (col - 1024)] = f2bf(v);
            }
        }
    }
}

// ---------------- bf16 transpose: vb[8192][512] -> vT[512][8192] ------------
__global__ __launch_bounds__(256) void trT_k(const unsigned short* __restrict__ vb,
                                             unsigned short* __restrict__ vT) {
    __shared__ unsigned short s[64][65];
    const int t = threadIdx.x;
    const int rowo = blockIdx.y * 64;
    const int colo = blockIdx.x * 64;
    {
        int r = t >> 2, cg = (t & 3) * 16;
        const s16x8* src = (const s16x8*)(vb + (size_t)(rowo + r) * 512 + colo + cg);
        s16x8 u0 = src[0], u1 = src[1];
        #pragma unroll
        for (int j = 0; j < 8; j++) {
            s[r][cg + j]     = (unsigned short)u0[j];
            s[r][cg + 8 + j] = (unsigned short)u1[j];
        }
    }
    __syncthreads();
    {
        int c = t >> 2, rg = (t & 3) * 16;
        s16x8 o0, o1;
        #pragma unroll
        for (int j = 0; j < 8; j++) {
            o0[j] = (short)s[rg + j][c];
            o1[j] = (short)s[rg + 8 + j][c];
        }
        s16x8* dst = (s16x8*)(vT + (size_t)(colo + c) * 8192 + rowo + rg);
        dst[0] = o0; dst[1] = o1;
    }
}

// ---------------- CSR build ------------------------------------------------
__global__ void count_deg_k(const int* eAB, const int* eBA, int* deg) {
    int i = blockIdx.x * 256 + threadIdx.x;
    if (i >= NE_) return;
    int s, d; edge_sd(i, eAB, eBA, s, d);
    atomicAdd(&deg[d], 1);
}

__global__ __launch_bounds__(256) void scan_k(const int* __restrict__ deg, int* rowstart) {
    __shared__ int part[256];
    int t = threadIdx.x;
    int base = t * 32;
    int loc[32]; int s = 0;
    #pragma unroll
    for (int j = 0; j < 32; j++) { loc[j] = s; s += deg[base + j]; }
    part[t] = s;
    __syncthreads();
    if (t == 0) {
        int a = 0;
        for (int i = 0; i < 256; i++) { int v = part[i]; part[i] = a; a += v; }
        rowstart[NN_] = a;
    }
    __syncthreads();
    int off = part[t];
    #pragma unroll
    for (int j = 0; j < 32; j++) rowstart[base + j] = off + loc[j];
}

__global__ void fill_csr_k(const int* eAB, const int* eBA,
                           const int* __restrict__ rowstart, int* cursor,
                           int* csr_src, int* pos) {
    int i = blockIdx.x * 256 + threadIdx.x;
    if (i >= NE_) return;
    int s, d; edge_sd(i, eAB, eBA, s, d);
    int p = atomicAdd(&cursor[d], 1);
    int slot = rowstart[d] + p;
    csr_src[slot] = s;
    pos[i] = slot;
}

// ---------------- fused GAT edge pass: e -> exp(e) scatter + denom ----------
__global__ void edge_fused_k(const int* eAB, const int* eBA,
                             const float* __restrict__ as_, const float* __restrict__ ad_,
                             const int* __restrict__ pos,
                             float* __restrict__ evs, float* __restrict__ denom) {
    int i = blockIdx.x * 256 + threadIdx.x;
    if (i >= NE_) return;
    int s, d; edge_sd(i, eAB, eBA, s, d);
    float e = as_[s] + ad_[d];
    e = (e >= 0.f) ? e : NEG_SLOPE_ * e;
    float ex = expf(e);
    evs[pos[i]] = ex;
    atomicAdd(&denom[d], ex);
}

// ---------------- GAT aggregation: streaming CSR, 2-edge unrolled -----------
template<bool SPLIT>
__global__ __launch_bounds__(256) void gat_agg_k(
    const int* __restrict__ rowstart, const int* __restrict__ csr_src,
    const float* __restrict__ evs, const float* __restrict__ denom,
    const unsigned short* __restrict__ hb, const float* __restrict__ bias,
    float* __restrict__ outF, int ldo,
    unsigned short* __restrict__ outHi, unsigned short* __restrict__ outLo)
{
    int wid  = (blockIdx.x * 256 + threadIdx.x) >> 6;
    int lane = threadIdx.x & 63;
    if (wid >= NN_) return;
    float acc[8] = {0.f,0.f,0.f,0.f,0.f,0.f,0.f,0.f};
    int beg = rowstart[wid], end = rowstart[wid + 1];
    float rden = 1.0f / denom[wid];
    int p = beg;
    for (; p + 1 < end; p += 2) {
        int s0 = csr_src[p], s1 = csr_src[p + 1];
        float al0 = evs[p] * rden, al1 = evs[p + 1] * rden;
        s16x8 h0 = *(const s16x8*)(hb + (size_t)s0 * HH_ + lane * 8);
        s16x8 h1 = *(const s16x8*)(hb + (size_t)s1 * HH_ + lane * 8);
        #pragma unroll
        for (int j = 0; j < 8; j++)
            acc[j] = fmaf(al1, bf2f((unsigned short)h1[j]),
                     fmaf(al0, bf2f((unsigned short)h0[j]), acc[j]));
    }
    if (p < end) {
        int s0 = csr_src[p];
        float al0 = evs[p] * rden;
        s16x8 h0 = *(const s16x8*)(hb + (size_t)s0 * HH_ + lane * 8);
        #pragma unroll
        for (int j = 0; j < 8; j++)
            acc[j] = fmaf(al0, bf2f((unsigned short)h0[j]), acc[j]);
    }
    #pragma unroll
    for (int j = 0; j < 8; j++) acc[j] += bias[lane * 8 + j];
    if (SPLIT) {
        s16x8 hi, lo;
        #pragma unroll
        for (int j = 0; j < 8; j++) {
            unsigned short h = f2bf(acc[j]);
            hi[j] = (short)h;
            lo[j] = (short)f2bf(acc[j] - bf2f(h));
        }
        *(s16x8*)(outHi + (size_t)wid * HH_ + lane * 8) = hi;
        *(s16x8*)(outLo + (size_t)wid * HH_ + lane * 8) = lo;
    } else {
        float* o = outF + (size_t)wid * ldo + lane * 8;
        *(float4*)(o)     = make_float4(acc[0], acc[1], acc[2], acc[3]);
        *(float4*)(o + 4) = make_float4(acc[4], acc[5], acc[6], acc[7]);
    }
}

// ===========================================================================
extern "C" void kernel_launch(void* const* d_in, const int* in_sizes, int n_in,
                              void* d_out, int out_size, void* d_ws, size_t ws_size,
                              hipStream_t stream)
{
    const float* x_A    = (const float*)d_in[0];
    const float* x_B    = (const float*)d_in[1];
    const int*   eAB    = (const int*)d_in[2];
    const int*   eBA    = (const int*)d_in[3];
    const float* W_inA  = (const float*)d_in[4];  const float* b_inA  = (const float*)d_in[5];
    const float* W_inB  = (const float*)d_in[6];  const float* b_inB  = (const float*)d_in[7];
    const float* W_in2A = (const float*)d_in[8];  const float* b_in2A = (const float*)d_in[9];
    const float* W_in2B = (const float*)d_in[10]; const float* b_in2B = (const float*)d_in[11];
    const float* Wg1    = (const float*)d_in[12]; const float* a_src1 = (const float*)d_in[13];
    const float* a_dst1 = (const float*)d_in[14]; const float* bg1    = (const float*)d_in[15];
    const float* Wg2    = (const float*)d_in[16]; const float* a_src2 = (const float*)d_in[17];
    const float* a_dst2 = (const float*)d_in[18]; const float* bg2    = (const float*)d_in[19];
    const float* Wqkv   = (const float*)d_in[20]; const float* bqkv   = (const float*)d_in[21];
    const float* Wo     = (const float*)d_in[22]; const float* bo     = (const float*)d_in[23];

    float* out = (float*)d_out;

    char* base = (char*)d_ws;
    size_t off = 0;
    auto alloc = [&](size_t nb) -> char* {
        char* p = base + off;
        off = (off + nb + 255) & ~(size_t)255;
        return p;
    };

    // bufA and bufB MUST be adjacent: Sb (32MB) spans both during attention.
    float*          bufA  = (float*)alloc((size_t)NN_ * 512 * 4);
    float*          bufB  = (float*)alloc((size_t)NN_ * 512 * 4);
    float*          bufC  = (float*)alloc((size_t)NN_ * 512 * 4);
    // as_..cdn contiguous: first memset covers all six; re-zero covers first 3
    float*          as_   = (float*)alloc(NN_ * 4);
    float*          ad_   = (float*)alloc(NN_ * 4);
    float*          denom = (float*)alloc(NN_ * 4);
    int*            deg   = (int*)alloc(NN_ * 4);
    int*            cursor= (int*)alloc(NN_ * 4);
    float*          cdn   = (float*)alloc(NN_ * 4);    // per-chunk attn denoms
    int*            rowst = (int*)alloc((NN_ + 1) * 4);
    int*            csrs  = (int*)alloc((size_t)NE_ * 4);   // src per CSR slot
    int*            pos   = (int*)alloc((size_t)NE_ * 4);   // edge -> CSR slot
    float*          evs   = (float*)alloc((size_t)NE_ * 4); // exp in CSR order
    unsigned short* xbA   = (unsigned short*)alloc((size_t)NA_ * 256 * 2);
    unsigned short* xbB   = (unsigned short*)alloc((size_t)NB_ * 256 * 2);
    unsigned short* WbinA = (unsigned short*)alloc((size_t)512 * 256 * 2);
    unsigned short* WbinB = (unsigned short*)alloc((size_t)512 * 256 * 2);
    unsigned short* Wbin2A= (unsigned short*)alloc((size_t)512 * 256 * 2);
    unsigned short* Wbin2B= (unsigned short*)alloc((size_t)512 * 256 * 2);
    unsigned short* Wbqkv = (unsigned short*)alloc((size_t)1536 * 512 * 2);
    unsigned short* Wbo   = (unsigned short*)alloc((size_t)512 * 512 * 2);
    unsigned short* Wg1b  = (unsigned short*)alloc((size_t)512 * 512 * 2);
    unsigned short* Wg2b  = (unsigned short*)alloc((size_t)512 * 512 * 2);
    unsigned short* qb    = (unsigned short*)alloc((size_t)NN_ * 512 * 2);
    unsigned short* kb    = (unsigned short*)alloc((size_t)NN_ * 512 * 2);
    unsigned short* vT    = (unsigned short*)alloc((size_t)512 * NN_ * 2);
    unsigned short* ab    = (unsigned short*)alloc((size_t)NN_ * 512 * 2);

    // overlays
    unsigned short* hb = vT;                              // bf16 h (local branch)
    unsigned short* gb = (unsigned short*)bufC;           // g bf16 (global, pre-loop)
    unsigned short* vb = gb + (size_t)NN_ * 512;          // v bf16 (global, pre-loop)
    unsigned short* Sb = (unsigned short*)bufA;           // scores: bufA+bufB = 32MB
    unsigned short* pv = (unsigned short*)bufC;           // PV bf16 partials (16MB)

    const int R = 2048, SEGS = 8, KSEG = 8192 / SEGS;
    const int EG = (NE_ + 255) / 256;
    const float scale2 = 0.044194173824159216f * 1.4426950408889634f; // /sqrt(512)*log2e

    // -------- all weight/input casts in ONE launch --------------------------
    CvtJobs jobs;
    jobs.j[0] = { x_A,    xbA,    nullptr, NA_ * 256 / 4 };
    jobs.j[1] = { x_B,    xbB,    nullptr, NB_ * 256 / 4 };
    jobs.j[2] = { W_inA,  WbinA,  nullptr, 512 * 256 / 4 };
    jobs.j[3] = { W_inB,  WbinB,  nullptr, 512 * 256 / 4 };
    jobs.j[4] = { W_in2A, Wbin2A, nullptr, 512 * 256 / 4 };
    jobs.j[5] = { W_in2B, Wbin2B, nullptr, 512 * 256 / 4 };
    jobs.j[6] = { Wqkv,   Wbqkv,  nullptr, 1536 * 512 / 4 };
    jobs.j[7] = { Wo,     Wbo,    nullptr, 512 * 512 / 4 };
    jobs.j[8] = { Wg1,    Wg1b,   nullptr, 512 * 512 / 4 };
    jobs.j[9] = { Wg2,    Wg2b,   nullptr, 512 * 512 / 4 };
    cvt_all_k<<<dim3(NA_ * 256 / 4 / 256, 10), 256, 0, stream>>>(jobs);

    // zero as_, ad_, denom, deg, cursor, cdn in one shot
    hipMemsetAsync(as_, 0, (size_t)NN_ * 4 * 6, stream);

    // -------- CSR build -----------------------------------------------------
    count_deg_k<<<EG, 256, 0, stream>>>(eAB, eBA, deg);
    scan_k<<<1, 256, 0, stream>>>(deg, rowst);
    fill_csr_k<<<EG, 256, 0, stream>>>(eAB, eBA, rowst, cursor, csrs, pos);

    // -------- local branch --------------------------------------------------
    mgemm_in_k<true><<<dim3(4, 64), 256, 0, stream>>>(
        xbA, xbB, WbinA, WbinB, b_inA, b_inB, qb, kb);
    mgemm3_k<<<dim3(4, 64), 256, 0, stream>>>(qb, kb, Wg1b,
                                              hb, a_src1, a_dst1, as_, ad_,
                                              512, 512, 512);
    edge_fused_k<<<EG, 256, 0, stream>>>(eAB, eBA, as_, ad_, pos, evs, denom);
    gat_agg_k<true><<<NN_/4, 256, 0, stream>>>(rowst, csrs, evs, denom,
                                               hb, bg1, nullptr, 0, qb, kb);
    hipMemsetAsync(as_, 0, NN_ * 12, stream);           // as_, ad_, denom
    mgemm3_k<<<dim3(4, 64), 256, 0, stream>>>(qb, kb, Wg2b,
                                              hb, a_src2, a_dst2, as_, ad_,
                                              512, 512, 512);
    edge_fused_k<<<EG, 256, 0, stream>>>(eAB, eBA, as_, ad_, pos, evs, denom);
    // layer-2 aggregation writes the local half of d_out directly (ldo=1024)
    gat_agg_k<false><<<NN_/4, 256, 0, stream>>>(rowst, csrs, evs, denom,
                                                hb, bg2, out, 1024, nullptr, nullptr);

    // -------- global branch -------------------------------------------------
    mgemm_in_k<false><<<dim3(4, 64), 256, 0, stream>>>(
        xbA, xbB, Wbin2A, Wbin2B, b_in2A, b_in2B, gb, nullptr);
    mgemm_qkv_k<<<dim3(12, 64), 256, 0, stream>>>(gb, Wbqkv, bqkv, scale2, qb, kb, vb);
    trT_k<<<dim3(8, 128), 256, 0, stream>>>(vb, vT);
    for (int c0 = 0; c0 < 8192; c0 += R) {
        float* dn = cdn + c0;   // this chunk's 2048 denominators (pre-zeroed)
        mgemm_qk_k<<<dim3(32, 8), 512, 0, stream>>>(
            qb + (size_t)c0 * 512, kb, Sb, dn);
        mgemm_pv_k<<<dim3(4, R/128, SEGS), 256, 0, stream>>>(
            Sb, vT, pv, KSEG, (size_t)R * 512);
        radd_k<<<(R*512/8 + 255)/256, 256, 0, stream>>>(
            pv, ab + (size_t)c0 * 512, dn, R*512/8, SEGS, (size_t)R*512/8);
    }
    // Wo GEMM writes the global half of d_out directly (ldc=1024, col offset 512)
    mgemm_k<128,128,true,float><<<dim3(4, 64), 256, 0, stream>>>(
        ab, Wbo, bo, out + 512, 512, 512, 512, 1024);
}